// Round 1
// baseline (8231.086 us; speedup 1.0000x reference)
//
#include <hip/hip_runtime.h>

// ---------------------------------------------------------------------------
// VQ-VAE forward on MI355X — round 0: correct fp32 direct-conv baseline.
// Layouts all NCHW (match reference). Intermediates in d_ws.
// ---------------------------------------------------------------------------

// Generic direct conv: one thread per output element.
// Flags: PRE_RELU (relu applied to loaded input), OUT_RELU, HAS_BIAS,
// ACC (out[idx] += result — used for residual-add fusion of the 1x1 conv).
template<int CIN, int KH, int KW, int STRIDE, int PAD,
         bool PRE_RELU, bool OUT_RELU, bool HAS_BIAS, bool ACC>
__global__ __launch_bounds__(256) void convk(
    const float* __restrict__ in, const float* __restrict__ w,
    const float* __restrict__ bias, float* __restrict__ out,
    int total, int Cout, int Hin, int Win, int Hout, int Wout)
{
    int idx = blockIdx.x * 256 + threadIdx.x;
    if (idx >= total) return;
    int ox = idx % Wout;
    int t  = idx / Wout;
    int oy = t % Hout;  t /= Hout;
    int o  = t % Cout;
    int b  = t / Cout;

    float acc = HAS_BIAS ? bias[o] : 0.0f;
    const float* wbase = w  + (size_t)o * CIN * KH * KW;
    const float* ibase = in + (size_t)b * CIN * Hin * Win;

    for (int ky = 0; ky < KH; ++ky) {
        int iy = oy * STRIDE + ky - PAD;
        if (iy < 0 || iy >= Hin) continue;
        for (int kx = 0; kx < KW; ++kx) {
            int ix = ox * STRIDE + kx - PAD;
            if (ix < 0 || ix >= Win) continue;
            const float* ip = ibase + (size_t)iy * Win + ix;
            const float* wp = wbase + ky * KW + kx;
            #pragma unroll 8
            for (int c = 0; c < CIN; ++c) {
                float v = ip[(size_t)c * Hin * Win];
                if (PRE_RELU) v = fmaxf(v, 0.0f);
                acc = fmaf(v, wp[(size_t)c * KH * KW], acc);
            }
        }
    }
    if (OUT_RELU) acc = fmaxf(acc, 0.0f);
    if (ACC) acc += out[idx];
    out[idx] = acc;
}

// Transposed conv k=4, stride=2, pad=1 (reference form: lhs-dilated
// cross-correlation with pad 2, NO kernel flip). Hout=2*Hin.
// Valid taps: ky ≡ oy (mod 2), kx ≡ ox (mod 2) — 2x2 taps per output.
template<int CIN, bool PRE_RELU, bool OUT_RELU>
__global__ __launch_bounds__(256) void convt4(
    const float* __restrict__ in, const float* __restrict__ w,
    const float* __restrict__ bias, float* __restrict__ out,
    int total, int Cout, int Hin, int Win)
{
    int Hout = Hin * 2, Wout = Win * 2;
    int idx = blockIdx.x * 256 + threadIdx.x;
    if (idx >= total) return;
    int ox = idx % Wout;
    int t  = idx / Wout;
    int oy = t % Hout;  t /= Hout;
    int o  = t % Cout;
    int b  = t / Cout;

    float acc = bias[o];
    const float* ibase = in + (size_t)b * CIN * Hin * Win;
    int ky0 = oy & 1;   // ky parity must equal oy parity
    int kx0 = ox & 1;

    #pragma unroll
    for (int tt = 0; tt < 2; ++tt) {
        int ky = ky0 + 2 * tt;
        int u  = oy + ky - 2;
        if (u < 0) continue;
        int iy = u >> 1;
        if (iy >= Hin) continue;
        #pragma unroll
        for (int ss = 0; ss < 2; ++ss) {
            int kx = kx0 + 2 * ss;
            int vv = ox + kx - 2;
            if (vv < 0) continue;
            int ix = vv >> 1;
            if (ix >= Win) continue;
            const float* ip = ibase + (size_t)iy * Win + ix;
            const float* wp = w + (size_t)o * CIN * 16 + ky * 4 + kx;
            #pragma unroll 8
            for (int c = 0; c < CIN; ++c) {
                float v = ip[(size_t)c * Hin * Win];
                if (PRE_RELU) v = fmaxf(v, 0.0f);
                acc = fmaf(v, wp[(size_t)c * 16], acc);
            }
        }
    }
    if (OUT_RELU) acc = fmaxf(acc, 0.0f);
    out[idx] = acc;
}

// Vector quantizer: one thread per z-vector (N = 32768, D = 64, K = 512).
// z layout [B,64,32,32] (stride 1024 between d elements). Writes q into the
// same layout (qc), histogram of idx, and the summed squared error.
__global__ __launch_bounds__(256) void vq_kernel(
    const float* __restrict__ z, const float* __restrict__ cb,
    float* __restrict__ qc, float* __restrict__ hist, float* __restrict__ sse)
{
    const int HW = 1024, D = 64, K = 512;
    int n = blockIdx.x * 256 + threadIdx.x;      // 0..32767
    int b = n >> 10;
    int p = n & 1023;
    const float* zp = z + (size_t)b * D * HW + p;

    float zv[D];
    #pragma unroll
    for (int d = 0; d < D; ++d) zv[d] = zp[(size_t)d * HW];

    float best = 3.402823e38f;
    int   bi   = 0;
    for (int k = 0; k < K; ++k) {
        const float* c = cb + (size_t)k * D;
        float dist = 0.0f;
        #pragma unroll
        for (int d = 0; d < D; ++d) {
            float df = zv[d] - c[d];
            dist = fmaf(df, df, dist);
        }
        if (dist < best) { best = dist; bi = k; }  // strict < : first argmin
    }

    const float* c = cb + (size_t)bi * D;
    float* qp = qc + (size_t)b * D * HW + p;
    float s = 0.0f;
    #pragma unroll
    for (int d = 0; d < D; ++d) {
        float q = c[d];
        qp[(size_t)d * HW] = q;
        float df = q - zv[d];
        s = fmaf(df, df, s);
    }
    atomicAdd(hist + bi, 1.0f);
    #pragma unroll
    for (int off = 32; off > 0; off >>= 1) s += __shfl_down(s, off, 64);
    if ((threadIdx.x & 63) == 0) atomicAdd(sse, s);
}

// loss = 1.25 * sse / (N*D);  perplexity = exp(-sum p*log(p+1e-10))
__global__ __launch_bounds__(512) void vq_finalize(
    const float* __restrict__ hist, const float* __restrict__ sse,
    float* __restrict__ out_loss, float* __restrict__ out_ppl)
{
    __shared__ float red[512];
    int t = threadIdx.x;
    float p = hist[t] * (1.0f / 32768.0f);
    red[t] = p * logf(p + 1e-10f);
    __syncthreads();
    for (int s = 256; s > 0; s >>= 1) {
        if (t < s) red[t] += red[t + s];
        __syncthreads();
    }
    if (t == 0) {
        *out_ppl  = expf(-red[0]);
        *out_loss = 1.25f * (*sse) * (1.0f / 2097152.0f);
    }
}

extern "C" void kernel_launch(void* const* d_in, const int* in_sizes, int n_in,
                              void* d_out, int out_size, void* d_ws, size_t ws_size,
                              hipStream_t stream)
{
    const float* x        = (const float*)d_in[0];
    const float* e_w1     = (const float*)d_in[1];
    const float* e_b1     = (const float*)d_in[2];
    const float* e_w2     = (const float*)d_in[3];
    const float* e_b2     = (const float*)d_in[4];
    const float* e_w3     = (const float*)d_in[5];
    const float* e_b3     = (const float*)d_in[6];
    const float* e_r1a    = (const float*)d_in[7];
    const float* e_r1b    = (const float*)d_in[8];
    const float* e_r2a    = (const float*)d_in[9];
    const float* e_r2b    = (const float*)d_in[10];
    const float* pre_w    = (const float*)d_in[11];
    const float* pre_b    = (const float*)d_in[12];
    const float* codebook = (const float*)d_in[13];
    const float* d_w1     = (const float*)d_in[14];
    const float* d_b1     = (const float*)d_in[15];
    const float* d_r1a    = (const float*)d_in[16];
    const float* d_r1b    = (const float*)d_in[17];
    const float* d_r2a    = (const float*)d_in[18];
    const float* d_r2b    = (const float*)d_in[19];
    const float* dt_w1    = (const float*)d_in[20];
    const float* dt_b1    = (const float*)d_in[21];
    const float* dt_w2    = (const float*)d_in[22];
    const float* dt_b2    = (const float*)d_in[23];
    float* out = (float*)d_out;

    // workspace layout (floats)
    float* ws = (float*)d_ws;
    float* A   = ws;               // 8,388,608  [32, 64,64,64] h1 / convT1 out
    float* Bb  = A  + 8388608;     // 4,194,304  [32,128,32,32] h2 / dec res
    float* C   = Bb + 4194304;     // 4,194,304  [32,128,32,32] enc res
    float* D   = C  + 4194304;     // 1,048,576  [32, 32,32,32] res 3x3 out
    float* E   = D  + 1048576;     // 2,097,152  [32, 64,32,32] z
    float* F   = E  + 2097152;     // 2,097,152  [32, 64,32,32] qc
    float* st  = F  + 2097152;     // 513        hist[512] + sse[1]

    auto g = [](int total) { return dim3((unsigned)((total + 255) / 256)); };

    // ----- encoder -----
    convk<3,4,4,2,1,false,true,true,false><<<g(8388608),256,0,stream>>>(
        x, e_w1, e_b1, A, 8388608, 64, 128,128, 64,64);
    convk<64,4,4,2,1,false,true,true,false><<<g(4194304),256,0,stream>>>(
        A, e_w2, e_b2, Bb, 4194304, 128, 64,64, 32,32);
    convk<128,3,3,1,1,false,false,true,false><<<g(4194304),256,0,stream>>>(
        Bb, e_w3, e_b3, C, 4194304, 128, 32,32, 32,32);
    convk<128,3,3,1,1,true,false,false,false><<<g(1048576),256,0,stream>>>(
        C, e_r1a, nullptr, D, 1048576, 32, 32,32, 32,32);
    convk<32,1,1,1,0,true,false,false,true><<<g(4194304),256,0,stream>>>(
        D, e_r1b, nullptr, C, 4194304, 128, 32,32, 32,32);
    convk<128,3,3,1,1,true,false,false,false><<<g(1048576),256,0,stream>>>(
        C, e_r2a, nullptr, D, 1048576, 32, 32,32, 32,32);
    convk<32,1,1,1,0,true,false,false,true><<<g(4194304),256,0,stream>>>(
        D, e_r2b, nullptr, C, 4194304, 128, 32,32, 32,32);
    convk<128,1,1,1,0,true,false,true,false><<<g(2097152),256,0,stream>>>(
        C, pre_w, pre_b, E, 2097152, 64, 32,32, 32,32);

    // ----- vector quantizer -----
    hipMemsetAsync(st, 0, 513 * sizeof(float), stream);
    vq_kernel<<<dim3(128),256,0,stream>>>(E, codebook, F, st, st + 512);
    vq_finalize<<<dim3(1),512,0,stream>>>(st, st + 512, out, out + 1572865);

    // ----- decoder -----
    convk<64,3,3,1,1,false,false,true,false><<<g(4194304),256,0,stream>>>(
        F, d_w1, d_b1, Bb, 4194304, 128, 32,32, 32,32);
    convk<128,3,3,1,1,true,false,false,false><<<g(1048576),256,0,stream>>>(
        Bb, d_r1a, nullptr, D, 1048576, 32, 32,32, 32,32);
    convk<32,1,1,1,0,true,false,false,true><<<g(4194304),256,0,stream>>>(
        D, d_r1b, nullptr, Bb, 4194304, 128, 32,32, 32,32);
    convk<128,3,3,1,1,true,false,false,false><<<g(1048576),256,0,stream>>>(
        Bb, d_r2a, nullptr, D, 1048576, 32, 32,32, 32,32);
    convk<32,1,1,1,0,true,false,false,true><<<g(4194304),256,0,stream>>>(
        D, d_r2b, nullptr, Bb, 4194304, 128, 32,32, 32,32);
    convt4<128,true,true><<<g(8388608),256,0,stream>>>(
        Bb, dt_w1, dt_b1, A, 8388608, 64, 32,32);
    convt4<64,false,false><<<g(1572864),256,0,stream>>>(
        A, dt_w2, dt_b2, out + 1, 1572864, 3, 64,64);
}

// Round 2
// 1695.193 us; speedup vs baseline: 4.8555x; 4.8555x over previous
//
#include <hip/hip_runtime.h>

// ---------------------------------------------------------------------------
// VQ-VAE forward, round 1: im2col + bf16 MFMA GEMM everywhere.
// Encoder path uses split-bf16 (hi+lo) 3-term MFMA for fp32-class accuracy
// (protects the VQ argmin / perplexity). Decoder path plain bf16.
// ---------------------------------------------------------------------------

typedef short short8 __attribute__((ext_vector_type(8)));
typedef short short2v __attribute__((ext_vector_type(2)));
typedef float f32x4 __attribute__((ext_vector_type(4)));

__device__ __forceinline__ unsigned short f2bf(float f) {
    unsigned u = __builtin_bit_cast(unsigned, f);
    u += 0x7fffu + ((u >> 16) & 1u);      // RNE
    return (unsigned short)(u >> 16);
}
__device__ __forceinline__ float bf2f(unsigned short b) {
    unsigned u = ((unsigned)b) << 16;
    return __builtin_bit_cast(float, u);
}
__device__ __forceinline__ void gload_lds16(const void* g, void* l) {
    __builtin_amdgcn_global_load_lds(
        (const __attribute__((address_space(1))) void*)g,
        (__attribute__((address_space(3))) void*)l, 16, 0, 0);
}

// ---------------------------------------------------------------------------
// im2col: A[m][k] bf16, k = tap*CIN + c. Coalesced input reads (lane = m),
// LDS transpose, coalesced 16B writes. Optional hi/lo split (2 planes).
// ---------------------------------------------------------------------------
template<int CIN, int KH, int KW, int S, bool PRERELU, bool SPLIT>
__global__ __launch_bounds__(256) void im2col_k(
    const float* __restrict__ in, unsigned short* __restrict__ A,
    int m0, int Hin, int Win, int Wout, int HWout,
    int Kpad, int pad_y, int pad_x, int nkt, unsigned long long lo_off)
{
    constexpr int K = CIN * KH * KW;
    __shared__ unsigned short lsh[64 * 66];
    __shared__ unsigned short lsl[SPLIT ? 64 * 66 : 64];
    int bid = blockIdx.x;
    int kt = (bid % nkt) * 64;
    int mt = (bid / nkt) * 64;
    int t = threadIdx.x;
    {
        int mloc = t & 63;
        int m = m0 + mt + mloc;
        int b = m / HWout;
        int rem = m - b * HWout;
        int oy = rem / Wout;
        int ox = rem - oy * Wout;
        const float* ib = in + (size_t)b * CIN * Hin * Win;
        int iy0 = oy * S - pad_y, ix0 = ox * S - pad_x;
        #pragma unroll
        for (int j = 0; j < 16; ++j) {
            int kk = (t >> 6) + j * 4;
            int k = kt + kk;
            float v = 0.0f;
            if (k < K) {
                int tap = k / CIN, c = k - tap * CIN;
                int ky = tap / KW, kx = tap - ky * KW;
                int iy = iy0 + ky, ix = ix0 + kx;
                if ((unsigned)iy < (unsigned)Hin && (unsigned)ix < (unsigned)Win) {
                    v = ib[((size_t)c * Hin + iy) * Win + ix];
                    if (PRERELU) v = fmaxf(v, 0.0f);
                }
            }
            unsigned short hb = f2bf(v);
            lsh[mloc * 66 + kk] = hb;
            if (SPLIT) lsl[mloc * 66 + kk] = f2bf(v - bf2f(hb));
        }
    }
    __syncthreads();
    int m2 = t >> 2, kg = (t & 3) * 16;
    int col = kt + kg;
    if (col < Kpad) {
        short8 v0, v1;
        #pragma unroll
        for (int i = 0; i < 4; ++i) {
            short2v p = *(const short2v*)&lsh[m2 * 66 + kg + 2 * i];
            v0[2 * i] = p[0]; v0[2 * i + 1] = p[1];
            short2v q = *(const short2v*)&lsh[m2 * 66 + kg + 8 + 2 * i];
            v1[2 * i] = q[0]; v1[2 * i + 1] = q[1];
        }
        size_t base = (size_t)(mt + m2) * Kpad + col;
        *(short8*)&A[base] = v0;
        *(short8*)&A[base + 8] = v1;
        if (SPLIT) {
            #pragma unroll
            for (int i = 0; i < 4; ++i) {
                short2v p = *(const short2v*)&lsl[m2 * 66 + kg + 2 * i];
                v0[2 * i] = p[0]; v0[2 * i + 1] = p[1];
                short2v q = *(const short2v*)&lsl[m2 * 66 + kg + 8 + 2 * i];
                v1[2 * i] = q[0]; v1[2 * i + 1] = q[1];
            }
            *(short8*)&A[lo_off + base] = v0;
            *(short8*)&A[lo_off + base + 8] = v1;
        }
    }
}

// ---------------------------------------------------------------------------
// GEMM: C[m][n] = A[m][:] . W[n][:]  (W stored row-major [N][Kpad] = B^T).
// BM=128, 256 threads = 4 waves. 16x16x32 bf16 MFMA.
// SPLIT: 3-term hi/lo product for ~2^-18 accuracy.
// ---------------------------------------------------------------------------
template<int BN, int WM_, int WN_, bool SPLIT, bool BIAS, bool RES, bool RELU, bool SCATTER>
__global__ __launch_bounds__(256) void gemm_conv(
    const unsigned short* __restrict__ A, const unsigned short* __restrict__ W,
    const float* __restrict__ bias, float* __restrict__ outp,
    const float* __restrict__ resp,
    int Kpad, int m0, int HW, int Cout, int Ws, int py, int px,
    unsigned long long aloff, unsigned long long wloff)
{
    constexpr int BM = 128;
    constexpr int MI = BM / WM_ / 16;
    constexpr int NI = BN / WN_ / 16;
    __shared__ __align__(16) unsigned short lsA[BM * 32 * (SPLIT ? 2 : 1)];
    __shared__ __align__(16) unsigned short lsB[BN * 32 * (SPLIT ? 2 : 1)];
    int t = threadIdx.x;
    int l = t & 63;
    int w = t >> 6;
    int tm = blockIdx.x * BM;
    int wm0 = (w / WN_) * (BM / WM_);
    int wn0 = (w % WN_) * (BN / WN_);
    f32x4 acc[MI][NI] = {};
    const int e0 = t * 8;
    for (int k0 = 0; k0 < Kpad; k0 += 32) {
        {   // A hi (+lo)
            size_t ga0 = (size_t)(tm + (e0 >> 5)) * Kpad + k0 + (e0 & 31);
            int e1 = e0 + 2048;
            size_t ga1 = (size_t)(tm + (e1 >> 5)) * Kpad + k0 + (e1 & 31);
            gload_lds16(A + ga0, &lsA[e0]);
            gload_lds16(A + ga1, &lsA[e1]);
            if (SPLIT) {
                gload_lds16(A + aloff + ga0, &lsA[BM * 32 + e0]);
                gload_lds16(A + aloff + ga1, &lsA[BM * 32 + e1]);
            }
        }
        if (e0 < BN * 32) {
            size_t gb0 = (size_t)(e0 >> 5) * Kpad + k0 + (e0 & 31);
            gload_lds16(W + gb0, &lsB[e0]);
            if (SPLIT) gload_lds16(W + wloff + gb0, &lsB[BN * 32 + e0]);
        }
        if (BN == 128) {
            int e1 = e0 + 2048;
            size_t gb1 = (size_t)(e1 >> 5) * Kpad + k0 + (e1 & 31);
            gload_lds16(W + gb1, &lsB[e1]);
            if (SPLIT) gload_lds16(W + wloff + gb1, &lsB[BN * 32 + e1]);
        }
        __syncthreads();
        short8 ah[MI], bh[NI];
        #pragma unroll
        for (int mi = 0; mi < MI; ++mi)
            ah[mi] = *(const short8*)&lsA[(wm0 + mi * 16 + (l & 15)) * 32 + (l >> 4) * 8];
        #pragma unroll
        for (int ni = 0; ni < NI; ++ni)
            bh[ni] = *(const short8*)&lsB[(wn0 + ni * 16 + (l & 15)) * 32 + (l >> 4) * 8];
        if (SPLIT) {
            short8 al[MI], bl[NI];
            #pragma unroll
            for (int mi = 0; mi < MI; ++mi)
                al[mi] = *(const short8*)&lsA[BM * 32 + (wm0 + mi * 16 + (l & 15)) * 32 + (l >> 4) * 8];
            #pragma unroll
            for (int ni = 0; ni < NI; ++ni)
                bl[ni] = *(const short8*)&lsB[BN * 32 + (wn0 + ni * 16 + (l & 15)) * 32 + (l >> 4) * 8];
            #pragma unroll
            for (int mi = 0; mi < MI; ++mi)
                #pragma unroll
                for (int ni = 0; ni < NI; ++ni) {
                    acc[mi][ni] = __builtin_amdgcn_mfma_f32_16x16x32_bf16(ah[mi], bh[ni], acc[mi][ni], 0, 0, 0);
                    acc[mi][ni] = __builtin_amdgcn_mfma_f32_16x16x32_bf16(ah[mi], bl[ni], acc[mi][ni], 0, 0, 0);
                    acc[mi][ni] = __builtin_amdgcn_mfma_f32_16x16x32_bf16(al[mi], bh[ni], acc[mi][ni], 0, 0, 0);
                }
        } else {
            #pragma unroll
            for (int mi = 0; mi < MI; ++mi)
                #pragma unroll
                for (int ni = 0; ni < NI; ++ni)
                    acc[mi][ni] = __builtin_amdgcn_mfma_f32_16x16x32_bf16(ah[mi], bh[ni], acc[mi][ni], 0, 0, 0);
        }
        __syncthreads();
    }
    #pragma unroll
    for (int mi = 0; mi < MI; ++mi) {
        #pragma unroll
        for (int ni = 0; ni < NI; ++ni) {
            int n = wn0 + ni * 16 + (l & 15);
            if (n >= Cout) continue;
            float bv = BIAS ? bias[n] : 0.0f;
            #pragma unroll
            for (int j = 0; j < 4; ++j) {
                int m = m0 + tm + wm0 + mi * 16 + (l >> 4) * 4 + j;
                float v = acc[mi][ni][j] + bv;
                if (RELU) v = fmaxf(v, 0.0f);
                size_t idx;
                int b = m / HW;
                int rem = m - b * HW;
                if (SCATTER) {
                    int y = rem / Ws, x = rem - y * Ws;
                    idx = (size_t)(b * Cout + n) * (4 * HW) + (size_t)(2 * y + py) * (2 * Ws) + (2 * x + px);
                } else {
                    idx = (size_t)(b * Cout + n) * HW + rem;
                }
                if (RES) v += resp[idx];
                outp[idx] = v;
            }
        }
    }
}

// ---------------------------------------------------------------------------
// Weight packing: wp[n][k] bf16, k = tap*CIN + c (mode 0: tap=ky*KW+kx over
// full kernel; mode 1: convT parity, tap=ty*2+tx, ky=py+2ty, kx=px+2tx).
// split: also write lo plane at dstoff + Npad*Kpad.
// ---------------------------------------------------------------------------
struct PackDesc {
    const float* src; unsigned long long dstoff;
    int Npad, N, CIN, KH, KW, K, Kpad, mode, py, px, split;
};
struct PackArgs { PackDesc d[21]; };

__global__ __launch_bounds__(256) void wpack_all(PackArgs pa, unsigned short* __restrict__ wp)
{
    PackDesc d = pa.d[blockIdx.y];
    int gid = blockIdx.x * 256 + threadIdx.x;
    int tot = d.Npad * d.Kpad;
    if (gid >= tot) return;
    int n = gid / d.Kpad;
    int k = gid - n * d.Kpad;
    float v = 0.0f;
    if (n < d.N && k < d.K) {
        int tap = k / d.CIN, c = k - tap * d.CIN;
        int ky, kx;
        if (d.mode == 0) { ky = tap / d.KW; kx = tap - ky * d.KW; }
        else { int ty = tap >> 1, tx = tap & 1; ky = d.py + 2 * ty; kx = d.px + 2 * tx; }
        v = d.src[((size_t)(n * d.CIN + c) * d.KH + ky) * d.KW + kx];
    }
    unsigned short hb = f2bf(v);
    wp[d.dstoff + gid] = hb;
    if (d.split) wp[d.dstoff + tot + gid] = f2bf(v - bf2f(hb));
}

// ---------------------------------------------------------------------------
// Vector quantizer (fp32 exact), as round 0.
// ---------------------------------------------------------------------------
__global__ __launch_bounds__(256) void vq_kernel(
    const float* __restrict__ z, const float* __restrict__ cb,
    float* __restrict__ qc, float* __restrict__ hist, float* __restrict__ sse)
{
    const int HW = 1024, D = 64, K = 512;
    int n = blockIdx.x * 256 + threadIdx.x;
    int b = n >> 10;
    int p = n & 1023;
    const float* zp = z + (size_t)b * D * HW + p;
    float zv[D];
    #pragma unroll
    for (int d = 0; d < D; ++d) zv[d] = zp[(size_t)d * HW];
    float best = 3.402823e38f;
    int bi = 0;
    for (int k = 0; k < K; ++k) {
        const float* c = cb + (size_t)k * D;
        float dist = 0.0f;
        #pragma unroll
        for (int d = 0; d < D; ++d) {
            float df = zv[d] - c[d];
            dist = fmaf(df, df, dist);
        }
        if (dist < best) { best = dist; bi = k; }
    }
    const float* c = cb + (size_t)bi * D;
    float* qp = qc + (size_t)b * D * HW + p;
    float s = 0.0f;
    #pragma unroll
    for (int d = 0; d < D; ++d) {
        float q = c[d];
        qp[(size_t)d * HW] = q;
        float df = q - zv[d];
        s = fmaf(df, df, s);
    }
    atomicAdd(hist + bi, 1.0f);
    #pragma unroll
    for (int off = 32; off > 0; off >>= 1) s += __shfl_down(s, off, 64);
    if ((threadIdx.x & 63) == 0) atomicAdd(sse, s);
}

__global__ __launch_bounds__(512) void vq_finalize(
    const float* __restrict__ hist, const float* __restrict__ sse,
    float* __restrict__ out_loss, float* __restrict__ out_ppl)
{
    __shared__ float red[512];
    int t = threadIdx.x;
    float p = hist[t] * (1.0f / 32768.0f);
    red[t] = p * logf(p + 1e-10f);
    __syncthreads();
    for (int s = 256; s > 0; s >>= 1) {
        if (t < s) red[t] += red[t + s];
        __syncthreads();
    }
    if (t == 0) {
        *out_ppl = expf(-red[0]);
        *out_loss = 1.25f * (*sse) * (1.0f / 2097152.0f);
    }
}

// ---------------------------------------------------------------------------
extern "C" void kernel_launch(void* const* d_in, const int* in_sizes, int n_in,
                              void* d_out, int out_size, void* d_ws, size_t ws_size,
                              hipStream_t stream)
{
    const float* x        = (const float*)d_in[0];
    const float* e_w1     = (const float*)d_in[1];
    const float* e_b1     = (const float*)d_in[2];
    const float* e_w2     = (const float*)d_in[3];
    const float* e_b2     = (const float*)d_in[4];
    const float* e_w3     = (const float*)d_in[5];
    const float* e_b3     = (const float*)d_in[6];
    const float* e_r1a    = (const float*)d_in[7];
    const float* e_r1b    = (const float*)d_in[8];
    const float* e_r2a    = (const float*)d_in[9];
    const float* e_r2b    = (const float*)d_in[10];
    const float* pre_w    = (const float*)d_in[11];
    const float* pre_b    = (const float*)d_in[12];
    const float* codebook = (const float*)d_in[13];
    const float* d_w1     = (const float*)d_in[14];
    const float* d_b1     = (const float*)d_in[15];
    const float* d_r1a    = (const float*)d_in[16];
    const float* d_r1b    = (const float*)d_in[17];
    const float* d_r2a    = (const float*)d_in[18];
    const float* d_r2b    = (const float*)d_in[19];
    const float* dt_w1    = (const float*)d_in[20];
    const float* dt_b1    = (const float*)d_in[21];
    const float* dt_w2    = (const float*)d_in[22];
    const float* dt_b2    = (const float*)d_in[23];
    float* out = (float*)d_out;

    // ---- workspace layout ----
    float* ws  = (float*)d_ws;
    float* h1g = ws;                    // 8,388,608  (h1; later reused as g)
    float* Bb  = h1g + 8388608;         // 4,194,304
    float* C   = Bb + 4194304;          // 4,194,304
    float* D   = C + 4194304;           // 1,048,576
    float* E   = D + 1048576;           // 2,097,152  z
    float* F   = E + 2097152;           // 2,097,152  qc
    float* st  = F + 2097152;           // 1024
    unsigned short* wp   = (unsigned short*)(st + 1024);
    const int WP_ELEMS   = 1056768;     // >= total packed weights (1,049,728)
    unsigned short* Abuf = wp + WP_ELEMS;
    size_t used = (size_t)((char*)Abuf - (char*)d_ws);
    long long Acap = ((long long)ws_size - (long long)used) / 2;  // bf16 elems

    // ---- weight packing descriptors ----
    PackArgs pa;
    int np = 0, wpo = 0;
    auto addpack = [&](const float* src, int N, int Npad, int CIN, int KH, int KW,
                       int K, int Kpad, int mode, int py, int px, int split) -> int {
        pa.d[np].src = src; pa.d[np].dstoff = (unsigned long long)wpo;
        pa.d[np].Npad = Npad; pa.d[np].N = N; pa.d[np].CIN = CIN;
        pa.d[np].KH = KH; pa.d[np].KW = KW; pa.d[np].K = K; pa.d[np].Kpad = Kpad;
        pa.d[np].mode = mode; pa.d[np].py = py; pa.d[np].px = px; pa.d[np].split = split;
        ++np; int off = wpo; wpo += Npad * Kpad * (split ? 2 : 1); return off;
    };
    int P_E1  = addpack(e_w1, 64, 64, 3, 4, 4, 48, 64, 0, 0, 0, 1);
    int P_E2  = addpack(e_w2, 128, 128, 64, 4, 4, 1024, 1024, 0, 0, 0, 1);
    int P_E3  = addpack(e_w3, 128, 128, 128, 3, 3, 1152, 1152, 0, 0, 0, 1);
    int P_R1A = addpack(e_r1a, 32, 32, 128, 3, 3, 1152, 1152, 0, 0, 0, 1);
    int P_R1B = addpack(e_r1b, 128, 128, 32, 1, 1, 32, 32, 0, 0, 0, 1);
    int P_R2A = addpack(e_r2a, 32, 32, 128, 3, 3, 1152, 1152, 0, 0, 0, 1);
    int P_R2B = addpack(e_r2b, 128, 128, 32, 1, 1, 32, 32, 0, 0, 0, 1);
    int P_PRE = addpack(pre_w, 64, 64, 128, 1, 1, 128, 128, 0, 0, 0, 1);
    int P_D1  = addpack(d_w1, 128, 128, 64, 3, 3, 576, 576, 0, 0, 0, 0);
    int P_DR1A = addpack(d_r1a, 32, 32, 128, 3, 3, 1152, 1152, 0, 0, 0, 0);
    int P_DR1B = addpack(d_r1b, 128, 128, 32, 1, 1, 32, 32, 0, 0, 0, 0);
    int P_DR2A = addpack(d_r2a, 32, 32, 128, 3, 3, 1152, 1152, 0, 0, 0, 0);
    int P_DR2B = addpack(d_r2b, 128, 128, 32, 1, 1, 32, 32, 0, 0, 0, 0);
    int P_DT1[4], P_DT2[4];
    for (int p = 0; p < 4; ++p)
        P_DT1[p] = addpack(dt_w1, 64, 64, 128, 4, 4, 512, 512, 1, p >> 1, p & 1, 0);
    for (int p = 0; p < 4; ++p)
        P_DT2[p] = addpack(dt_w2, 3, 16, 64, 4, 4, 256, 256, 1, p >> 1, p & 1, 0);

    wpack_all<<<dim3(576, 21), 256, 0, stream>>>(pa, wp);
    hipMemsetAsync(st, 0, 513 * sizeof(float), stream);

    auto chunk_rows = [&](long long M, long long Kpad, bool split) -> int {
        long long per_row = Kpad * (split ? 2 : 1);
        long long cap = Acap / per_row;
        cap &= ~127LL;
        if (cap < 128) cap = 128;
        if (cap > M) cap = M;
        return (int)cap;
    };

    // ---- macro-ish per-layer runner (explicit template instantiations) ----
    #define RUN(CIN, KH, KW, S, PRER, SPL, BN, WMX, WNX, BIASF, RESF, RELUF, SCATF, \
                INP, WOFF, BIASP, OUTP, RESP, M, KPAD, HIN, WIN, WOUT, HWOUT, PADY, PADX, HW, COUT, WSZ, PY, PX) \
    { \
        int nkt = ((KPAD) + 63) / 64; \
        int rows = chunk_rows((M), (KPAD), (SPL)); \
        for (int m0 = 0; m0 < (M); m0 += rows) { \
            int r = (M) - m0 < rows ? (M) - m0 : rows; \
            unsigned long long aloff = (unsigned long long)r * (KPAD); \
            im2col_k<CIN, KH, KW, S, PRER, SPL><<<dim3((r / 64) * nkt), 256, 0, stream>>>( \
                (INP), Abuf, m0, (HIN), (WIN), (WOUT), (HWOUT), (KPAD), (PADY), (PADX), nkt, aloff); \
            gemm_conv<BN, WMX, WNX, SPL, BIASF, RESF, RELUF, SCATF><<<dim3(r / 128), 256, 0, stream>>>( \
                Abuf, wp + (WOFF), (BIASP), (OUTP), (RESP), (KPAD), m0, (HW), (COUT), (WSZ), (PY), (PX), \
                aloff, (unsigned long long)(BN) * (KPAD)); \
        } \
    }

    // ----- encoder (split precision) -----
    RUN(3, 4, 4, 2, false, true, 64, 4, 1, true, false, true, false,
        x, P_E1, e_b1, h1g, nullptr, 131072, 64, 128, 128, 64, 4096, 1, 1, 4096, 64, 0, 0, 0)
    RUN(64, 4, 4, 2, false, true, 128, 2, 2, true, false, true, false,
        h1g, P_E2, e_b2, Bb, nullptr, 32768, 1024, 64, 64, 32, 1024, 1, 1, 1024, 128, 0, 0, 0)
    RUN(128, 3, 3, 1, false, true, 128, 2, 2, true, false, false, false,
        Bb, P_E3, e_b3, C, nullptr, 32768, 1152, 32, 32, 32, 1024, 1, 1, 1024, 128, 0, 0, 0)
    RUN(128, 3, 3, 1, true, true, 32, 4, 1, false, false, false, false,
        C, P_R1A, nullptr, D, nullptr, 32768, 1152, 32, 32, 32, 1024, 1, 1, 1024, 32, 0, 0, 0)
    RUN(32, 1, 1, 1, true, true, 128, 2, 2, false, true, false, false,
        D, P_R1B, nullptr, C, C, 32768, 32, 32, 32, 32, 1024, 0, 0, 1024, 128, 0, 0, 0)
    RUN(128, 3, 3, 1, true, true, 32, 4, 1, false, false, false, false,
        C, P_R2A, nullptr, D, nullptr, 32768, 1152, 32, 32, 32, 1024, 1, 1, 1024, 32, 0, 0, 0)
    RUN(32, 1, 1, 1, true, true, 128, 2, 2, false, true, false, false,
        D, P_R2B, nullptr, C, C, 32768, 32, 32, 32, 32, 1024, 0, 0, 1024, 128, 0, 0, 0)
    RUN(128, 1, 1, 1, true, true, 64, 4, 1, true, false, false, false,
        C, P_PRE, pre_b, E, nullptr, 32768, 128, 32, 32, 32, 1024, 0, 0, 1024, 64, 0, 0, 0)

    // ----- vector quantizer -----
    vq_kernel<<<dim3(128), 256, 0, stream>>>(E, codebook, F, st, st + 512);
    vq_finalize<<<dim3(1), 512, 0, stream>>>(st, st + 512, out, out + 1572865);

    // ----- decoder (plain bf16) -----
    RUN(64, 3, 3, 1, false, false, 128, 2, 2, true, false, false, false,
        F, P_D1, d_b1, Bb, nullptr, 32768, 576, 32, 32, 32, 1024, 1, 1, 1024, 128, 0, 0, 0)
    RUN(128, 3, 3, 1, true, false, 32, 4, 1, false, false, false, false,
        Bb, P_DR1A, nullptr, D, nullptr, 32768, 1152, 32, 32, 32, 1024, 1, 1, 1024, 32, 0, 0, 0)
    RUN(32, 1, 1, 1, true, false, 128, 2, 2, false, true, false, false,
        D, P_DR1B, nullptr, Bb, Bb, 32768, 32, 32, 32, 32, 1024, 0, 0, 1024, 128, 0, 0, 0)
    RUN(128, 3, 3, 1, true, false, 32, 4, 1, false, false, false, false,
        Bb, P_DR2A, nullptr, D, nullptr, 32768, 1152, 32, 32, 32, 1024, 1, 1, 1024, 32, 0, 0, 0)
    RUN(32, 1, 1, 1, true, false, 128, 2, 2, false, true, false, false,
        D, P_DR2B, nullptr, Bb, Bb, 32768, 32, 32, 32, 32, 1024, 0, 0, 1024, 128, 0, 0, 0)

    for (int p = 0; p < 4; ++p) {
        RUN(128, 2, 2, 1, true, false, 64, 4, 1, true, false, true, true,
            Bb, P_DT1[p], dt_b1, h1g, nullptr, 32768, 512, 32, 32, 32, 1024,
            1 - (p >> 1), 1 - (p & 1), 1024, 64, 32, p >> 1, p & 1)
    }
    for (int p = 0; p < 4; ++p) {
        RUN(64, 2, 2, 1, false, false, 16, 4, 1, true, false, false, true,
            h1g, P_DT2[p], dt_b2, out + 1, nullptr, 131072, 256, 64, 64, 64, 4096,
            1 - (p >> 1), 1 - (p & 1), 4096, 3, 64, p >> 1, p & 1)
    }
    #undef RUN
}

// Round 3
// 1459.410 us; speedup vs baseline: 5.6400x; 1.1616x over previous
//
#include <hip/hip_runtime.h>

// ---------------------------------------------------------------------------
// VQ-VAE forward, round 2: round-1 conv pipeline (im2col + bf16 MFMA GEMM,
// split-bf16 encoder) + rewritten parallel VQ:
//   vq_sq     : ccsq[k] = |codebook[k]|^2
//   vq_scan   : 4 code-chunks x 32768 vectors, score = ccsq - 2*dot (argmin-
//               equivalent), 4 independent FMA chains, scalar codebook loads
//   vq_reduce : min over chunks (first-argmin), gather q, exact fp32 SSE+hist
// ---------------------------------------------------------------------------

typedef short short8 __attribute__((ext_vector_type(8)));
typedef short short2v __attribute__((ext_vector_type(2)));
typedef float f32x4 __attribute__((ext_vector_type(4)));

__device__ __forceinline__ unsigned short f2bf(float f) {
    unsigned u = __builtin_bit_cast(unsigned, f);
    u += 0x7fffu + ((u >> 16) & 1u);      // RNE
    return (unsigned short)(u >> 16);
}
__device__ __forceinline__ float bf2f(unsigned short b) {
    unsigned u = ((unsigned)b) << 16;
    return __builtin_bit_cast(float, u);
}
__device__ __forceinline__ void gload_lds16(const void* g, void* l) {
    __builtin_amdgcn_global_load_lds(
        (const __attribute__((address_space(1))) void*)g,
        (__attribute__((address_space(3))) void*)l, 16, 0, 0);
}

// ---------------------------------------------------------------------------
// im2col: A[m][k] bf16, k = tap*CIN + c. (unchanged from round 1)
// ---------------------------------------------------------------------------
template<int CIN, int KH, int KW, int S, bool PRERELU, bool SPLIT>
__global__ __launch_bounds__(256) void im2col_k(
    const float* __restrict__ in, unsigned short* __restrict__ A,
    int m0, int Hin, int Win, int Wout, int HWout,
    int Kpad, int pad_y, int pad_x, int nkt, unsigned long long lo_off)
{
    constexpr int K = CIN * KH * KW;
    __shared__ unsigned short lsh[64 * 66];
    __shared__ unsigned short lsl[SPLIT ? 64 * 66 : 64];
    int bid = blockIdx.x;
    int kt = (bid % nkt) * 64;
    int mt = (bid / nkt) * 64;
    int t = threadIdx.x;
    {
        int mloc = t & 63;
        int m = m0 + mt + mloc;
        int b = m / HWout;
        int rem = m - b * HWout;
        int oy = rem / Wout;
        int ox = rem - oy * Wout;
        const float* ib = in + (size_t)b * CIN * Hin * Win;
        int iy0 = oy * S - pad_y, ix0 = ox * S - pad_x;
        #pragma unroll
        for (int j = 0; j < 16; ++j) {
            int kk = (t >> 6) + j * 4;
            int k = kt + kk;
            float v = 0.0f;
            if (k < K) {
                int tap = k / CIN, c = k - tap * CIN;
                int ky = tap / KW, kx = tap - ky * KW;
                int iy = iy0 + ky, ix = ix0 + kx;
                if ((unsigned)iy < (unsigned)Hin && (unsigned)ix < (unsigned)Win) {
                    v = ib[((size_t)c * Hin + iy) * Win + ix];
                    if (PRERELU) v = fmaxf(v, 0.0f);
                }
            }
            unsigned short hb = f2bf(v);
            lsh[mloc * 66 + kk] = hb;
            if (SPLIT) lsl[mloc * 66 + kk] = f2bf(v - bf2f(hb));
        }
    }
    __syncthreads();
    int m2 = t >> 2, kg = (t & 3) * 16;
    int col = kt + kg;
    if (col < Kpad) {
        short8 v0, v1;
        #pragma unroll
        for (int i = 0; i < 4; ++i) {
            short2v p = *(const short2v*)&lsh[m2 * 66 + kg + 2 * i];
            v0[2 * i] = p[0]; v0[2 * i + 1] = p[1];
            short2v q = *(const short2v*)&lsh[m2 * 66 + kg + 8 + 2 * i];
            v1[2 * i] = q[0]; v1[2 * i + 1] = q[1];
        }
        size_t base = (size_t)(mt + m2) * Kpad + col;
        *(short8*)&A[base] = v0;
        *(short8*)&A[base + 8] = v1;
        if (SPLIT) {
            #pragma unroll
            for (int i = 0; i < 4; ++i) {
                short2v p = *(const short2v*)&lsl[m2 * 66 + kg + 2 * i];
                v0[2 * i] = p[0]; v0[2 * i + 1] = p[1];
                short2v q = *(const short2v*)&lsl[m2 * 66 + kg + 8 + 2 * i];
                v1[2 * i] = q[0]; v1[2 * i + 1] = q[1];
            }
            *(short8*)&A[lo_off + base] = v0;
            *(short8*)&A[lo_off + base + 8] = v1;
        }
    }
}

// ---------------------------------------------------------------------------
// GEMM (unchanged from round 1)
// ---------------------------------------------------------------------------
template<int BN, int WM_, int WN_, bool SPLIT, bool BIAS, bool RES, bool RELU, bool SCATTER>
__global__ __launch_bounds__(256) void gemm_conv(
    const unsigned short* __restrict__ A, const unsigned short* __restrict__ W,
    const float* __restrict__ bias, float* __restrict__ outp,
    const float* __restrict__ resp,
    int Kpad, int m0, int HW, int Cout, int Ws, int py, int px,
    unsigned long long aloff, unsigned long long wloff)
{
    constexpr int BM = 128;
    constexpr int MI = BM / WM_ / 16;
    constexpr int NI = BN / WN_ / 16;
    __shared__ __align__(16) unsigned short lsA[BM * 32 * (SPLIT ? 2 : 1)];
    __shared__ __align__(16) unsigned short lsB[BN * 32 * (SPLIT ? 2 : 1)];
    int t = threadIdx.x;
    int l = t & 63;
    int w = t >> 6;
    int tm = blockIdx.x * BM;
    int wm0 = (w / WN_) * (BM / WM_);
    int wn0 = (w % WN_) * (BN / WN_);
    f32x4 acc[MI][NI] = {};
    const int e0 = t * 8;
    for (int k0 = 0; k0 < Kpad; k0 += 32) {
        {
            size_t ga0 = (size_t)(tm + (e0 >> 5)) * Kpad + k0 + (e0 & 31);
            int e1 = e0 + 2048;
            size_t ga1 = (size_t)(tm + (e1 >> 5)) * Kpad + k0 + (e1 & 31);
            gload_lds16(A + ga0, &lsA[e0]);
            gload_lds16(A + ga1, &lsA[e1]);
            if (SPLIT) {
                gload_lds16(A + aloff + ga0, &lsA[BM * 32 + e0]);
                gload_lds16(A + aloff + ga1, &lsA[BM * 32 + e1]);
            }
        }
        if (e0 < BN * 32) {
            size_t gb0 = (size_t)(e0 >> 5) * Kpad + k0 + (e0 & 31);
            gload_lds16(W + gb0, &lsB[e0]);
            if (SPLIT) gload_lds16(W + wloff + gb0, &lsB[BN * 32 + e0]);
        }
        if (BN == 128) {
            int e1 = e0 + 2048;
            size_t gb1 = (size_t)(e1 >> 5) * Kpad + k0 + (e1 & 31);
            gload_lds16(W + gb1, &lsB[e1]);
            if (SPLIT) gload_lds16(W + wloff + gb1, &lsB[BN * 32 + e1]);
        }
        __syncthreads();
        short8 ah[MI], bh[NI];
        #pragma unroll
        for (int mi = 0; mi < MI; ++mi)
            ah[mi] = *(const short8*)&lsA[(wm0 + mi * 16 + (l & 15)) * 32 + (l >> 4) * 8];
        #pragma unroll
        for (int ni = 0; ni < NI; ++ni)
            bh[ni] = *(const short8*)&lsB[(wn0 + ni * 16 + (l & 15)) * 32 + (l >> 4) * 8];
        if (SPLIT) {
            short8 al[MI], bl[NI];
            #pragma unroll
            for (int mi = 0; mi < MI; ++mi)
                al[mi] = *(const short8*)&lsA[BM * 32 + (wm0 + mi * 16 + (l & 15)) * 32 + (l >> 4) * 8];
            #pragma unroll
            for (int ni = 0; ni < NI; ++ni)
                bl[ni] = *(const short8*)&lsB[BN * 32 + (wn0 + ni * 16 + (l & 15)) * 32 + (l >> 4) * 8];
            #pragma unroll
            for (int mi = 0; mi < MI; ++mi)
                #pragma unroll
                for (int ni = 0; ni < NI; ++ni) {
                    acc[mi][ni] = __builtin_amdgcn_mfma_f32_16x16x32_bf16(ah[mi], bh[ni], acc[mi][ni], 0, 0, 0);
                    acc[mi][ni] = __builtin_amdgcn_mfma_f32_16x16x32_bf16(ah[mi], bl[ni], acc[mi][ni], 0, 0, 0);
                    acc[mi][ni] = __builtin_amdgcn_mfma_f32_16x16x32_bf16(al[mi], bh[ni], acc[mi][ni], 0, 0, 0);
                }
        } else {
            #pragma unroll
            for (int mi = 0; mi < MI; ++mi)
                #pragma unroll
                for (int ni = 0; ni < NI; ++ni)
                    acc[mi][ni] = __builtin_amdgcn_mfma_f32_16x16x32_bf16(ah[mi], bh[ni], acc[mi][ni], 0, 0, 0);
        }
        __syncthreads();
    }
    #pragma unroll
    for (int mi = 0; mi < MI; ++mi) {
        #pragma unroll
        for (int ni = 0; ni < NI; ++ni) {
            int n = wn0 + ni * 16 + (l & 15);
            if (n >= Cout) continue;
            float bv = BIAS ? bias[n] : 0.0f;
            #pragma unroll
            for (int j = 0; j < 4; ++j) {
                int m = m0 + tm + wm0 + mi * 16 + (l >> 4) * 4 + j;
                float v = acc[mi][ni][j] + bv;
                if (RELU) v = fmaxf(v, 0.0f);
                size_t idx;
                int b = m / HW;
                int rem = m - b * HW;
                if (SCATTER) {
                    int y = rem / Ws, x = rem - y * Ws;
                    idx = (size_t)(b * Cout + n) * (4 * HW) + (size_t)(2 * y + py) * (2 * Ws) + (2 * x + px);
                } else {
                    idx = (size_t)(b * Cout + n) * HW + rem;
                }
                if (RES) v += resp[idx];
                outp[idx] = v;
            }
        }
    }
}

// ---------------------------------------------------------------------------
// Weight packing (unchanged)
// ---------------------------------------------------------------------------
struct PackDesc {
    const float* src; unsigned long long dstoff;
    int Npad, N, CIN, KH, KW, K, Kpad, mode, py, px, split;
};
struct PackArgs { PackDesc d[21]; };

__global__ __launch_bounds__(256) void wpack_all(PackArgs pa, unsigned short* __restrict__ wp)
{
    PackDesc d = pa.d[blockIdx.y];
    int gid = blockIdx.x * 256 + threadIdx.x;
    int tot = d.Npad * d.Kpad;
    if (gid >= tot) return;
    int n = gid / d.Kpad;
    int k = gid - n * d.Kpad;
    float v = 0.0f;
    if (n < d.N && k < d.K) {
        int tap = k / d.CIN, c = k - tap * d.CIN;
        int ky, kx;
        if (d.mode == 0) { ky = tap / d.KW; kx = tap - ky * d.KW; }
        else { int ty = tap >> 1, tx = tap & 1; ky = d.py + 2 * ty; kx = d.px + 2 * tx; }
        v = d.src[((size_t)(n * d.CIN + c) * d.KH + ky) * d.KW + kx];
    }
    unsigned short hb = f2bf(v);
    wp[d.dstoff + gid] = hb;
    if (d.split) wp[d.dstoff + tot + gid] = f2bf(v - bf2f(hb));
}

// ---------------------------------------------------------------------------
// VQ, parallel version.
// ---------------------------------------------------------------------------
__global__ __launch_bounds__(256) void vq_sq(
    const float* __restrict__ cb, float* __restrict__ ccsq)
{
    int k = blockIdx.x * 256 + threadIdx.x;   // 0..511
    const float* c = cb + (size_t)k * 64;
    float a0 = 0.f, a1 = 0.f;
    #pragma unroll
    for (int d = 0; d < 64; d += 2) {
        a0 = fmaf(c[d], c[d], a0);
        a1 = fmaf(c[d + 1], c[d + 1], a1);
    }
    ccsq[k] = a0 + a1;
}

// grid (128, 4): blockIdx.x = vector tile (256 vec), blockIdx.y = code chunk
// score = ccsq[k] - 2*dot(z,c)  (|z|^2 dropped: constant per vector)
__global__ __launch_bounds__(256) void vq_scan(
    const float* __restrict__ z, const float* __restrict__ cb,
    const float* __restrict__ ccsq,
    float* __restrict__ pdist, int* __restrict__ pidx)
{
    const int HW = 1024;
    int n = blockIdx.x * 256 + threadIdx.x;   // 0..32767
    int chunk = blockIdx.y;                    // 0..3
    int base = chunk * 128;
    int b = n >> 10;
    int p = n & 1023;
    const float* zp = z + (size_t)b * 64 * HW + p;
    float zv[64];
    #pragma unroll
    for (int d = 0; d < 64; ++d) zv[d] = zp[(size_t)d * HW];

    float best = 3.402823e38f;
    int bi = base;
    for (int kk = 0; kk < 128; kk += 2) {
        const float* c0 = cb + (size_t)(base + kk) * 64;
        float a0 = 0.f, a1 = 0.f, b0 = 0.f, b1 = 0.f;
        #pragma unroll
        for (int d = 0; d < 64; d += 2) {
            a0 = fmaf(zv[d],     c0[d],          a0);
            a1 = fmaf(zv[d + 1], c0[d + 1],      a1);
            b0 = fmaf(zv[d],     c0[64 + d],     b0);
            b1 = fmaf(zv[d + 1], c0[64 + d + 1], b1);
        }
        float s0 = ccsq[base + kk]     - 2.0f * (a0 + a1);
        float s1 = ccsq[base + kk + 1] - 2.0f * (b0 + b1);
        if (s0 < best) { best = s0; bi = base + kk; }
        if (s1 < best) { best = s1; bi = base + kk + 1; }
    }
    pdist[(size_t)chunk * 32768 + n] = best;
    pidx [(size_t)chunk * 32768 + n] = bi;
}

// final argmin over chunks + gather q + exact SSE + histogram
__global__ __launch_bounds__(256) void vq_reduce(
    const float* __restrict__ z, const float* __restrict__ cb,
    const float* __restrict__ pdist, const int* __restrict__ pidx,
    float* __restrict__ qc, float* __restrict__ hist, float* __restrict__ sse)
{
    const int HW = 1024;
    int n = blockIdx.x * 256 + threadIdx.x;
    float best = pdist[n];
    int bi = pidx[n];
    #pragma unroll
    for (int ch = 1; ch < 4; ++ch) {
        float dv = pdist[(size_t)ch * 32768 + n];
        int iv = pidx[(size_t)ch * 32768 + n];
        if (dv < best) { best = dv; bi = iv; }   // strict <: earliest chunk wins
    }
    int b = n >> 10;
    int p = n & 1023;
    const float* zp = z + (size_t)b * 64 * HW + p;
    float* qp = qc + (size_t)b * 64 * HW + p;
    const float* c = cb + (size_t)bi * 64;
    float s = 0.f;
    #pragma unroll
    for (int d = 0; d < 64; ++d) {
        float q = c[d];
        qp[(size_t)d * HW] = q;
        float df = q - zp[(size_t)d * HW];
        s = fmaf(df, df, s);
    }
    atomicAdd(hist + bi, 1.0f);
    #pragma unroll
    for (int off = 32; off > 0; off >>= 1) s += __shfl_down(s, off, 64);
    if ((threadIdx.x & 63) == 0) atomicAdd(sse, s);
}

__global__ __launch_bounds__(512) void vq_finalize(
    const float* __restrict__ hist, const float* __restrict__ sse,
    float* __restrict__ out_loss, float* __restrict__ out_ppl)
{
    __shared__ float red[512];
    int t = threadIdx.x;
    float p = hist[t] * (1.0f / 32768.0f);
    red[t] = p * logf(p + 1e-10f);
    __syncthreads();
    for (int s = 256; s > 0; s >>= 1) {
        if (t < s) red[t] += red[t + s];
        __syncthreads();
    }
    if (t == 0) {
        *out_ppl = expf(-red[0]);
        *out_loss = 1.25f * (*sse) * (1.0f / 2097152.0f);
    }
}

// ---------------------------------------------------------------------------
extern "C" void kernel_launch(void* const* d_in, const int* in_sizes, int n_in,
                              void* d_out, int out_size, void* d_ws, size_t ws_size,
                              hipStream_t stream)
{
    const float* x        = (const float*)d_in[0];
    const float* e_w1     = (const float*)d_in[1];
    const float* e_b1     = (const float*)d_in[2];
    const float* e_w2     = (const float*)d_in[3];
    const float* e_b2     = (const float*)d_in[4];
    const float* e_w3     = (const float*)d_in[5];
    const float* e_b3     = (const float*)d_in[6];
    const float* e_r1a    = (const float*)d_in[7];
    const float* e_r1b    = (const float*)d_in[8];
    const float* e_r2a    = (const float*)d_in[9];
    const float* e_r2b    = (const float*)d_in[10];
    const float* pre_w    = (const float*)d_in[11];
    const float* pre_b    = (const float*)d_in[12];
    const float* codebook = (const float*)d_in[13];
    const float* d_w1     = (const float*)d_in[14];
    const float* d_b1     = (const float*)d_in[15];
    const float* d_r1a    = (const float*)d_in[16];
    const float* d_r1b    = (const float*)d_in[17];
    const float* d_r2a    = (const float*)d_in[18];
    const float* d_r2b    = (const float*)d_in[19];
    const float* dt_w1    = (const float*)d_in[20];
    const float* dt_b1    = (const float*)d_in[21];
    const float* dt_w2    = (const float*)d_in[22];
    const float* dt_b2    = (const float*)d_in[23];
    float* out = (float*)d_out;

    // ---- workspace layout ----
    float* ws  = (float*)d_ws;
    float* h1g = ws;                    // 8,388,608  (h1; later reused as g)
    float* Bb  = h1g + 8388608;         // 4,194,304
    float* C   = Bb + 4194304;          // 4,194,304
    float* D   = C + 4194304;           // 1,048,576 (res 3x3 out; VQ scratch)
    float* E   = D + 1048576;           // 2,097,152  z
    float* F   = E + 2097152;           // 2,097,152  qc
    float* st  = F + 2097152;           // 1024
    unsigned short* wp   = (unsigned short*)(st + 1024);
    const int WP_ELEMS   = 1056768;
    unsigned short* Abuf = wp + WP_ELEMS;
    size_t used = (size_t)((char*)Abuf - (char*)d_ws);
    long long Acap = ((long long)ws_size - (long long)used) / 2;

    // VQ scratch aliases D (dead during VQ)
    float* pdist = D;                   // 131072
    int*   pidx  = (int*)(D + 131072);  // 131072
    float* ccsq  = D + 262144;          // 512

    // ---- weight packing descriptors ----
    PackArgs pa;
    int np = 0, wpo = 0;
    auto addpack = [&](const float* src, int N, int Npad, int CIN, int KH, int KW,
                       int K, int Kpad, int mode, int py, int px, int split) -> int {
        pa.d[np].src = src; pa.d[np].dstoff = (unsigned long long)wpo;
        pa.d[np].Npad = Npad; pa.d[np].N = N; pa.d[np].CIN = CIN;
        pa.d[np].KH = KH; pa.d[np].KW = KW; pa.d[np].K = K; pa.d[np].Kpad = Kpad;
        pa.d[np].mode = mode; pa.d[np].py = py; pa.d[np].px = px; pa.d[np].split = split;
        ++np; int off = wpo; wpo += Npad * Kpad * (split ? 2 : 1); return off;
    };
    int P_E1  = addpack(e_w1, 64, 64, 3, 4, 4, 48, 64, 0, 0, 0, 1);
    int P_E2  = addpack(e_w2, 128, 128, 64, 4, 4, 1024, 1024, 0, 0, 0, 1);
    int P_E3  = addpack(e_w3, 128, 128, 128, 3, 3, 1152, 1152, 0, 0, 0, 1);
    int P_R1A = addpack(e_r1a, 32, 32, 128, 3, 3, 1152, 1152, 0, 0, 0, 1);
    int P_R1B = addpack(e_r1b, 128, 128, 32, 1, 1, 32, 32, 0, 0, 0, 1);
    int P_R2A = addpack(e_r2a, 32, 32, 128, 3, 3, 1152, 1152, 0, 0, 0, 1);
    int P_R2B = addpack(e_r2b, 128, 128, 32, 1, 1, 32, 32, 0, 0, 0, 1);
    int P_PRE = addpack(pre_w, 64, 64, 128, 1, 1, 128, 128, 0, 0, 0, 1);
    int P_D1  = addpack(d_w1, 128, 128, 64, 3, 3, 576, 576, 0, 0, 0, 0);
    int P_DR1A = addpack(d_r1a, 32, 32, 128, 3, 3, 1152, 1152, 0, 0, 0, 0);
    int P_DR1B = addpack(d_r1b, 128, 128, 32, 1, 1, 32, 32, 0, 0, 0, 0);
    int P_DR2A = addpack(d_r2a, 32, 32, 128, 3, 3, 1152, 1152, 0, 0, 0, 0);
    int P_DR2B = addpack(d_r2b, 128, 128, 32, 1, 1, 32, 32, 0, 0, 0, 0);
    int P_DT1[4], P_DT2[4];
    for (int p = 0; p < 4; ++p)
        P_DT1[p] = addpack(dt_w1, 64, 64, 128, 4, 4, 512, 512, 1, p >> 1, p & 1, 0);
    for (int p = 0; p < 4; ++p)
        P_DT2[p] = addpack(dt_w2, 3, 16, 64, 4, 4, 256, 256, 1, p >> 1, p & 1, 0);

    wpack_all<<<dim3(576, 21), 256, 0, stream>>>(pa, wp);
    hipMemsetAsync(st, 0, 513 * sizeof(float), stream);

    auto chunk_rows = [&](long long M, long long Kpad, bool split) -> int {
        long long per_row = Kpad * (split ? 2 : 1);
        long long cap = Acap / per_row;
        cap &= ~127LL;
        if (cap < 128) cap = 128;
        if (cap > M) cap = M;
        return (int)cap;
    };

    #define RUN(CIN, KH, KW, S, PRER, SPL, BN, WMX, WNX, BIASF, RESF, RELUF, SCATF, \
                INP, WOFF, BIASP, OUTP, RESP, M, KPAD, HIN, WIN, WOUT, HWOUT, PADY, PADX, HW, COUT, WSZ, PY, PX) \
    { \
        int nkt = ((KPAD) + 63) / 64; \
        int rows = chunk_rows((M), (KPAD), (SPL)); \
        for (int m0 = 0; m0 < (M); m0 += rows) { \
            int r = (M) - m0 < rows ? (M) - m0 : rows; \
            unsigned long long aloff = (unsigned long long)r * (KPAD); \
            im2col_k<CIN, KH, KW, S, PRER, SPL><<<dim3((r / 64) * nkt), 256, 0, stream>>>( \
                (INP), Abuf, m0, (HIN), (WIN), (WOUT), (HWOUT), (KPAD), (PADY), (PADX), nkt, aloff); \
            gemm_conv<BN, WMX, WNX, SPL, BIASF, RESF, RELUF, SCATF><<<dim3(r / 128), 256, 0, stream>>>( \
                Abuf, wp + (WOFF), (BIASP), (OUTP), (RESP), (KPAD), m0, (HW), (COUT), (WSZ), (PY), (PX), \
                aloff, (unsigned long long)(BN) * (KPAD)); \
        } \
    }

    // ----- encoder (split precision) -----
    RUN(3, 4, 4, 2, false, true, 64, 4, 1, true, false, true, false,
        x, P_E1, e_b1, h1g, nullptr, 131072, 64, 128, 128, 64, 4096, 1, 1, 4096, 64, 0, 0, 0)
    RUN(64, 4, 4, 2, false, true, 128, 2, 2, true, false, true, false,
        h1g, P_E2, e_b2, Bb, nullptr, 32768, 1024, 64, 64, 32, 1024, 1, 1, 1024, 128, 0, 0, 0)
    RUN(128, 3, 3, 1, false, true, 128, 2, 2, true, false, false, false,
        Bb, P_E3, e_b3, C, nullptr, 32768, 1152, 32, 32, 32, 1024, 1, 1, 1024, 128, 0, 0, 0)
    RUN(128, 3, 3, 1, true, true, 32, 4, 1, false, false, false, false,
        C, P_R1A, nullptr, D, nullptr, 32768, 1152, 32, 32, 32, 1024, 1, 1, 1024, 32, 0, 0, 0)
    RUN(32, 1, 1, 1, true, true, 128, 2, 2, false, true, false, false,
        D, P_R1B, nullptr, C, C, 32768, 32, 32, 32, 32, 1024, 0, 0, 1024, 128, 0, 0, 0)
    RUN(128, 3, 3, 1, true, true, 32, 4, 1, false, false, false, false,
        C, P_R2A, nullptr, D, nullptr, 32768, 1152, 32, 32, 32, 1024, 1, 1, 1024, 32, 0, 0, 0)
    RUN(32, 1, 1, 1, true, true, 128, 2, 2, false, true, false, false,
        D, P_R2B, nullptr, C, C, 32768, 32, 32, 32, 32, 1024, 0, 0, 1024, 128, 0, 0, 0)
    RUN(128, 1, 1, 1, true, true, 64, 4, 1, true, false, false, false,
        C, P_PRE, pre_b, E, nullptr, 32768, 128, 32, 32, 32, 1024, 0, 0, 1024, 64, 0, 0, 0)

    // ----- vector quantizer -----
    vq_sq<<<dim3(2), 256, 0, stream>>>(codebook, ccsq);
    vq_scan<<<dim3(128, 4), 256, 0, stream>>>(E, codebook, ccsq, pdist, pidx);
    vq_reduce<<<dim3(128), 256, 0, stream>>>(E, codebook, pdist, pidx, F, st, st + 512);
    vq_finalize<<<dim3(1), 512, 0, stream>>>(st, st + 512, out, out + 1572865);

    // ----- decoder (plain bf16) -----
    RUN(64, 3, 3, 1, false, false, 128, 2, 2, true, false, false, false,
        F, P_D1, d_b1, Bb, nullptr, 32768, 576, 32, 32, 32, 1024, 1, 1, 1024, 128, 0, 0, 0)
    RUN(128, 3, 3, 1, true, false, 32, 4, 1, false, false, false, false,
        Bb, P_DR1A, nullptr, D, nullptr, 32768, 1152, 32, 32, 32, 1024, 1, 1, 1024, 32, 0, 0, 0)
    RUN(32, 1, 1, 1, true, false, 128, 2, 2, false, true, false, false,
        D, P_DR1B, nullptr, Bb, Bb, 32768, 32, 32, 32, 32, 1024, 0, 0, 1024, 128, 0, 0, 0)
    RUN(128, 3, 3, 1, true, false, 32, 4, 1, false, false, false, false,
        Bb, P_DR2A, nullptr, D, nullptr, 32768, 1152, 32, 32, 32, 1024, 1, 1, 1024, 32, 0, 0, 0)
    RUN(32, 1, 1, 1, true, false, 128, 2, 2, false, true, false, false,
        D, P_DR2B, nullptr, Bb, Bb, 32768, 32, 32, 32, 32, 1024, 0, 0, 1024, 128, 0, 0, 0)

    for (int p = 0; p < 4; ++p) {
        RUN(128, 2, 2, 1, true, false, 64, 4, 1, true, false, true, true,
            Bb, P_DT1[p], dt_b1, h1g, nullptr, 32768, 512, 32, 32, 32, 1024,
            1 - (p >> 1), 1 - (p & 1), 1024, 64, 32, p >> 1, p & 1)
    }
    for (int p = 0; p < 4; ++p) {
        RUN(64, 2, 2, 1, false, false, 16, 4, 1, true, false, false, true,
            h1g, P_DT2[p], dt_b2, out + 1, nullptr, 131072, 256, 64, 64, 64, 4096,
            1 - (p >> 1), 1 - (p & 1), 4096, 3, 64, p >> 1, p & 1)
    }
    #undef RUN
}

// Round 5
// 1411.418 us; speedup vs baseline: 5.8318x; 1.0340x over previous
//
#include <hip/hip_runtime.h>

// ---------------------------------------------------------------------------
// VQ-VAE forward, round 5 = round 4 + fix: BN==128 second-half W staging
// (rows 64..127 of lsB were never loaded -> NaN). Fused implicit-GEMM conv,
// split-bf16 encoder, plain bf16 decoder, parallel VQ.
// ---------------------------------------------------------------------------

typedef short short8 __attribute__((ext_vector_type(8)));
typedef float f32x4 __attribute__((ext_vector_type(4)));

__device__ __forceinline__ unsigned short f2bf(float f) {
    unsigned u = __builtin_bit_cast(unsigned, f);
    u += 0x7fffu + ((u >> 16) & 1u);      // RNE
    return (unsigned short)(u >> 16);
}
__device__ __forceinline__ float bf2f(unsigned short b) {
    unsigned u = ((unsigned)b) << 16;
    return __builtin_bit_cast(float, u);
}
__device__ __forceinline__ void gload_lds16(const void* g, void* l) {
    __builtin_amdgcn_global_load_lds(
        (const __attribute__((address_space(1))) void*)g,
        (__attribute__((address_space(3))) void*)l, 16, 0, 0);
}

// ---------------------------------------------------------------------------
// Fused conv GEMM. A[m][k] (k = tap*CIN + c) built on the fly from fp32 NCHW
// input: each thread stages 16 elements/K-step, converts to bf16 hi(+lo),
// ds_writes into LDS. W pre-packed bf16 [N][Kpad] staged via global_load_lds.
// ---------------------------------------------------------------------------
template<int CIN, int KH, int KW, int S, bool PRERELU, bool SPLIT,
         int BN, int WM_, int WN_, bool BIAS, bool RES, bool RELU, bool SCATTER>
__global__ __launch_bounds__(256) void conv_gemm(
    const float* __restrict__ in, const unsigned short* __restrict__ W,
    const float* __restrict__ bias, float* __restrict__ outp,
    const float* __restrict__ resp,
    int Kpad, int HWout, int Cout, int Hin, int Win, int Wout,
    int pady, int padx, int Ws, int py, int px, unsigned long long wloff)
{
    constexpr int BM = 128;
    constexpr int K = CIN * KH * KW;
    constexpr int ASTR = 40;                    // shorts; 80B rows (16B-mult)
    constexpr int MI = BM / WM_ / 16;
    constexpr int NI = BN / WN_ / 16;
    constexpr bool PIX1 = (KH == 1 && KW == 1 && S == 1);
    __shared__ __align__(16) unsigned short lsA[(SPLIT ? 2 : 1) * BM * ASTR];
    __shared__ __align__(16) unsigned short lsB[(SPLIT ? 2 : 1) * BN * 32];

    int t = threadIdx.x;
    int l = t & 63;
    int w = t >> 6;
    int tm = blockIdx.x * BM;
    int wm0 = (w / WN_) * (BM / WM_);
    int wn0 = (w % WN_) * (BN / WN_);

    // per-thread staging coords (fixed m-row, k-half)
    int mloc = t & 127;
    int khalf = t >> 7;
    int ms = tm + mloc;
    int bs = ms / HWout;
    int rems = ms - bs * HWout;
    int oys = rems / Wout;
    int oxs = rems - oys * Wout;
    int iy0 = oys * S - pady;
    int ix0 = oxs * S - padx;
    const float* ibase = in + (size_t)bs * CIN * Hin * Win;

    f32x4 acc[MI][NI] = {};
    const int e0 = t * 8;

    for (int k0 = 0; k0 < Kpad; k0 += 32) {
        // ---- W stage (async global->LDS) ----
        if (e0 < BN * 32) {
            size_t gb0 = (size_t)(e0 >> 5) * Kpad + k0 + (e0 & 31);
            gload_lds16(W + gb0, &lsB[e0]);
            if (SPLIT) gload_lds16(W + wloff + gb0, &lsB[BN * 32 + e0]);
        }
        if (BN == 128) {                         // second half: rows 64..127
            int e1 = e0 + 2048;
            size_t gb1 = (size_t)(e1 >> 5) * Kpad + k0 + (e1 & 31);
            gload_lds16(W + gb1, &lsB[e1]);
            if (SPLIT) gload_lds16(W + wloff + gb1, &lsB[BN * 32 + e1]);
        }
        // ---- A stage (reg: load fp32, cvt, ds_write) ----
        #pragma unroll
        for (int pp = 0; pp < 8; ++pp) {
            unsigned v2 = 0, v2l = 0;
            #pragma unroll
            for (int h = 0; h < 2; ++h) {
                int k = k0 + khalf * 16 + 2 * pp + h;
                float v = 0.0f;
                if ((K % 32 == 0) || k < K) {
                    int tap = k / CIN, c = k - tap * CIN;
                    int ky = tap / KW, kx = tap - ky * KW;
                    int iy = iy0 + ky, ix = ix0 + kx;
                    bool ok = PIX1 ? true :
                        ((unsigned)iy < (unsigned)Hin && (unsigned)ix < (unsigned)Win);
                    if (ok) v = ibase[((size_t)c * Hin + iy) * Win + ix];
                    if (PRERELU) v = fmaxf(v, 0.0f);
                }
                unsigned short hb = f2bf(v);
                v2 |= ((unsigned)hb) << (16 * h);
                if (SPLIT) v2l |= ((unsigned)f2bf(v - bf2f(hb))) << (16 * h);
            }
            *(unsigned*)&lsA[mloc * ASTR + khalf * 16 + 2 * pp] = v2;
            if (SPLIT)
                *(unsigned*)&lsA[BM * ASTR + mloc * ASTR + khalf * 16 + 2 * pp] = v2l;
        }
        __syncthreads();
        // ---- fragments + MFMA ----
        short8 ah[MI], bh[NI];
        #pragma unroll
        for (int mi = 0; mi < MI; ++mi)
            ah[mi] = *(const short8*)&lsA[(wm0 + mi * 16 + (l & 15)) * ASTR + (l >> 4) * 8];
        #pragma unroll
        for (int ni = 0; ni < NI; ++ni)
            bh[ni] = *(const short8*)&lsB[(wn0 + ni * 16 + (l & 15)) * 32 + (l >> 4) * 8];
        if (SPLIT) {
            short8 al[MI], bl[NI];
            #pragma unroll
            for (int mi = 0; mi < MI; ++mi)
                al[mi] = *(const short8*)&lsA[BM * ASTR + (wm0 + mi * 16 + (l & 15)) * ASTR + (l >> 4) * 8];
            #pragma unroll
            for (int ni = 0; ni < NI; ++ni)
                bl[ni] = *(const short8*)&lsB[BN * 32 + (wn0 + ni * 16 + (l & 15)) * 32 + (l >> 4) * 8];
            #pragma unroll
            for (int mi = 0; mi < MI; ++mi)
                #pragma unroll
                for (int ni = 0; ni < NI; ++ni) {
                    acc[mi][ni] = __builtin_amdgcn_mfma_f32_16x16x32_bf16(ah[mi], bh[ni], acc[mi][ni], 0, 0, 0);
                    acc[mi][ni] = __builtin_amdgcn_mfma_f32_16x16x32_bf16(ah[mi], bl[ni], acc[mi][ni], 0, 0, 0);
                    acc[mi][ni] = __builtin_amdgcn_mfma_f32_16x16x32_bf16(al[mi], bh[ni], acc[mi][ni], 0, 0, 0);
                }
        } else {
            #pragma unroll
            for (int mi = 0; mi < MI; ++mi)
                #pragma unroll
                for (int ni = 0; ni < NI; ++ni)
                    acc[mi][ni] = __builtin_amdgcn_mfma_f32_16x16x32_bf16(ah[mi], bh[ni], acc[mi][ni], 0, 0, 0);
        }
        __syncthreads();
    }
    // ---- epilogue ----
    #pragma unroll
    for (int mi = 0; mi < MI; ++mi) {
        #pragma unroll
        for (int ni = 0; ni < NI; ++ni) {
            int n = wn0 + ni * 16 + (l & 15);
            if (n >= Cout) continue;
            float bv = BIAS ? bias[n] : 0.0f;
            #pragma unroll
            for (int j = 0; j < 4; ++j) {
                int m = tm + wm0 + mi * 16 + (l >> 4) * 4 + j;
                float v = acc[mi][ni][j] + bv;
                if (RELU) v = fmaxf(v, 0.0f);
                size_t idx;
                int b = m / HWout;
                int rem = m - b * HWout;
                if (SCATTER) {
                    int y = rem / Ws, x = rem - y * Ws;
                    idx = (size_t)(b * Cout + n) * (4 * HWout)
                        + (size_t)(2 * y + py) * (2 * Ws) + (2 * x + px);
                } else {
                    idx = (size_t)(b * Cout + n) * HWout + rem;
                }
                if (RES) v += resp[idx];
                outp[idx] = v;
            }
        }
    }
}

// ---------------------------------------------------------------------------
// Weight packing (unchanged)
// ---------------------------------------------------------------------------
struct PackDesc {
    const float* src; unsigned long long dstoff;
    int Npad, N, CIN, KH, KW, K, Kpad, mode, py, px, split;
};
struct PackArgs { PackDesc d[21]; };

__global__ __launch_bounds__(256) void wpack_all(PackArgs pa, unsigned short* __restrict__ wp)
{
    PackDesc d = pa.d[blockIdx.y];
    int gid = blockIdx.x * 256 + threadIdx.x;
    int tot = d.Npad * d.Kpad;
    if (gid >= tot) return;
    int n = gid / d.Kpad;
    int k = gid - n * d.Kpad;
    float v = 0.0f;
    if (n < d.N && k < d.K) {
        int tap = k / d.CIN, c = k - tap * d.CIN;
        int ky, kx;
        if (d.mode == 0) { ky = tap / d.KW; kx = tap - ky * d.KW; }
        else { int ty = tap >> 1, tx = tap & 1; ky = d.py + 2 * ty; kx = d.px + 2 * tx; }
        v = d.src[((size_t)(n * d.CIN + c) * d.KH + ky) * d.KW + kx];
    }
    unsigned short hb = f2bf(v);
    wp[d.dstoff + gid] = hb;
    if (d.split) wp[d.dstoff + tot + gid] = f2bf(v - bf2f(hb));
}

// ---------------------------------------------------------------------------
// VQ
// ---------------------------------------------------------------------------
__global__ __launch_bounds__(256) void vq_sq(
    const float* __restrict__ cb, float* __restrict__ ccsq)
{
    int k = blockIdx.x * 256 + threadIdx.x;   // 0..511
    const float* c = cb + (size_t)k * 64;
    float a0 = 0.f, a1 = 0.f;
    #pragma unroll
    for (int d = 0; d < 64; d += 2) {
        a0 = fmaf(c[d], c[d], a0);
        a1 = fmaf(c[d + 1], c[d + 1], a1);
    }
    ccsq[k] = a0 + a1;
}

// grid (128, 8): 64-code chunks. score = ccsq[k] - 2*dot(z,c).
__global__ __launch_bounds__(256) void vq_scan(
    const float* __restrict__ z, const float* __restrict__ cb,
    const float* __restrict__ ccsq,
    float* __restrict__ pdist, int* __restrict__ pidx)
{
    const int HW = 1024;
    int n = blockIdx.x * 256 + threadIdx.x;   // 0..32767
    int chunk = blockIdx.y;                    // 0..7
    int base = chunk * 64;
    int b = n >> 10;
    int p = n & 1023;
    const float* zp = z + (size_t)b * 64 * HW + p;
    float zv[64];
    #pragma unroll
    for (int d = 0; d < 64; ++d) zv[d] = zp[(size_t)d * HW];

    float best = 3.402823e38f;
    int bi = base;
    for (int kk = 0; kk < 64; kk += 2) {
        const float* c0 = cb + (size_t)(base + kk) * 64;
        float a0 = 0.f, a1 = 0.f, b0 = 0.f, b1 = 0.f;
        #pragma unroll
        for (int d = 0; d < 64; d += 2) {
            a0 = fmaf(zv[d],     c0[d],          a0);
            a1 = fmaf(zv[d + 1], c0[d + 1],      a1);
            b0 = fmaf(zv[d],     c0[64 + d],     b0);
            b1 = fmaf(zv[d + 1], c0[64 + d + 1], b1);
        }
        float s0 = ccsq[base + kk]     - 2.0f * (a0 + a1);
        float s1 = ccsq[base + kk + 1] - 2.0f * (b0 + b1);
        if (s0 < best) { best = s0; bi = base + kk; }
        if (s1 < best) { best = s1; bi = base + kk + 1; }
    }
    pdist[(size_t)chunk * 32768 + n] = best;
    pidx [(size_t)chunk * 32768 + n] = bi;
}

// d-split reduce: 512 blocks; block = 64 n x 4 d-groups of 16.
__global__ __launch_bounds__(256) void vq_reduce(
    const float* __restrict__ z, const float* __restrict__ cb,
    const float* __restrict__ pdist, const int* __restrict__ pidx,
    float* __restrict__ qc, float* __restrict__ hist, float* __restrict__ sse)
{
    const int HW = 1024;
    int lane = threadIdx.x & 63;
    int dg = threadIdx.x >> 6;
    int n = blockIdx.x * 64 + lane;
    float best = pdist[n];
    int bi = pidx[n];
    #pragma unroll
    for (int ch = 1; ch < 8; ++ch) {
        float dv = pdist[(size_t)ch * 32768 + n];
        int iv = pidx[(size_t)ch * 32768 + n];
        if (dv < best) { best = dv; bi = iv; }   // strict <: earliest chunk wins
    }
    int b = n >> 10;
    int p = n & 1023;
    const float* zp = z + (size_t)b * 64 * HW + p;
    float* qp = qc + (size_t)b * 64 * HW + p;
    const float* c = cb + (size_t)bi * 64;
    float s = 0.f;
    #pragma unroll
    for (int j = 0; j < 16; ++j) {
        int d = dg * 16 + j;
        float q = c[d];
        qp[(size_t)d * HW] = q;
        float df = q - zp[(size_t)d * HW];
        s = fmaf(df, df, s);
    }
    if (dg == 0) atomicAdd(hist + bi, 1.0f);
    #pragma unroll
    for (int off = 32; off > 0; off >>= 1) s += __shfl_down(s, off, 64);
    __shared__ float red[4];
    if (lane == 0) red[dg] = s;
    __syncthreads();
    if (threadIdx.x == 0) atomicAdd(sse, red[0] + red[1] + red[2] + red[3]);
}

__global__ __launch_bounds__(512) void vq_finalize(
    const float* __restrict__ hist, const float* __restrict__ sse,
    float* __restrict__ out_loss, float* __restrict__ out_ppl)
{
    __shared__ float red[512];
    int t = threadIdx.x;
    float p = hist[t] * (1.0f / 32768.0f);
    red[t] = p * logf(p + 1e-10f);
    __syncthreads();
    for (int s = 256; s > 0; s >>= 1) {
        if (t < s) red[t] += red[t + s];
        __syncthreads();
    }
    if (t == 0) {
        *out_ppl = expf(-red[0]);
        *out_loss = 1.25f * (*sse) * (1.0f / 2097152.0f);
    }
}

// ---------------------------------------------------------------------------
extern "C" void kernel_launch(void* const* d_in, const int* in_sizes, int n_in,
                              void* d_out, int out_size, void* d_ws, size_t ws_size,
                              hipStream_t stream)
{
    const float* x        = (const float*)d_in[0];
    const float* e_w1     = (const float*)d_in[1];
    const float* e_b1     = (const float*)d_in[2];
    const float* e_w2     = (const float*)d_in[3];
    const float* e_b2     = (const float*)d_in[4];
    const float* e_w3     = (const float*)d_in[5];
    const float* e_b3     = (const float*)d_in[6];
    const float* e_r1a    = (const float*)d_in[7];
    const float* e_r1b    = (const float*)d_in[8];
    const float* e_r2a    = (const float*)d_in[9];
    const float* e_r2b    = (const float*)d_in[10];
    const float* pre_w    = (const float*)d_in[11];
    const float* pre_b    = (const float*)d_in[12];
    const float* codebook = (const float*)d_in[13];
    const float* d_w1     = (const float*)d_in[14];
    const float* d_b1     = (const float*)d_in[15];
    const float* d_r1a    = (const float*)d_in[16];
    const float* d_r1b    = (const float*)d_in[17];
    const float* d_r2a    = (const float*)d_in[18];
    const float* d_r2b    = (const float*)d_in[19];
    const float* dt_w1    = (const float*)d_in[20];
    const float* dt_b1    = (const float*)d_in[21];
    const float* dt_w2    = (const float*)d_in[22];
    const float* dt_b2    = (const float*)d_in[23];
    float* out = (float*)d_out;

    // ---- workspace layout (floats) ----
    float* ws  = (float*)d_ws;
    float* h1g = ws;                    // 8,388,608  (h1; later reused as g)
    float* Bb  = h1g + 8388608;         // 4,194,304
    float* C   = Bb + 4194304;          // 4,194,304
    float* D   = C + 4194304;           // 1,048,576 (res 3x3 out; VQ scratch)
    float* E   = D + 1048576;           // 2,097,152  z
    float* F   = E + 2097152;           // 2,097,152  qc
    float* st  = F + 2097152;           // 1024
    unsigned short* wp = (unsigned short*)(st + 1024);

    // VQ scratch aliases D (dead during VQ)
    float* pdist = D;                       // 262144
    int*   pidx  = (int*)(D + 262144);      // 262144
    float* ccsq  = D + 524288;              // 512

    // ---- weight packing descriptors ----
    PackArgs pa;
    int np = 0, wpo = 0;
    auto addpack = [&](const float* src, int N, int Npad, int CIN, int KH, int KW,
                       int K, int Kpad, int mode, int py, int px, int split) -> int {
        pa.d[np].src = src; pa.d[np].dstoff = (unsigned long long)wpo;
        pa.d[np].Npad = Npad; pa.d[np].N = N; pa.d[np].CIN = CIN;
        pa.d[np].KH = KH; pa.d[np].KW = KW; pa.d[np].K = K; pa.d[np].Kpad = Kpad;
        pa.d[np].mode = mode; pa.d[np].py = py; pa.d[np].px = px; pa.d[np].split = split;
        ++np; int off = wpo; wpo += Npad * Kpad * (split ? 2 : 1); return off;
    };
    int P_E1  = addpack(e_w1, 64, 64, 3, 4, 4, 48, 64, 0, 0, 0, 1);
    int P_E2  = addpack(e_w2, 128, 128, 64, 4, 4, 1024, 1024, 0, 0, 0, 1);
    int P_E3  = addpack(e_w3, 128, 128, 128, 3, 3, 1152, 1152, 0, 0, 0, 1);
    int P_R1A = addpack(e_r1a, 32, 32, 128, 3, 3, 1152, 1152, 0, 0, 0, 1);
    int P_R1B = addpack(e_r1b, 128, 128, 32, 1, 1, 32, 32, 0, 0, 0, 1);
    int P_R2A = addpack(e_r2a, 32, 32, 128, 3, 3, 1152, 1152, 0, 0, 0, 1);
    int P_R2B = addpack(e_r2b, 128, 128, 32, 1, 1, 32, 32, 0, 0, 0, 1);
    int P_PRE = addpack(pre_w, 64, 64, 128, 1, 1, 128, 128, 0, 0, 0, 1);
    int P_D1  = addpack(d_w1, 128, 128, 64, 3, 3, 576, 576, 0, 0, 0, 0);
    int P_DR1A = addpack(d_r1a, 32, 32, 128, 3, 3, 1152, 1152, 0, 0, 0, 0);
    int P_DR1B = addpack(d_r1b, 128, 128, 32, 1, 1, 32, 32, 0, 0, 0, 0);
    int P_DR2A = addpack(d_r2a, 32, 32, 128, 3, 3, 1152, 1152, 0, 0, 0, 0);
    int P_DR2B = addpack(d_r2b, 128, 128, 32, 1, 1, 32, 32, 0, 0, 0, 0);
    int P_DT1[4], P_DT2[4];
    for (int p = 0; p < 4; ++p)
        P_DT1[p] = addpack(dt_w1, 64, 64, 128, 4, 4, 512, 512, 1, p >> 1, p & 1, 0);
    for (int p = 0; p < 4; ++p)
        P_DT2[p] = addpack(dt_w2, 3, 16, 64, 4, 4, 256, 256, 1, p >> 1, p & 1, 0);

    wpack_all<<<dim3(576, 21), 256, 0, stream>>>(pa, wp);
    hipMemsetAsync(st, 0, 513 * sizeof(float), stream);

    // ----- encoder (split precision) -----
    conv_gemm<3,4,4,2,false,true, 64,4,1, true,false,true,false><<<dim3(1024),256,0,stream>>>(
        x, wp + P_E1, e_b1, h1g, nullptr, 64, 4096, 64, 128,128,64, 1,1, 0,0,0, 64ull*64);
    conv_gemm<64,4,4,2,false,true, 128,2,2, true,false,true,false><<<dim3(256),256,0,stream>>>(
        h1g, wp + P_E2, e_b2, Bb, nullptr, 1024, 1024, 128, 64,64,32, 1,1, 0,0,0, 128ull*1024);
    conv_gemm<128,3,3,1,false,true, 128,2,2, true,false,false,false><<<dim3(256),256,0,stream>>>(
        Bb, wp + P_E3, e_b3, C, nullptr, 1152, 1024, 128, 32,32,32, 1,1, 0,0,0, 128ull*1152);
    conv_gemm<128,3,3,1,true,true, 32,4,1, false,false,false,false><<<dim3(256),256,0,stream>>>(
        C, wp + P_R1A, nullptr, D, nullptr, 1152, 1024, 32, 32,32,32, 1,1, 0,0,0, 32ull*1152);
    conv_gemm<32,1,1,1,true,true, 128,2,2, false,true,false,false><<<dim3(256),256,0,stream>>>(
        D, wp + P_R1B, nullptr, C, C, 32, 1024, 128, 32,32,32, 0,0, 0,0,0, 128ull*32);
    conv_gemm<128,3,3,1,true,true, 32,4,1, false,false,false,false><<<dim3(256),256,0,stream>>>(
        C, wp + P_R2A, nullptr, D, nullptr, 1152, 1024, 32, 32,32,32, 1,1, 0,0,0, 32ull*1152);
    conv_gemm<32,1,1,1,true,true, 128,2,2, false,true,false,false><<<dim3(256),256,0,stream>>>(
        D, wp + P_R2B, nullptr, C, C, 32, 1024, 128, 32,32,32, 0,0, 0,0,0, 128ull*32);
    conv_gemm<128,1,1,1,true,true, 64,4,1, true,false,false,false><<<dim3(256),256,0,stream>>>(
        C, wp + P_PRE, pre_b, E, nullptr, 128, 1024, 64, 32,32,32, 0,0, 0,0,0, 64ull*128);

    // ----- vector quantizer -----
    vq_sq<<<dim3(2), 256, 0, stream>>>(codebook, ccsq);
    vq_scan<<<dim3(128, 8), 256, 0, stream>>>(E, codebook, ccsq, pdist, pidx);
    vq_reduce<<<dim3(512), 256, 0, stream>>>(E, codebook, pdist, pidx, F, st, st + 512);
    vq_finalize<<<dim3(1), 512, 0, stream>>>(st, st + 512, out, out + 1572865);

    // ----- decoder (plain bf16) -----
    conv_gemm<64,3,3,1,false,false, 128,2,2, true,false,false,false><<<dim3(256),256,0,stream>>>(
        F, wp + P_D1, d_b1, Bb, nullptr, 576, 1024, 128, 32,32,32, 1,1, 0,0,0, 0ull);
    conv_gemm<128,3,3,1,true,false, 32,4,1, false,false,false,false><<<dim3(256),256,0,stream>>>(
        Bb, wp + P_DR1A, nullptr, D, nullptr, 1152, 1024, 32, 32,32,32, 1,1, 0,0,0, 0ull);
    conv_gemm<32,1,1,1,true,false, 128,2,2, false,true,false,false><<<dim3(256),256,0,stream>>>(
        D, wp + P_DR1B, nullptr, Bb, Bb, 32, 1024, 128, 32,32,32, 0,0, 0,0,0, 0ull);
    conv_gemm<128,3,3,1,true,false, 32,4,1, false,false,false,false><<<dim3(256),256,0,stream>>>(
        Bb, wp + P_DR2A, nullptr, D, nullptr, 1152, 1024, 32, 32,32,32, 1,1, 0,0,0, 0ull);
    conv_gemm<32,1,1,1,true,false, 128,2,2, false,true,false,false><<<dim3(256),256,0,stream>>>(
        D, wp + P_DR2B, nullptr, Bb, Bb, 32, 1024, 128, 32,32,32, 0,0, 0,0,0, 0ull);

    for (int p = 0; p < 4; ++p) {
        conv_gemm<128,2,2,1,true,false, 64,4,1, true,false,true,true><<<dim3(256),256,0,stream>>>(
            Bb, wp + P_DT1[p], dt_b1, h1g, nullptr, 512, 1024, 64, 32,32,32,
            1 - (p >> 1), 1 - (p & 1), 32, p >> 1, p & 1, 0ull);
    }
    for (int p = 0; p < 4; ++p) {
        conv_gemm<64,2,2,1,false,false, 16,4,1, true,false,false,true><<<dim3(1024),256,0,stream>>>(
            h1g, wp + P_DT2[p], dt_b2, out + 1, nullptr, 256, 4096, 3, 64,64,64,
            1 - (p >> 1), 1 - (p & 1), 64, p >> 1, p & 1, 0ull);
    }
}

// Round 6
// 894.740 us; speedup vs baseline: 9.1994x; 1.5775x over previous
//
#include <hip/hip_runtime.h>

// ---------------------------------------------------------------------------
// VQ-VAE forward, round 6:
//  - conv_gemm: BM=64 + N-tiling (grid 512-2048, 4 blocks/CU), fast-path
//    staging for CIN%32==0 (wave-uniform tap per K-step), b128 LDS writes.
//  - VQ: hist atomics removed from reduce (single-block LDS histogram),
//    reduce at 1024 blocks.
//  - split-bf16 (hi+lo) encoder, plain bf16 decoder (unchanged numerics).
// ---------------------------------------------------------------------------

typedef short short8 __attribute__((ext_vector_type(8)));
typedef float f32x4 __attribute__((ext_vector_type(4)));

__device__ __forceinline__ unsigned short f2bf(float f) {
    unsigned u = __builtin_bit_cast(unsigned, f);
    u += 0x7fffu + ((u >> 16) & 1u);      // RNE
    return (unsigned short)(u >> 16);
}
__device__ __forceinline__ float bf2f(unsigned short b) {
    unsigned u = ((unsigned)b) << 16;
    return __builtin_bit_cast(float, u);
}
__device__ __forceinline__ void gload_lds16(const void* g, void* l) {
    __builtin_amdgcn_global_load_lds(
        (const __attribute__((address_space(1))) void*)g,
        (__attribute__((address_space(3))) void*)l, 16, 0, 0);
}

// ---------------------------------------------------------------------------
// Fused conv GEMM, BM=64. A built on the fly (fp32 NCHW -> bf16 hi(+lo) LDS),
// W pre-packed bf16 [Npad][Kpad] (hi plane, then lo plane at wloff).
// Grid: (M/64) * nbn blocks; nt = bid % nbn selects the BN-column tile.
// FAST: CIN%32==0 && K%32==0 -> tap wave-uniform per K-step.
// ---------------------------------------------------------------------------
template<int CIN, int KH, int KW, int S, bool PRERELU, bool SPLIT,
         int BN, int WM_, int WN_, bool BIAS, bool RES, bool RELU, bool SCATTER,
         bool FAST>
__global__ __launch_bounds__(256, 4) void conv_gemm(
    const float* __restrict__ in, const unsigned short* __restrict__ W,
    const float* __restrict__ bias, float* __restrict__ outp,
    const float* __restrict__ resp,
    int Kpad, int HWout, int Cout, int Hin, int Win, int Wout,
    int pady, int padx, int Ws, int py, int px,
    unsigned long long wloff, int nbn)
{
    constexpr int BM = 64;
    constexpr int K = CIN * KH * KW;
    constexpr int ASTR = 40;                    // shorts; 80B rows
    constexpr int MI = BM / WM_ / 16;
    constexpr int NI = BN / WN_ / 16;
    constexpr bool PIX1 = (KH == 1 && KW == 1 && S == 1);
    __shared__ __align__(16) unsigned short lsA[(SPLIT ? 2 : 1) * BM * ASTR];
    __shared__ __align__(16) unsigned short lsB[(SPLIT ? 2 : 1) * BN * 32];

    int t = threadIdx.x;
    int l = t & 63;
    int w = t >> 6;
    int bid = blockIdx.x;
    int nt = bid % nbn;
    int tm = (bid / nbn) * BM;
    int ncol0 = nt * BN;
    const unsigned short* Wt = W + (size_t)ncol0 * Kpad;
    int wm0 = (w / WN_) * (BM / WM_);
    int wn0 = (w % WN_) * (BN / WN_);

    // staging coords: thread -> (m row, 8-short k segment)
    int m_l = t & 63;
    int kseg = t >> 6;                          // 0..3
    int ms = tm + m_l;
    int bs = ms / HWout;
    int rems = ms - bs * HWout;
    int oys = rems / Wout;
    int oxs = rems - oys * Wout;
    int iy0 = oys * S - pady;
    int ix0 = oxs * S - padx;
    const float* ibase = in + (size_t)bs * CIN * Hin * Win;
    const int HinWin = Hin * Win;

    f32x4 acc[MI][NI] = {};
    const int e0 = t * 8;

    for (int k0 = 0; k0 < Kpad; k0 += 32) {
        // ---- W stage (async global->LDS, 16B/lane) ----
        if (e0 < BN * 32) {
            size_t gb = (size_t)(e0 >> 5) * Kpad + k0 + (e0 & 31);
            gload_lds16(Wt + gb, &lsB[e0]);
            if (SPLIT) gload_lds16(Wt + wloff + gb, &lsB[BN * 32 + e0]);
        }
        // ---- A stage ----
        float vv[8];
        if (FAST) {
            int tap = k0 / CIN;                 // wave-uniform
            int c0 = k0 - tap * CIN + kseg * 8;
            int ky = tap / KW, kx = tap - ky * KW;
            int iy = iy0 + ky, ix = ix0 + kx;
            bool ok = PIX1 ||
                ((unsigned)iy < (unsigned)Hin && (unsigned)ix < (unsigned)Win);
            const float* p = ibase + (size_t)c0 * HinWin + (size_t)iy * Win + ix;
            #pragma unroll
            for (int j = 0; j < 8; ++j) vv[j] = ok ? p[(size_t)j * HinWin] : 0.0f;
        } else {
            #pragma unroll
            for (int j = 0; j < 8; ++j) {
                int k = k0 + kseg * 8 + j;
                float v = 0.0f;
                if ((K % 32 == 0) || k < K) {
                    int tap = k / CIN, c = k - tap * CIN;
                    int ky = tap / KW, kx = tap - ky * KW;
                    int iy = iy0 + ky, ix = ix0 + kx;
                    if (PIX1 ||
                        ((unsigned)iy < (unsigned)Hin && (unsigned)ix < (unsigned)Win))
                        v = ibase[((size_t)c * Hin + iy) * Win + ix];
                }
                vv[j] = v;
            }
        }
        short8 hi, lo;
        #pragma unroll
        for (int j = 0; j < 8; ++j) {
            float v = PRERELU ? fmaxf(vv[j], 0.0f) : vv[j];
            unsigned short hb = f2bf(v);
            hi[j] = (short)hb;
            if (SPLIT) lo[j] = (short)f2bf(v - bf2f(hb));
        }
        *(short8*)&lsA[m_l * ASTR + kseg * 8] = hi;
        if (SPLIT) *(short8*)&lsA[BM * ASTR + m_l * ASTR + kseg * 8] = lo;
        __syncthreads();
        // ---- fragments + MFMA ----
        short8 ah[MI], bh[NI];
        #pragma unroll
        for (int mi = 0; mi < MI; ++mi)
            ah[mi] = *(const short8*)&lsA[(wm0 + mi * 16 + (l & 15)) * ASTR + (l >> 4) * 8];
        #pragma unroll
        for (int ni = 0; ni < NI; ++ni)
            bh[ni] = *(const short8*)&lsB[(wn0 + ni * 16 + (l & 15)) * 32 + (l >> 4) * 8];
        if (SPLIT) {
            short8 al[MI], bl[NI];
            #pragma unroll
            for (int mi = 0; mi < MI; ++mi)
                al[mi] = *(const short8*)&lsA[BM * ASTR + (wm0 + mi * 16 + (l & 15)) * ASTR + (l >> 4) * 8];
            #pragma unroll
            for (int ni = 0; ni < NI; ++ni)
                bl[ni] = *(const short8*)&lsB[BN * 32 + (wn0 + ni * 16 + (l & 15)) * 32 + (l >> 4) * 8];
            #pragma unroll
            for (int mi = 0; mi < MI; ++mi)
                #pragma unroll
                for (int ni = 0; ni < NI; ++ni) {
                    acc[mi][ni] = __builtin_amdgcn_mfma_f32_16x16x32_bf16(ah[mi], bh[ni], acc[mi][ni], 0, 0, 0);
                    acc[mi][ni] = __builtin_amdgcn_mfma_f32_16x16x32_bf16(ah[mi], bl[ni], acc[mi][ni], 0, 0, 0);
                    acc[mi][ni] = __builtin_amdgcn_mfma_f32_16x16x32_bf16(al[mi], bh[ni], acc[mi][ni], 0, 0, 0);
                }
        } else {
            #pragma unroll
            for (int mi = 0; mi < MI; ++mi)
                #pragma unroll
                for (int ni = 0; ni < NI; ++ni)
                    acc[mi][ni] = __builtin_amdgcn_mfma_f32_16x16x32_bf16(ah[mi], bh[ni], acc[mi][ni], 0, 0, 0);
        }
        __syncthreads();
    }
    // ---- epilogue ----
    #pragma unroll
    for (int mi = 0; mi < MI; ++mi) {
        #pragma unroll
        for (int ni = 0; ni < NI; ++ni) {
            int n = ncol0 + wn0 + ni * 16 + (l & 15);
            if (n >= Cout) continue;
            float bv = BIAS ? bias[n] : 0.0f;
            #pragma unroll
            for (int j = 0; j < 4; ++j) {
                int m = tm + wm0 + mi * 16 + (l >> 4) * 4 + j;
                float v = acc[mi][ni][j] + bv;
                if (RELU) v = fmaxf(v, 0.0f);
                size_t idx;
                int b = m / HWout;
                int rem = m - b * HWout;
                if (SCATTER) {
                    int y = rem / Ws, x = rem - y * Ws;
                    idx = (size_t)(b * Cout + n) * (4 * HWout)
                        + (size_t)(2 * y + py) * (2 * Ws) + (2 * x + px);
                } else {
                    idx = (size_t)(b * Cout + n) * HWout + rem;
                }
                if (RES) v += resp[idx];
                outp[idx] = v;
            }
        }
    }
}

// ---------------------------------------------------------------------------
// Weight packing (unchanged)
// ---------------------------------------------------------------------------
struct PackDesc {
    const float* src; unsigned long long dstoff;
    int Npad, N, CIN, KH, KW, K, Kpad, mode, py, px, split;
};
struct PackArgs { PackDesc d[21]; };

__global__ __launch_bounds__(256) void wpack_all(PackArgs pa, unsigned short* __restrict__ wp)
{
    PackDesc d = pa.d[blockIdx.y];
    int gid = blockIdx.x * 256 + threadIdx.x;
    int tot = d.Npad * d.Kpad;
    if (gid >= tot) return;
    int n = gid / d.Kpad;
    int k = gid - n * d.Kpad;
    float v = 0.0f;
    if (n < d.N && k < d.K) {
        int tap = k / d.CIN, c = k - tap * d.CIN;
        int ky, kx;
        if (d.mode == 0) { ky = tap / d.KW; kx = tap - ky * d.KW; }
        else { int ty = tap >> 1, tx = tap & 1; ky = d.py + 2 * ty; kx = d.px + 2 * tx; }
        v = d.src[((size_t)(n * d.CIN + c) * d.KH + ky) * d.KW + kx];
    }
    unsigned short hb = f2bf(v);
    wp[d.dstoff + gid] = hb;
    if (d.split) wp[d.dstoff + tot + gid] = f2bf(v - bf2f(hb));
}

// ---------------------------------------------------------------------------
// VQ
// ---------------------------------------------------------------------------
__global__ __launch_bounds__(256) void vq_sq(
    const float* __restrict__ cb, float* __restrict__ ccsq)
{
    int k = blockIdx.x * 256 + threadIdx.x;   // 0..511
    const float* c = cb + (size_t)k * 64;
    float a0 = 0.f, a1 = 0.f;
    #pragma unroll
    for (int d = 0; d < 64; d += 2) {
        a0 = fmaf(c[d], c[d], a0);
        a1 = fmaf(c[d + 1], c[d + 1], a1);
    }
    ccsq[k] = a0 + a1;
}

// grid (128, 8): 64-code chunks. score = ccsq[k] - 2*dot(z,c).
__global__ __launch_bounds__(256) void vq_scan(
    const float* __restrict__ z, const float* __restrict__ cb,
    const float* __restrict__ ccsq,
    float* __restrict__ pdist, int* __restrict__ pidx)
{
    const int HW = 1024;
    int n = blockIdx.x * 256 + threadIdx.x;   // 0..32767
    int chunk = blockIdx.y;                    // 0..7
    int base = chunk * 64;
    int b = n >> 10;
    int p = n & 1023;
    const float* zp = z + (size_t)b * 64 * HW + p;
    float zv[64];
    #pragma unroll
    for (int d = 0; d < 64; ++d) zv[d] = zp[(size_t)d * HW];

    float best = 3.402823e38f;
    int bi = base;
    for (int kk = 0; kk < 64; kk += 2) {
        const float* c0 = cb + (size_t)(base + kk) * 64;
        float a0 = 0.f, a1 = 0.f, b0 = 0.f, b1 = 0.f;
        #pragma unroll
        for (int d = 0; d < 64; d += 2) {
            a0 = fmaf(zv[d],     c0[d],          a0);
            a1 = fmaf(zv[d + 1], c0[d + 1],      a1);
            b0 = fmaf(zv[d],     c0[64 + d],     b0);
            b1 = fmaf(zv[d + 1], c0[64 + d + 1], b1);
        }
        float s0 = ccsq[base + kk]     - 2.0f * (a0 + a1);
        float s1 = ccsq[base + kk + 1] - 2.0f * (b0 + b1);
        if (s0 < best) { best = s0; bi = base + kk; }
        if (s1 < best) { best = s1; bi = base + kk + 1; }
    }
    pdist[(size_t)chunk * 32768 + n] = best;
    pidx [(size_t)chunk * 32768 + n] = bi;
}

// reduce: 1024 blocks; block = 32 n x 8 d-groups of 8. No hist atomics —
// writes winning idx to idxbuf; q gather + exact fp32 SSE (1 atomic/block).
__global__ __launch_bounds__(256) void vq_reduce(
    const float* __restrict__ z, const float* __restrict__ cb,
    const float* __restrict__ pdist, const int* __restrict__ pidx,
    float* __restrict__ qc, int* __restrict__ idxbuf, float* __restrict__ sse)
{
    const int HW = 1024;
    int nl = threadIdx.x & 31;
    int dg = threadIdx.x >> 5;                 // 0..7
    int n = blockIdx.x * 32 + nl;
    float best = pdist[n];
    int bi = pidx[n];
    #pragma unroll
    for (int ch = 1; ch < 8; ++ch) {
        float dv = pdist[(size_t)ch * 32768 + n];
        int iv = pidx[(size_t)ch * 32768 + n];
        if (dv < best) { best = dv; bi = iv; }   // strict <: earliest chunk wins
    }
    if (dg == 0) idxbuf[n] = bi;
    int b = n >> 10;
    int p = n & 1023;
    const float* zp = z + (size_t)b * 64 * HW + p;
    float* qp = qc + (size_t)b * 64 * HW + p;
    const float* c = cb + (size_t)bi * 64;
    float s = 0.f;
    #pragma unroll
    for (int j = 0; j < 8; ++j) {
        int d = dg * 8 + j;
        float q = c[d];
        qp[(size_t)d * HW] = q;
        float df = q - zp[(size_t)d * HW];
        s = fmaf(df, df, s);
    }
    #pragma unroll
    for (int off = 32; off > 0; off >>= 1) s += __shfl_down(s, off, 64);
    __shared__ float red[4];
    if ((threadIdx.x & 63) == 0) red[threadIdx.x >> 6] = s;
    __syncthreads();
    if (threadIdx.x == 0) atomicAdd(sse, red[0] + red[1] + red[2] + red[3]);
}

// single-block LDS histogram of 32768 indices into 512 bins (no global atomics)
__global__ __launch_bounds__(1024) void vq_hist(
    const int* __restrict__ idxbuf, float* __restrict__ hist)
{
    __shared__ int lh[512];
    int t = threadIdx.x;
    if (t < 512) lh[t] = 0;
    __syncthreads();
    #pragma unroll
    for (int j = 0; j < 32; ++j)
        atomicAdd(&lh[idxbuf[j * 1024 + t]], 1);
    __syncthreads();
    if (t < 512) hist[t] = (float)lh[t];
}

__global__ __launch_bounds__(512) void vq_finalize(
    const float* __restrict__ hist, const float* __restrict__ sse,
    float* __restrict__ out_loss, float* __restrict__ out_ppl)
{
    __shared__ float red[512];
    int t = threadIdx.x;
    float p = hist[t] * (1.0f / 32768.0f);
    red[t] = p * logf(p + 1e-10f);
    __syncthreads();
    for (int s = 256; s > 0; s >>= 1) {
        if (t < s) red[t] += red[t + s];
        __syncthreads();
    }
    if (t == 0) {
        *out_ppl = expf(-red[0]);
        *out_loss = 1.25f * (*sse) * (1.0f / 2097152.0f);
    }
}

// ---------------------------------------------------------------------------
extern "C" void kernel_launch(void* const* d_in, const int* in_sizes, int n_in,
                              void* d_out, int out_size, void* d_ws, size_t ws_size,
                              hipStream_t stream)
{
    const float* x        = (const float*)d_in[0];
    const float* e_w1     = (const float*)d_in[1];
    const float* e_b1     = (const float*)d_in[2];
    const float* e_w2     = (const float*)d_in[3];
    const float* e_b2     = (const float*)d_in[4];
    const float* e_w3     = (const float*)d_in[5];
    const float* e_b3     = (const float*)d_in[6];
    const float* e_r1a    = (const float*)d_in[7];
    const float* e_r1b    = (const float*)d_in[8];
    const float* e_r2a    = (const float*)d_in[9];
    const float* e_r2b    = (const float*)d_in[10];
    const float* pre_w    = (const float*)d_in[11];
    const float* pre_b    = (const float*)d_in[12];
    const float* codebook = (const float*)d_in[13];
    const float* d_w1     = (const float*)d_in[14];
    const float* d_b1     = (const float*)d_in[15];
    const float* d_r1a    = (const float*)d_in[16];
    const float* d_r1b    = (const float*)d_in[17];
    const float* d_r2a    = (const float*)d_in[18];
    const float* d_r2b    = (const float*)d_in[19];
    const float* dt_w1    = (const float*)d_in[20];
    const float* dt_b1    = (const float*)d_in[21];
    const float* dt_w2    = (const float*)d_in[22];
    const float* dt_b2    = (const float*)d_in[23];
    float* out = (float*)d_out;

    // ---- workspace layout (floats) ----
    float* ws  = (float*)d_ws;
    float* h1g = ws;                    // 8,388,608  (h1; later reused as g)
    float* Bb  = h1g + 8388608;         // 4,194,304
    float* C   = Bb + 4194304;          // 4,194,304
    float* D   = C + 4194304;           // 1,048,576 (res 3x3 out; VQ scratch)
    float* E   = D + 1048576;           // 2,097,152  z
    float* F   = E + 2097152;           // 2,097,152  qc
    float* st  = F + 2097152;           // 1024 (hist[512], sse at +512)
    unsigned short* wp = (unsigned short*)(st + 1024);

    // VQ scratch aliases D (dead during VQ)
    float* pdist  = D;                       // 262144
    int*   pidx   = (int*)(D + 262144);      // 262144
    int*   idxbuf = (int*)(D + 524288);      // 32768
    float* ccsq   = D + 557056;              // 512

    // ---- weight packing descriptors ----
    PackArgs pa;
    int np = 0, wpo = 0;
    auto addpack = [&](const float* src, int N, int Npad, int CIN, int KH, int KW,
                       int K, int Kpad, int mode, int py, int px, int split) -> int {
        pa.d[np].src = src; pa.d[np].dstoff = (unsigned long long)wpo;
        pa.d[np].Npad = Npad; pa.d[np].N = N; pa.d[np].CIN = CIN;
        pa.d[np].KH = KH; pa.d[np].KW = KW; pa.d[np].K = K; pa.d[np].Kpad = Kpad;
        pa.d[np].mode = mode; pa.d[np].py = py; pa.d[np].px = px; pa.d[np].split = split;
        ++np; int off = wpo; wpo += Npad * Kpad * (split ? 2 : 1); return off;
    };
    int P_E1  = addpack(e_w1, 64, 64, 3, 4, 4, 48, 64, 0, 0, 0, 1);
    int P_E2  = addpack(e_w2, 128, 128, 64, 4, 4, 1024, 1024, 0, 0, 0, 1);
    int P_E3  = addpack(e_w3, 128, 128, 128, 3, 3, 1152, 1152, 0, 0, 0, 1);
    int P_R1A = addpack(e_r1a, 32, 32, 128, 3, 3, 1152, 1152, 0, 0, 0, 1);
    int P_R1B = addpack(e_r1b, 128, 128, 32, 1, 1, 32, 32, 0, 0, 0, 1);
    int P_R2A = addpack(e_r2a, 32, 32, 128, 3, 3, 1152, 1152, 0, 0, 0, 1);
    int P_R2B = addpack(e_r2b, 128, 128, 32, 1, 1, 32, 32, 0, 0, 0, 1);
    int P_PRE = addpack(pre_w, 64, 64, 128, 1, 1, 128, 128, 0, 0, 0, 1);
    int P_D1  = addpack(d_w1, 128, 128, 64, 3, 3, 576, 576, 0, 0, 0, 0);
    int P_DR1A = addpack(d_r1a, 32, 32, 128, 3, 3, 1152, 1152, 0, 0, 0, 0);
    int P_DR1B = addpack(d_r1b, 128, 128, 32, 1, 1, 32, 32, 0, 0, 0, 0);
    int P_DR2A = addpack(d_r2a, 32, 32, 128, 3, 3, 1152, 1152, 0, 0, 0, 0);
    int P_DR2B = addpack(d_r2b, 128, 128, 32, 1, 1, 32, 32, 0, 0, 0, 0);
    int P_DT1[4], P_DT2[4];
    for (int p = 0; p < 4; ++p)
        P_DT1[p] = addpack(dt_w1, 64, 64, 128, 4, 4, 512, 512, 1, p >> 1, p & 1, 0);
    for (int p = 0; p < 4; ++p)
        P_DT2[p] = addpack(dt_w2, 3, 16, 64, 4, 4, 256, 256, 1, p >> 1, p & 1, 0);

    wpack_all<<<dim3(576, 21), 256, 0, stream>>>(pa, wp);
    hipMemsetAsync(st, 0, 513 * sizeof(float), stream);

    // ----- encoder (split precision) -----
    conv_gemm<3,4,4,2,false,true, 64,2,2, true,false,true,false, false>
        <<<dim3(2048),256,0,stream>>>(x, wp + P_E1, e_b1, h1g, nullptr,
        64, 4096, 64, 128,128,64, 1,1, 0,0,0, 64ull*64, 1);
    conv_gemm<64,4,4,2,false,true, 64,2,2, true,false,true,false, true>
        <<<dim3(1024),256,0,stream>>>(h1g, wp + P_E2, e_b2, Bb, nullptr,
        1024, 1024, 128, 64,64,32, 1,1, 0,0,0, 128ull*1024, 2);
    conv_gemm<128,3,3,1,false,true, 64,2,2, true,false,false,false, true>
        <<<dim3(1024),256,0,stream>>>(Bb, wp + P_E3, e_b3, C, nullptr,
        1152, 1024, 128, 32,32,32, 1,1, 0,0,0, 128ull*1152, 2);
    conv_gemm<128,3,3,1,true,true, 32,4,1, false,false,false,false, true>
        <<<dim3(512),256,0,stream>>>(C, wp + P_R1A, nullptr, D, nullptr,
        1152, 1024, 32, 32,32,32, 1,1, 0,0,0, 32ull*1152, 1);
    conv_gemm<32,1,1,1,true,true, 64,2,2, false,true,false,false, true>
        <<<dim3(1024),256,0,stream>>>(D, wp + P_R1B, nullptr, C, C,
        32, 1024, 128, 32,32,32, 0,0, 0,0,0, 128ull*32, 2);
    conv_gemm<128,3,3,1,true,true, 32,4,1, false,false,false,false, true>
        <<<dim3(512),256,0,stream>>>(C, wp + P_R2A, nullptr, D, nullptr,
        1152, 1024, 32, 32,32,32, 1,1, 0,0,0, 32ull*1152, 1);
    conv_gemm<32,1,1,1,true,true, 64,2,2, false,true,false,false, true>
        <<<dim3(1024),256,0,stream>>>(D, wp + P_R2B, nullptr, C, C,
        32, 1024, 128, 32,32,32, 0,0, 0,0,0, 128ull*32, 2);
    conv_gemm<128,1,1,1,true,true, 64,2,2, true,false,false,false, true>
        <<<dim3(512),256,0,stream>>>(C, wp + P_PRE, pre_b, E, nullptr,
        128, 1024, 64, 32,32,32, 0,0, 0,0,0, 64ull*128, 1);

    // ----- vector quantizer -----
    vq_sq<<<dim3(2), 256, 0, stream>>>(codebook, ccsq);
    vq_scan<<<dim3(128, 8), 256, 0, stream>>>(E, codebook, ccsq, pdist, pidx);
    vq_reduce<<<dim3(1024), 256, 0, stream>>>(E, codebook, pdist, pidx, F, idxbuf, st + 512);
    vq_hist<<<dim3(1), 1024, 0, stream>>>(idxbuf, st);
    vq_finalize<<<dim3(1), 512, 0, stream>>>(st, st + 512, out, out + 1572865);

    // ----- decoder (plain bf16) -----
    conv_gemm<64,3,3,1,false,false, 64,2,2, true,false,false,false, true>
        <<<dim3(1024),256,0,stream>>>(F, wp + P_D1, d_b1, Bb, nullptr,
        576, 1024, 128, 32,32,32, 1,1, 0,0,0, 0ull, 2);
    conv_gemm<128,3,3,1,true,false, 32,4,1, false,false,false,false, true>
        <<<dim3(512),256,0,stream>>>(Bb, wp + P_DR1A, nullptr, D, nullptr,
        1152, 1024, 32, 32,32,32, 1,1, 0,0,0, 0ull, 1);
    conv_gemm<32,1,1,1,true,false, 64,2,2, false,true,false,false, true>
        <<<dim3(1024),256,0,stream>>>(D, wp + P_DR1B, nullptr, Bb, Bb,
        32, 1024, 128, 32,32,32, 0,0, 0,0,0, 0ull, 2);
    conv_gemm<128,3,3,1,true,false, 32,4,1, false,false,false,false, true>
        <<<dim3(512),256,0,stream>>>(Bb, wp + P_DR2A, nullptr, D, nullptr,
        1152, 1024, 32, 32,32,32, 1,1, 0,0,0, 0ull, 1);
    conv_gemm<32,1,1,1,true,false, 64,2,2, false,true,false,false, true>
        <<<dim3(1024),256,0,stream>>>(D, wp + P_DR2B, nullptr, Bb, Bb,
        32, 1024, 128, 32,32,32, 0,0, 0,0,0, 0ull, 2);

    for (int p = 0; p < 4; ++p) {
        conv_gemm<128,2,2,1,true,false, 64,2,2, true,false,true,true, true>
            <<<dim3(512),256,0,stream>>>(Bb, wp + P_DT1[p], dt_b1, h1g, nullptr,
            512, 1024, 64, 32,32,32, 1 - (p >> 1), 1 - (p & 1), 32, p >> 1, p & 1, 0ull, 1);
    }
    for (int p = 0; p < 4; ++p) {
        conv_gemm<64,2,2,1,false,false, 16,4,1, true,false,false,true, true>
            <<<dim3(2048),256,0,stream>>>(h1g, wp + P_DT2[p], dt_b2, out + 1, nullptr,
            256, 4096, 3, 64,64,64, 1 - (p >> 1), 1 - (p & 1), 64, p >> 1, p & 1, 0ull, 1);
    }
}

// Round 10
// 595.049 us; speedup vs baseline: 13.8326x; 1.5036x over previous
//
#include <hip/hip_runtime.h>

// ---------------------------------------------------------------------------
// VQ-VAE forward, round 7 design (3rd resubmit; rounds 7-9 were infra
// failures: 2x GPU-acquisition timeout, 1x container failure — never ran).
// bf16-NHWC activation pipeline: all inter-layer activations stored as bf16
// NHWC planes (hi+lo split for encoder); conv A-staging is pure
// global_load_lds (no cvt, no ds_write). OOB taps read a shared zero page.
// ReLU/split moved to producer epilogues.
// ---------------------------------------------------------------------------

typedef short short8 __attribute__((ext_vector_type(8)));
typedef float f32x4 __attribute__((ext_vector_type(4)));

__device__ __forceinline__ unsigned short f2bf(float f) {
    unsigned u = __builtin_bit_cast(unsigned, f);
    u += 0x7fffu + ((u >> 16) & 1u);      // RNE
    return (unsigned short)(u >> 16);
}
__device__ __forceinline__ float bf2f(unsigned short b) {
    unsigned u = ((unsigned)b) << 16;
    return __builtin_bit_cast(float, u);
}
__device__ __forceinline__ void gload_lds16(const void* g, void* l) {
    __builtin_amdgcn_global_load_lds(
        (const __attribute__((address_space(1))) void*)g,
        (__attribute__((address_space(3))) void*)l, 16, 0, 0);
}

template<bool SPLIT, int MI, int NI, int ASTR, int BM, int BN>
__device__ __forceinline__ void mfma_step(
    const unsigned short* lsA, const unsigned short* lsB,
    f32x4* acc, int wm0, int wn0, int l)
{
    short8 ah[MI], bh[NI];
    #pragma unroll
    for (int mi = 0; mi < MI; ++mi)
        ah[mi] = *(const short8*)&lsA[(wm0 + mi*16 + (l&15))*ASTR + (l>>4)*8];
    #pragma unroll
    for (int ni = 0; ni < NI; ++ni)
        bh[ni] = *(const short8*)&lsB[(wn0 + ni*16 + (l&15))*32 + (l>>4)*8];
    if (SPLIT) {
        short8 al[MI], bl[NI];
        #pragma unroll
        for (int mi = 0; mi < MI; ++mi)
            al[mi] = *(const short8*)&lsA[BM*ASTR + (wm0 + mi*16 + (l&15))*ASTR + (l>>4)*8];
        #pragma unroll
        for (int ni = 0; ni < NI; ++ni)
            bl[ni] = *(const short8*)&lsB[BN*32 + (wn0 + ni*16 + (l&15))*32 + (l>>4)*8];
        #pragma unroll
        for (int mi = 0; mi < MI; ++mi)
            #pragma unroll
            for (int ni = 0; ni < NI; ++ni) {
                acc[mi*NI+ni] = __builtin_amdgcn_mfma_f32_16x16x32_bf16(ah[mi], bh[ni], acc[mi*NI+ni], 0, 0, 0);
                acc[mi*NI+ni] = __builtin_amdgcn_mfma_f32_16x16x32_bf16(ah[mi], bl[ni], acc[mi*NI+ni], 0, 0, 0);
                acc[mi*NI+ni] = __builtin_amdgcn_mfma_f32_16x16x32_bf16(al[mi], bh[ni], acc[mi*NI+ni], 0, 0, 0);
            }
    } else {
        #pragma unroll
        for (int mi = 0; mi < MI; ++mi)
            #pragma unroll
            for (int ni = 0; ni < NI; ++ni)
                acc[mi*NI+ni] = __builtin_amdgcn_mfma_f32_16x16x32_bf16(ah[mi], bh[ni], acc[mi*NI+ni], 0, 0, 0);
    }
}

// ---------------------------------------------------------------------------
// Fused conv GEMM. A from bf16 NHWC planes via global_load_lds (FP32IN=false)
// or from fp32 NCHW via cvt path (E1 only). W pre-packed bf16 [Npad][KP].
// RESID: 0 none, 1 bf16 hi+lo, 2 bf16 single. DUAL: also write raw copy.
// OMODE: 0 bf16 NHWC, 1 fp32 NCHW, 2 fp32 NCHW scatter, 3 bf16 NHWC scatter.
// ---------------------------------------------------------------------------
template<int CIN, int KH, int KW, int S, bool FP32IN, bool SPLIT,
         int BN, int WM_, int WN_, bool BIAS, int RESID, bool RELU, bool DUAL, int OMODE>
__global__ __launch_bounds__(256, 4) void conv_gemm(
    const unsigned short* __restrict__ inH, const unsigned short* __restrict__ inL,
    const float* __restrict__ inF,
    const unsigned short* __restrict__ Wp, unsigned long long wloff,
    const float* __restrict__ bias,
    unsigned short* __restrict__ oH, unsigned short* __restrict__ oL,
    unsigned short* __restrict__ o2H, unsigned short* __restrict__ o2L,
    float* __restrict__ oF,
    const unsigned short* __restrict__ rH, const unsigned short* __restrict__ rL,
    const unsigned short* __restrict__ zpage,
    int Hin, int Win, int Wout, int HWout, int Cout, int pady, int padx,
    int py, int px, int nbn)
{
    constexpr int BM = 64;
    constexpr int K = CIN * KH * KW;
    constexpr int KP = ((K + 31) / 32) * 32;
    constexpr int TAPS = KH * KW;
    constexpr int ASTR = FP32IN ? 40 : 32;
    constexpr int MI = BM / WM_ / 16, NI = BN / WN_ / 16;
    constexpr bool PIX1 = (KH == 1 && KW == 1 && S == 1);
    __shared__ __align__(16) unsigned short lsA[(SPLIT ? 2 : 1) * BM * ASTR];
    __shared__ __align__(16) unsigned short lsB[(SPLIT ? 2 : 1) * BN * 32];

    int t = threadIdx.x, l = t & 63, w = t >> 6;
    int bid = blockIdx.x;
    int nt = bid % nbn;
    int tm = (bid / nbn) * BM;
    int ncol0 = nt * BN;
    const unsigned short* Wt = Wp + (size_t)ncol0 * KP;
    int wm0 = (w / WN_) * (BM / WM_);
    int wn0 = (w % WN_) * (BN / WN_);
    f32x4 acc[MI * NI] = {};
    const int e0 = t * 8;

    if (FP32IN) {
        int m_l = t & 63, kseg = t >> 6;
        int ms = tm + m_l;
        int bsv = ms / HWout; int remv = ms - bsv * HWout;
        int oys = remv / Wout, oxs = remv - (remv / Wout) * Wout;
        int iy0 = oys * S - pady, ix0 = oxs * S - padx;
        const float* ibase = inF + (size_t)bsv * CIN * Hin * Win;
        for (int k0 = 0; k0 < KP; k0 += 32) {
            if (e0 < BN * 32) {
                size_t gb = (size_t)(e0 >> 5) * KP + k0 + (e0 & 31);
                gload_lds16(Wt + gb, &lsB[e0]);
                if (SPLIT) gload_lds16(Wt + wloff + gb, &lsB[BN * 32 + e0]);
            }
            short8 hi, lo;
            #pragma unroll
            for (int j = 0; j < 8; ++j) {
                int k = k0 + kseg * 8 + j;
                float v = 0.f;
                if (k < K) {
                    int tap = k / CIN, c = k - tap * CIN;
                    int ky = tap / KW, kx = tap - (tap / KW) * KW;
                    int iy = iy0 + ky, ix = ix0 + kx;
                    if ((unsigned)iy < (unsigned)Hin && (unsigned)ix < (unsigned)Win)
                        v = ibase[((size_t)c * Hin + iy) * Win + ix];
                }
                unsigned short hb = f2bf(v);
                hi[j] = (short)hb;
                if (SPLIT) lo[j] = (short)f2bf(v - bf2f(hb));
            }
            *(short8*)&lsA[m_l * ASTR + kseg * 8] = hi;
            if (SPLIT) *(short8*)&lsA[BM * ASTR + m_l * ASTR + kseg * 8] = lo;
            __syncthreads();
            mfma_step<SPLIT, MI, NI, ASTR, BM, BN>(lsA, lsB, acc, wm0, wn0, l);
            __syncthreads();
        }
    } else {
        int mrow = t >> 2;
        int lane8 = (t & 3) * 8;
        int m = tm + mrow;
        int bsv = m / HWout; int remv = m - bsv * HWout;
        int oys = remv / Wout, oxs = remv - oys * Wout;
        int iy0 = oys * S - pady, ix0 = oxs * S - padx;
        #pragma unroll
        for (int tap = 0; tap < TAPS; ++tap) {
            int ky = tap / KW, kx = tap - (tap / KW) * KW;
            int iy = iy0 + ky, ix = ix0 + kx;
            bool ok = PIX1 || ((unsigned)iy < (unsigned)Hin && (unsigned)ix < (unsigned)Win);
            size_t pix = ((size_t)bsv * Hin + iy) * Win + ix;
            const unsigned short* phi = ok ? inH + pix * CIN + lane8 : zpage + lane8;
            const unsigned short* plo = zpage;
            if (SPLIT) plo = ok ? inL + pix * CIN + lane8 : zpage + lane8;
            #pragma unroll
            for (int cc = 0; cc < CIN; cc += 32) {
                const int k0 = tap * CIN + cc;
                if (e0 < BN * 32) {
                    size_t gb = (size_t)(e0 >> 5) * KP + k0 + (e0 & 31);
                    gload_lds16(Wt + gb, &lsB[e0]);
                    if (SPLIT) gload_lds16(Wt + wloff + gb, &lsB[BN * 32 + e0]);
                }
                gload_lds16(phi + cc, &lsA[t * 8]);
                if (SPLIT) gload_lds16(plo + cc, &lsA[BM * 32 + t * 8]);
                __syncthreads();
                mfma_step<SPLIT, MI, NI, ASTR, BM, BN>(lsA, lsB, acc, wm0, wn0, l);
                __syncthreads();
            }
        }
    }

    // ---- epilogue ----
    #pragma unroll
    for (int mi = 0; mi < MI; ++mi) {
        #pragma unroll
        for (int ni = 0; ni < NI; ++ni) {
            int n = ncol0 + wn0 + ni * 16 + (l & 15);
            if (n >= Cout) continue;
            float bv = BIAS ? bias[n] : 0.f;
            #pragma unroll
            for (int j = 0; j < 4; ++j) {
                int m = tm + wm0 + mi * 16 + (l >> 4) * 4 + j;
                float v = acc[mi * NI + ni][j] + bv;
                if (RESID == 1) { size_t ri = (size_t)m * Cout + n; v += bf2f(rH[ri]) + bf2f(rL[ri]); }
                if (RESID == 2) { v += bf2f(rH[(size_t)m * Cout + n]); }
                float vr = RELU ? fmaxf(v, 0.f) : v;
                if (DUAL) {
                    size_t oi = (size_t)m * Cout + n;
                    unsigned short hb = f2bf(v);
                    o2H[oi] = hb;
                    if (SPLIT) o2L[oi] = f2bf(v - bf2f(hb));
                }
                if (OMODE == 0) {
                    size_t oi = (size_t)m * Cout + n;
                    unsigned short hb = f2bf(vr);
                    oH[oi] = hb;
                    if (SPLIT) oL[oi] = f2bf(vr - bf2f(hb));
                } else if (OMODE == 1) {
                    int b2 = m / HWout, rem = m - b2 * HWout;
                    oF[(size_t)(b2 * Cout + n) * HWout + rem] = vr;
                } else if (OMODE == 2) {
                    int b2 = m / HWout, rem = m - b2 * HWout;
                    int y = rem / Wout, x2 = rem - y * Wout;
                    oF[(size_t)(b2 * Cout + n) * (4 * HWout)
                       + (size_t)(2 * y + py) * (2 * Wout) + (2 * x2 + px)] = vr;
                } else {
                    int b2 = m / HWout, rem = m - b2 * HWout;
                    int y = rem / Wout, x2 = rem - y * Wout;
                    int Hg2 = 2 * (HWout / Wout);
                    size_t oi = (((size_t)b2 * Hg2 + (2 * y + py)) * (size_t)(2 * Wout)
                                 + (2 * x2 + px)) * Cout + n;
                    oH[oi] = f2bf(vr);
                }
            }
        }
    }
}

// ---------------------------------------------------------------------------
// Weight packing
// ---------------------------------------------------------------------------
struct PackDesc {
    const float* src; unsigned long long dstoff;
    int Npad, N, CIN, KH, KW, K, Kpad, mode, py, px, split;
};
struct PackArgs { PackDesc d[21]; };

__global__ __launch_bounds__(256) void wpack_all(PackArgs pa, unsigned short* __restrict__ wp)
{
    PackDesc d = pa.d[blockIdx.y];
    int gid = blockIdx.x * 256 + threadIdx.x;
    int tot = d.Npad * d.Kpad;
    if (gid >= tot) return;
    int n = gid / d.Kpad;
    int k = gid - n * d.Kpad;
    float v = 0.0f;
    if (n < d.N && k < d.K) {
        int tap = k / d.CIN, c = k - tap * d.CIN;
        int ky, kx;
        if (d.mode == 0) { ky = tap / d.KW; kx = tap - (tap / d.KW) * d.KW; }
        else { int ty = tap >> 1, tx = tap & 1; ky = d.py + 2 * ty; kx = d.px + 2 * tx; }
        v = d.src[((size_t)(n * d.CIN + c) * d.KH + ky) * d.KW + kx];
    }
    unsigned short hb = f2bf(v);
    wp[d.dstoff + gid] = hb;
    if (d.split) wp[d.dstoff + tot + gid] = f2bf(v - bf2f(hb));
}

// ---------------------------------------------------------------------------
// VQ
// ---------------------------------------------------------------------------
__global__ __launch_bounds__(256) void vq_sq(
    const float* __restrict__ cb, float* __restrict__ ccsq)
{
    int k = blockIdx.x * 256 + threadIdx.x;
    const float* c = cb + (size_t)k * 64;
    float a0 = 0.f, a1 = 0.f;
    #pragma unroll
    for (int d = 0; d < 64; d += 2) {
        a0 = fmaf(c[d], c[d], a0);
        a1 = fmaf(c[d + 1], c[d + 1], a1);
    }
    ccsq[k] = a0 + a1;
}

__global__ __launch_bounds__(256) void vq_scan(
    const float* __restrict__ z, const float* __restrict__ cb,
    const float* __restrict__ ccsq,
    float* __restrict__ pdist, int* __restrict__ pidx)
{
    const int HW = 1024;
    int n = blockIdx.x * 256 + threadIdx.x;
    int chunk = blockIdx.y;
    int base = chunk * 64;
    int b = n >> 10;
    int p = n & 1023;
    const float* zp = z + (size_t)b * 64 * HW + p;
    float zv[64];
    #pragma unroll
    for (int d = 0; d < 64; ++d) zv[d] = zp[(size_t)d * HW];

    float best = 3.402823e38f;
    int bi = base;
    for (int kk = 0; kk < 64; kk += 2) {
        const float* c0 = cb + (size_t)(base + kk) * 64;
        float a0 = 0.f, a1 = 0.f, b0 = 0.f, b1 = 0.f;
        #pragma unroll
        for (int d = 0; d < 64; d += 2) {
            a0 = fmaf(zv[d],     c0[d],          a0);
            a1 = fmaf(zv[d + 1], c0[d + 1],      a1);
            b0 = fmaf(zv[d],     c0[64 + d],     b0);
            b1 = fmaf(zv[d + 1], c0[64 + d + 1], b1);
        }
        float s0 = ccsq[base + kk]     - 2.0f * (a0 + a1);
        float s1 = ccsq[base + kk + 1] - 2.0f * (b0 + b1);
        if (s0 < best) { best = s0; bi = base + kk; }
        if (s1 < best) { best = s1; bi = base + kk + 1; }
    }
    pdist[(size_t)chunk * 32768 + n] = best;
    pidx [(size_t)chunk * 32768 + n] = bi;
}

// reduce: 1024 blocks; 32 n x 8 d-groups. Writes q as bf16 NHWC + idx + SSE.
__global__ __launch_bounds__(256) void vq_reduce(
    const float* __restrict__ z, const float* __restrict__ cb,
    const float* __restrict__ pdist, const int* __restrict__ pidx,
    unsigned short* __restrict__ qb, int* __restrict__ idxbuf, float* __restrict__ sse)
{
    const int HW = 1024;
    int nl = threadIdx.x & 31;
    int dg = threadIdx.x >> 5;
    int n = blockIdx.x * 32 + nl;
    float best = pdist[n];
    int bi = pidx[n];
    #pragma unroll
    for (int ch = 1; ch < 8; ++ch) {
        float dv = pdist[(size_t)ch * 32768 + n];
        int iv = pidx[(size_t)ch * 32768 + n];
        if (dv < best) { best = dv; bi = iv; }
    }
    if (dg == 0) idxbuf[n] = bi;
    int b = n >> 10;
    int p = n & 1023;
    const float* zp = z + (size_t)b * 64 * HW + p;
    const float* c = cb + (size_t)bi * 64;
    float s = 0.f;
    short8 qv;
    #pragma unroll
    for (int j = 0; j < 8; ++j) {
        int d = dg * 8 + j;
        float q = c[d];
        qv[j] = (short)f2bf(q);
        float df = q - zp[(size_t)d * HW];
        s = fmaf(df, df, s);
    }
    *(short8*)&qb[(size_t)n * 64 + dg * 8] = qv;
    #pragma unroll
    for (int off = 32; off > 0; off >>= 1) s += __shfl_down(s, off, 64);
    __shared__ float red[4];
    if ((threadIdx.x & 63) == 0) red[threadIdx.x >> 6] = s;
    __syncthreads();
    if (threadIdx.x == 0) atomicAdd(sse, red[0] + red[1] + red[2] + red[3]);
}

__global__ __launch_bounds__(1024) void vq_hist(
    const int* __restrict__ idxbuf, float* __restrict__ hist)
{
    __shared__ int lh[512];
    int t = threadIdx.x;
    if (t < 512) lh[t] = 0;
    __syncthreads();
    #pragma unroll
    for (int j = 0; j < 32; ++j)
        atomicAdd(&lh[idxbuf[j * 1024 + t]], 1);
    __syncthreads();
    if (t < 512) hist[t] = (float)lh[t];
}

__global__ __launch_bounds__(512) void vq_finalize(
    const float* __restrict__ hist, const float* __restrict__ sse,
    float* __restrict__ out_loss, float* __restrict__ out_ppl)
{
    __shared__ float red[512];
    int t = threadIdx.x;
    float p = hist[t] * (1.0f / 32768.0f);
    red[t] = p * logf(p + 1e-10f);
    __syncthreads();
    for (int s = 256; s > 0; s >>= 1) {
        if (t < s) red[t] += red[t + s];
        __syncthreads();
    }
    if (t == 0) {
        *out_ppl = expf(-red[0]);
        *out_loss = 1.25f * (*sse) * (1.0f / 2097152.0f);
    }
}

// ---------------------------------------------------------------------------
extern "C" void kernel_launch(void* const* d_in, const int* in_sizes, int n_in,
                              void* d_out, int out_size, void* d_ws, size_t ws_size,
                              hipStream_t stream)
{
    typedef unsigned short us;
    const float* x        = (const float*)d_in[0];
    const float* e_w1     = (const float*)d_in[1];
    const float* e_b1     = (const float*)d_in[2];
    const float* e_w2     = (const float*)d_in[3];
    const float* e_b2     = (const float*)d_in[4];
    const float* e_w3     = (const float*)d_in[5];
    const float* e_b3     = (const float*)d_in[6];
    const float* e_r1a    = (const float*)d_in[7];
    const float* e_r1b    = (const float*)d_in[8];
    const float* e_r2a    = (const float*)d_in[9];
    const float* e_r2b    = (const float*)d_in[10];
    const float* pre_w    = (const float*)d_in[11];
    const float* pre_b    = (const float*)d_in[12];
    const float* codebook = (const float*)d_in[13];
    const float* d_w1     = (const float*)d_in[14];
    const float* d_b1     = (const float*)d_in[15];
    const float* d_r1a    = (const float*)d_in[16];
    const float* d_r1b    = (const float*)d_in[17];
    const float* d_r2a    = (const float*)d_in[18];
    const float* d_r2b    = (const float*)d_in[19];
    const float* dt_w1    = (const float*)d_in[20];
    const float* dt_b1    = (const float*)d_in[21];
    const float* dt_w2    = (const float*)d_in[22];
    const float* dt_b2    = (const float*)d_in[23];
    float* out = (float*)d_out;

    // ---- arena (byte offsets) ----
    const size_t MB = 1024 * 1024;
    char* base = (char*)d_ws;
    char* A0 = base;               // 32 MB slot
    char* B0 = base + 32 * MB;     // 16 MB slot
    char* C0 = base + 48 * MB;     // 16 MB slot
    char* D0 = base + 64 * MB;     //  4 MB slot
    float* st = (float*)(base + 68 * MB);                 // 4 KB (hist/sse/zpage)
    us* wp = (us*)(base + 68 * MB + 4096);

    us* h1H = (us*)A0;              us* h1L = (us*)(A0 + 16 * MB);
    us* hBH = (us*)B0;              us* hBL = (us*)(B0 + 8 * MB);
    us* CeH = (us*)A0;              us* CeL = (us*)(A0 + 8 * MB);   // C relu
    us* CrH = (us*)C0;              us* CrL = (us*)(C0 + 8 * MB);   // C raw
    us* DsH = (us*)D0;              us* DsL = (us*)(D0 + 2 * MB);
    us* T2rH = (us*)A0;             us* T2rL = (us*)(A0 + 8 * MB);  // T2 raw
    us* T2eH = (us*)B0;             us* T2eL = (us*)(B0 + 8 * MB);  // T2 relu
    us* T3H = (us*)C0;              us* T3L = (us*)(C0 + 8 * MB);
    float* E = (float*)B0;                                          // z fp32
    us* qb = (us*)(B0 + 8 * MB);                                    // q bf16 NHWC
    float* pdist = (float*)A0;
    int* pidx = (int*)(A0 + 1 * MB);
    int* idxbuf = (int*)(A0 + 2 * MB);
    float* ccsq = (float*)(A0 + 2 * MB + 128 * 1024);
    us* GeH = (us*)A0;              us* GrH = (us*)(A0 + 8 * MB);   // dec g relu/raw
    us* dDs = (us*)D0;
    us* dT2e = (us*)B0;             us* dT2r = (us*)(B0 + 8 * MB);
    us* dT3 = (us*)C0;
    us* gbuf = (us*)A0;
    const us* zpage = (const us*)(st + 576);                        // zeros

    // ---- weight packing ----
    PackArgs pa;
    int np = 0; unsigned long long wpo = 0;
    auto addpack = [&](const float* src, int N, int Npad, int CIN, int KH, int KW,
                       int K, int Kpad, int mode, int py, int px, int split) -> unsigned long long {
        pa.d[np].src = src; pa.d[np].dstoff = wpo;
        pa.d[np].Npad = Npad; pa.d[np].N = N; pa.d[np].CIN = CIN;
        pa.d[np].KH = KH; pa.d[np].KW = KW; pa.d[np].K = K; pa.d[np].Kpad = Kpad;
        pa.d[np].mode = mode; pa.d[np].py = py; pa.d[np].px = px; pa.d[np].split = split;
        ++np; unsigned long long off = wpo; wpo += (unsigned long long)Npad * Kpad * (split ? 2 : 1);
        return off;
    };
    unsigned long long P_E1  = addpack(e_w1, 64, 64, 3, 4, 4, 48, 64, 0, 0, 0, 1);
    unsigned long long P_E2  = addpack(e_w2, 128, 128, 64, 4, 4, 1024, 1024, 0, 0, 0, 1);
    unsigned long long P_E3  = addpack(e_w3, 128, 128, 128, 3, 3, 1152, 1152, 0, 0, 0, 1);
    unsigned long long P_R1A = addpack(e_r1a, 32, 32, 128, 3, 3, 1152, 1152, 0, 0, 0, 1);
    unsigned long long P_R1B = addpack(e_r1b, 128, 128, 32, 1, 1, 32, 32, 0, 0, 0, 1);
    unsigned long long P_R2A = addpack(e_r2a, 32, 32, 128, 3, 3, 1152, 1152, 0, 0, 0, 1);
    unsigned long long P_R2B = addpack(e_r2b, 128, 128, 32, 1, 1, 32, 32, 0, 0, 0, 1);
    unsigned long long P_PRE = addpack(pre_w, 64, 64, 128, 1, 1, 128, 128, 0, 0, 0, 1);
    unsigned long long P_D1  = addpack(d_w1, 128, 128, 64, 3, 3, 576, 576, 0, 0, 0, 0);
    unsigned long long P_DR1A = addpack(d_r1a, 32, 32, 128, 3, 3, 1152, 1152, 0, 0, 0, 0);
    unsigned long long P_DR1B = addpack(d_r1b, 128, 128, 32, 1, 1, 32, 32, 0, 0, 0, 0);
    unsigned long long P_DR2A = addpack(d_r2a, 32, 32, 128, 3, 3, 1152, 1152, 0, 0, 0, 0);
    unsigned long long P_DR2B = addpack(d_r2b, 128, 128, 32, 1, 1, 32, 32, 0, 0, 0, 0);
    unsigned long long P_DT1[4], P_DT2[4];
    for (int p = 0; p < 4; ++p)
        P_DT1[p] = addpack(dt_w1, 64, 64, 128, 4, 4, 512, 512, 1, p >> 1, p & 1, 0);
    for (int p = 0; p < 4; ++p)
        P_DT2[p] = addpack(dt_w2, 3, 16, 64, 4, 4, 256, 256, 1, p >> 1, p & 1, 0);

    hipMemsetAsync(st, 0, 4096, stream);    // hist, sse, zero page
    wpack_all<<<dim3(576, 21), 256, 0, stream>>>(pa, wp);

    // ----- encoder (split) -----
    conv_gemm<3,4,4,2, true,true, 64,2,2, true,0,true,false,0><<<dim3(2048),256,0,stream>>>(
        nullptr, nullptr, x, wp + P_E1, 64ull*64, e_b1,
        h1H, h1L, nullptr, nullptr, nullptr, nullptr, nullptr, zpage,
        128,128, 64, 4096, 64, 1,1, 0,0, 1);
    conv_gemm<64,4,4,2, false,true, 64,2,2, true,0,true,false,0><<<dim3(1024),256,0,stream>>>(
        h1H, h1L, nullptr, wp + P_E2, 128ull*1024, e_b2,
        hBH, hBL, nullptr, nullptr, nullptr, nullptr, nullptr, zpage,
        64,64, 32, 1024, 128, 1,1, 0,0, 2);
    conv_gemm<128,3,3,1, false,true, 64,2,2, true,0,true,true,0><<<dim3(1024),256,0,stream>>>(
        hBH, hBL, nullptr, wp + P_E3, 128ull*1152, e_b3,
        CeH, CeL, CrH, CrL, nullptr, nullptr, nullptr, zpage,
        32,32, 32, 1024, 128, 1,1, 0,0, 2);
    conv_gemm<128,3,3,1, false,true, 32,4,1, false,0,true,false,0><<<dim3(512),256,0,stream>>>(
        CeH, CeL, nullptr, wp + P_R1A, 32ull*1152, nullptr,
        DsH, DsL, nullptr, nullptr, nullptr, nullptr, nullptr, zpage,
        32,32, 32, 1024, 32, 1,1, 0,0, 1);
    conv_gemm<32,1,1,1, false,true, 64,2,2, false,1,true,true,0><<<dim3(1024),256,0,stream>>>(
        DsH, DsL, nullptr, wp + P_R1B, 128ull*32, nullptr,
        T2eH, T2eL, T2rH, T2rL, nullptr, CrH, CrL, zpage,
        32,32, 32, 1024, 128, 0,0, 0,0, 2);
    conv_gemm<128,3,3,1, false,true, 32,4,1, false,0,true,false,0><<<dim3(512),256,0,stream>>>(
        T2eH, T2eL, nullptr, wp + P_R2A, 32ull*1152, nullptr,
        DsH, DsL, nullptr, nullptr, nullptr, nullptr, nullptr, zpage,
        32,32, 32, 1024, 32, 1,1, 0,0, 1);
    conv_gemm<32,1,1,1, false,true, 64,2,2, false,1,true,false,0><<<dim3(1024),256,0,stream>>>(
        DsH, DsL, nullptr, wp + P_R2B, 128ull*32, nullptr,
        T3H, T3L, nullptr, nullptr, nullptr, T2rH, T2rL, zpage,
        32,32, 32, 1024, 128, 0,0, 0,0, 2);
    conv_gemm<128,1,1,1, false,true, 64,2,2, true,0,false,false,1><<<dim3(512),256,0,stream>>>(
        T3H, T3L, nullptr, wp + P_PRE, 64ull*128, pre_b,
        nullptr, nullptr, nullptr, nullptr, E, nullptr, nullptr, zpage,
        32,32, 32, 1024, 64, 0,0, 0,0, 1);

    // ----- vector quantizer -----
    vq_sq<<<dim3(2), 256, 0, stream>>>(codebook, ccsq);
    vq_scan<<<dim3(128, 8), 256, 0, stream>>>(E, codebook, ccsq, pdist, pidx);
    vq_reduce<<<dim3(1024), 256, 0, stream>>>(E, codebook, pdist, pidx, qb, idxbuf, st + 512);
    vq_hist<<<dim3(1), 1024, 0, stream>>>(idxbuf, st);
    vq_finalize<<<dim3(1), 512, 0, stream>>>(st, st + 512, out, out + 1572865);

    // ----- decoder (plain bf16) -----
    conv_gemm<64,3,3,1, false,false, 64,2,2, true,0,true,true,0><<<dim3(1024),256,0,stream>>>(
        qb, nullptr, nullptr, wp + P_D1, 0ull, d_b1,
        GeH, nullptr, GrH, nullptr, nullptr, nullptr, nullptr, zpage,
        32,32, 32, 1024, 128, 1,1, 0,0, 2);
    conv_gemm<128,3,3,1, false,false, 32,4,1, false,0,true,false,0><<<dim3(512),256,0,stream>>>(
        GeH, nullptr, nullptr, wp + P_DR1A, 0ull, nullptr,
        dDs, nullptr, nullptr, nullptr, nullptr, nullptr, nullptr, zpage,
        32,32, 32, 1024, 32, 1,1, 0,0, 1);
    conv_gemm<32,1,1,1, false,false, 64,2,2, false,2,true,true,0><<<dim3(1024),256,0,stream>>>(
        dDs, nullptr, nullptr, wp + P_DR1B, 0ull, nullptr,
        dT2e, nullptr, dT2r, nullptr, nullptr, GrH, nullptr, zpage,
        32,32, 32, 1024, 128, 0,0, 0,0, 2);
    conv_gemm<128,3,3,1, false,false, 32,4,1, false,0,true,false,0><<<dim3(512),256,0,stream>>>(
        dT2e, nullptr, nullptr, wp + P_DR2A, 0ull, nullptr,
        dDs, nullptr, nullptr, nullptr, nullptr, nullptr, nullptr, zpage,
        32,32, 32, 1024, 32, 1,1, 0,0, 1);
    conv_gemm<32,1,1,1, false,false, 64,2,2, false,2,true,false,0><<<dim3(1024),256,0,stream>>>(
        dDs, nullptr, nullptr, wp + P_DR2B, 0ull, nullptr,
        dT3, nullptr, nullptr, nullptr, nullptr, dT2r, nullptr, zpage,
        32,32, 32, 1024, 128, 0,0, 0,0, 2);
    for (int p = 0; p < 4; ++p) {
        conv_gemm<128,2,2,1, false,false, 64,2,2, true,0,true,false,3><<<dim3(512),256,0,stream>>>(
            dT3, nullptr, nullptr, wp + P_DT1[p], 0ull, dt_b1,
            gbuf, nullptr, nullptr, nullptr, nullptr, nullptr, nullptr, zpage,
            32,32, 32, 1024, 64, 1-(p>>1), 1-(p&1), p>>1, p&1, 1);
    }
    for (int p = 0; p < 4; ++p) {
        conv_gemm<64,2,2,1, false,false, 16,4,1, true,0,false,false,2><<<dim3(2048),256,0,stream>>>(
            gbuf, nullptr, nullptr, wp + P_DT2[p], 0ull, dt_b2,
            nullptr, nullptr, nullptr, nullptr, out + 1, nullptr, nullptr, zpage,
            64,64, 64, 4096, 3, 1-(p>>1), 1-(p&1), p>>1, p&1, 1);
    }
}

// Round 11
// 456.042 us; speedup vs baseline: 18.0490x; 1.3048x over previous
//
#include <hip/hip_runtime.h>

// ---------------------------------------------------------------------------
// VQ-VAE forward, round 11: bf16-NHWC pipeline + BK=64 K-steps with XOR
// chunk swizzle (A: pre-swizzled per-lane global source; B: swizzle baked
// into packed-weight storage; reads apply pc = kc ^ (row&7)) -> conflict-free
// ds_read_b128, half the barriers. K=32 layers and E1 keep BK=32 paths.
// Numerics identical to round 10 (same k order, same f2bf).
// ---------------------------------------------------------------------------

typedef short short8 __attribute__((ext_vector_type(8)));
typedef float f32x4 __attribute__((ext_vector_type(4)));
typedef unsigned short us;

__device__ __forceinline__ us f2bf(float f) {
    unsigned u = __builtin_bit_cast(unsigned, f);
    u += 0x7fffu + ((u >> 16) & 1u);      // RNE
    return (us)(u >> 16);
}
__device__ __forceinline__ float bf2f(us b) {
    unsigned u = ((unsigned)b) << 16;
    return __builtin_bit_cast(float, u);
}
__device__ __forceinline__ void gload_lds16(const void* g, void* l) {
    __builtin_amdgcn_global_load_lds(
        (const __attribute__((address_space(1))) void*)g,
        (__attribute__((address_space(3))) void*)l, 16, 0, 0);
}

// BK=32 linear fragment reads (FP32IN path / K=32 path)
template<bool SPLIT, int MI, int NI, int ASTR, int APLANE, int BPLANE>
__device__ __forceinline__ void mfma_step32(
    const us* lsA, const us* lsB, f32x4* acc, int wm0, int wn0, int l)
{
    short8 ah[MI], bh[NI];
    #pragma unroll
    for (int mi = 0; mi < MI; ++mi)
        ah[mi] = *(const short8*)&lsA[(wm0 + mi*16 + (l&15))*ASTR + (l>>4)*8];
    #pragma unroll
    for (int ni = 0; ni < NI; ++ni)
        bh[ni] = *(const short8*)&lsB[(wn0 + ni*16 + (l&15))*32 + (l>>4)*8];
    if (SPLIT) {
        short8 al[MI], bl[NI];
        #pragma unroll
        for (int mi = 0; mi < MI; ++mi)
            al[mi] = *(const short8*)&lsA[APLANE + (wm0 + mi*16 + (l&15))*ASTR + (l>>4)*8];
        #pragma unroll
        for (int ni = 0; ni < NI; ++ni)
            bl[ni] = *(const short8*)&lsB[BPLANE + (wn0 + ni*16 + (l&15))*32 + (l>>4)*8];
        #pragma unroll
        for (int mi = 0; mi < MI; ++mi)
            #pragma unroll
            for (int ni = 0; ni < NI; ++ni) {
                acc[mi*NI+ni] = __builtin_amdgcn_mfma_f32_16x16x32_bf16(ah[mi], bh[ni], acc[mi*NI+ni], 0, 0, 0);
                acc[mi*NI+ni] = __builtin_amdgcn_mfma_f32_16x16x32_bf16(ah[mi], bl[ni], acc[mi*NI+ni], 0, 0, 0);
                acc[mi*NI+ni] = __builtin_amdgcn_mfma_f32_16x16x32_bf16(al[mi], bh[ni], acc[mi*NI+ni], 0, 0, 0);
            }
    } else {
        #pragma unroll
        for (int mi = 0; mi < MI; ++mi)
            #pragma unroll
            for (int ni = 0; ni < NI; ++ni)
                acc[mi*NI+ni] = __builtin_amdgcn_mfma_f32_16x16x32_bf16(ah[mi], bh[ni], acc[mi*NI+ni], 0, 0, 0);
    }
}

// ---------------------------------------------------------------------------
// Fused conv GEMM. FP32IN: fp32 NCHW cvt path (E1). Else bf16 NHWC planes
// via global_load_lds; BK64: 64-k steps + XOR chunk swizzle (conflict-free).
// RESID: 0 none, 1 bf16 hi+lo, 2 bf16 single. DUAL: also write raw copy.
// OMODE: 0 bf16 NHWC, 1 fp32 NCHW, 2 fp32 NCHW scatter, 3 bf16 NHWC scatter.
// ---------------------------------------------------------------------------
template<int CIN, int KH, int KW, int S, bool FP32IN, bool SPLIT,
         int BN, int WM_, int WN_, bool BIAS, int RESID, bool RELU, bool DUAL,
         int OMODE, bool BK64>
__global__ __launch_bounds__(256, 4) void conv_gemm(
    const us* __restrict__ inH, const us* __restrict__ inL,
    const float* __restrict__ inF,
    const us* __restrict__ Wp, unsigned long long wloff,
    const float* __restrict__ bias,
    us* __restrict__ oH, us* __restrict__ oL,
    us* __restrict__ o2H, us* __restrict__ o2L,
    float* __restrict__ oF,
    const us* __restrict__ rH, const us* __restrict__ rL,
    const us* __restrict__ zpage,
    int Hin, int Win, int Wout, int HWout, int Cout, int pady, int padx,
    int py, int px, int nbn)
{
    constexpr int BM = 64;
    constexpr int K = CIN * KH * KW;
    constexpr int KP = ((K + 31) / 32) * 32;
    constexpr int TAPS = KH * KW;
    constexpr int ASTR = FP32IN ? 40 : 32;
    constexpr int ASHORT = FP32IN ? BM*40 : (BK64 ? BM*64 : BM*32);
    constexpr int BSHORT = (BK64 && !FP32IN) ? BN*64 : BN*32;
    constexpr int MI = BM / WM_ / 16, NI = BN / WN_ / 16;
    constexpr bool PIX1 = (KH == 1 && KW == 1 && S == 1);
    __shared__ __align__(16) us lsA[(SPLIT ? 2 : 1) * ASHORT];
    __shared__ __align__(16) us lsB[(SPLIT ? 2 : 1) * BSHORT];

    int t = threadIdx.x, l = t & 63, w = t >> 6;
    int bid = blockIdx.x;
    int nt = bid % nbn;
    int tm = (bid / nbn) * BM;
    int ncol0 = nt * BN;
    const us* Wt = Wp + (size_t)ncol0 * KP;
    int wm0 = (w / WN_) * (BM / WM_);
    int wn0 = (w % WN_) * (BN / WN_);
    f32x4 acc[MI * NI] = {};
    const int e0 = t * 8;

    if (FP32IN) {
        int m_l = t & 63, kseg = t >> 6;
        int ms = tm + m_l;
        int bsv = ms / HWout; int remv = ms - bsv * HWout;
        int oys = remv / Wout, oxs = remv - (remv / Wout) * Wout;
        int iy0 = oys * S - pady, ix0 = oxs * S - padx;
        const float* ibase = inF + (size_t)bsv * CIN * Hin * Win;
        for (int k0 = 0; k0 < KP; k0 += 32) {
            if (e0 < BN * 32) {
                size_t gb = (size_t)(e0 >> 5) * KP + k0 + (e0 & 31);
                gload_lds16(Wt + gb, &lsB[e0]);
                if (SPLIT) gload_lds16(Wt + wloff + gb, &lsB[BSHORT + e0]);
            }
            short8 hi, lo;
            #pragma unroll
            for (int j = 0; j < 8; ++j) {
                int k = k0 + kseg * 8 + j;
                float v = 0.f;
                if (k < K) {
                    int tap = k / CIN, c = k - tap * CIN;
                    int ky = tap / KW, kx = tap - (tap / KW) * KW;
                    int iy = iy0 + ky, ix = ix0 + kx;
                    if ((unsigned)iy < (unsigned)Hin && (unsigned)ix < (unsigned)Win)
                        v = ibase[((size_t)c * Hin + iy) * Win + ix];
                }
                us hb = f2bf(v);
                hi[j] = (short)hb;
                if (SPLIT) lo[j] = (short)f2bf(v - bf2f(hb));
            }
            *(short8*)&lsA[m_l * ASTR + kseg * 8] = hi;
            if (SPLIT) *(short8*)&lsA[ASHORT + m_l * ASTR + kseg * 8] = lo;
            __syncthreads();
            mfma_step32<SPLIT, MI, NI, ASTR, ASHORT, BSHORT>(lsA, lsB, acc, wm0, wn0, l);
            __syncthreads();
        }
    } else if (!BK64) {
        // BK=32 linear path (K=32 1x1 layers)
        int mrow = t >> 2;
        int lane8 = (t & 3) * 8;
        int m = tm + mrow;
        int bsv = m / HWout; int remv = m - bsv * HWout;
        int oys = remv / Wout, oxs = remv - oys * Wout;
        int iy0 = oys * S - pady, ix0 = oxs * S - padx;
        #pragma unroll
        for (int tap = 0; tap < TAPS; ++tap) {
            int ky = tap / KW, kx = tap - (tap / KW) * KW;
            int iy = iy0 + ky, ix = ix0 + kx;
            bool ok = PIX1 || ((unsigned)iy < (unsigned)Hin && (unsigned)ix < (unsigned)Win);
            size_t pix = ((size_t)bsv * Hin + iy) * Win + ix;
            const us* phi = ok ? inH + pix * CIN + lane8 : zpage + lane8;
            const us* plo = zpage;
            if (SPLIT) plo = ok ? inL + pix * CIN + lane8 : zpage + lane8;
            #pragma unroll
            for (int cc = 0; cc < CIN; cc += 32) {
                const int k0 = tap * CIN + cc;
                if (e0 < BN * 32) {
                    size_t gb = (size_t)(e0 >> 5) * KP + k0 + (e0 & 31);
                    gload_lds16(Wt + gb, &lsB[e0]);
                    if (SPLIT) gload_lds16(Wt + wloff + gb, &lsB[BSHORT + e0]);
                }
                gload_lds16(phi + cc, &lsA[t * 8]);
                if (SPLIT) gload_lds16(plo + cc, &lsA[ASHORT + t * 8]);
                __syncthreads();
                mfma_step32<SPLIT, MI, NI, ASTR, ASHORT, BSHORT>(lsA, lsB, acc, wm0, wn0, l);
                __syncthreads();
            }
        }
    } else {
        // BK=64 swizzled path. Thread t stages rows r0=t>>3, r1=r0+32,
        // physical chunk t&7; loads LOGICAL chunk (t&7)^((t>>3)&7).
        int r0 = t >> 3;
        int lc8 = (((t & 7) ^ (t >> 3)) & 7) * 8;
        int m0v = tm + r0, m1v = tm + r0 + 32;
        int bs0 = m0v / HWout, rm0 = m0v - bs0 * HWout;
        int oy0 = rm0 / Wout, ox0 = rm0 - oy0 * Wout;
        int bs1 = m1v / HWout, rm1 = m1v - bs1 * HWout;
        int oy1 = rm1 / Wout, ox1 = rm1 - oy1 * Wout;
        int iy00 = oy0 * S - pady, ix00 = ox0 * S - padx;
        int iy10 = oy1 * S - pady, ix10 = ox1 * S - padx;
        #pragma unroll
        for (int tap = 0; tap < TAPS; ++tap) {
            int ky = tap / KW, kx = tap - (tap / KW) * KW;
            int iyA = iy00 + ky, ixA = ix00 + kx;
            int iyB = iy10 + ky, ixB = ix10 + kx;
            bool okA = PIX1 || ((unsigned)iyA < (unsigned)Hin && (unsigned)ixA < (unsigned)Win);
            bool okB = PIX1 || ((unsigned)iyB < (unsigned)Hin && (unsigned)ixB < (unsigned)Win);
            size_t pxA = ((size_t)bs0 * Hin + iyA) * Win + ixA;
            size_t pxB = ((size_t)bs1 * Hin + iyB) * Win + ixB;
            const us* pA = okA ? inH + pxA * CIN + lc8 : zpage + lc8;
            const us* pB = okB ? inH + pxB * CIN + lc8 : zpage + lc8;
            const us* qA = zpage + lc8;
            const us* qB = zpage + lc8;
            if (SPLIT) {
                qA = okA ? inL + pxA * CIN + lc8 : zpage + lc8;
                qB = okB ? inL + pxB * CIN + lc8 : zpage + lc8;
            }
            #pragma unroll
            for (int cc = 0; cc < CIN; cc += 64) {
                const int k0 = tap * CIN + cc;
                // B stage (storage pre-swizzled -> linear load)
                #pragma unroll
                for (int q = 0; q < (BN + 31) / 32; ++q) {
                    if (BN >= 32 || t < BN * 8) {
                        size_t gb = (size_t)(q * 32 + (t >> 3)) * KP + k0 + (t & 7) * 8;
                        gload_lds16(Wt + gb, &lsB[q * 2048 + t * 8]);
                        if (SPLIT) gload_lds16(Wt + wloff + gb, &lsB[BSHORT + q * 2048 + t * 8]);
                    }
                }
                // A stage: per-lane swizzled global source
                gload_lds16(pA + cc, &lsA[t * 8]);
                gload_lds16(pB + cc, &lsA[2048 + t * 8]);
                if (SPLIT) {
                    gload_lds16(qA + cc, &lsA[ASHORT + t * 8]);
                    gload_lds16(qB + cc, &lsA[ASHORT + 2048 + t * 8]);
                }
                __syncthreads();
                #pragma unroll
                for (int kk = 0; kk < 2; ++kk) {
                    short8 ah[MI], bh[NI];
                    #pragma unroll
                    for (int mi = 0; mi < MI; ++mi) {
                        int row = wm0 + mi * 16 + (l & 15);
                        int pc = (kk * 4 + (l >> 4)) ^ (row & 7);
                        ah[mi] = *(const short8*)&lsA[row * 64 + pc * 8];
                    }
                    #pragma unroll
                    for (int ni = 0; ni < NI; ++ni) {
                        int row = wn0 + ni * 16 + (l & 15);
                        int pc = (kk * 4 + (l >> 4)) ^ (row & 7);
                        bh[ni] = *(const short8*)&lsB[row * 64 + pc * 8];
                    }
                    if (SPLIT) {
                        short8 al[MI], bl[NI];
                        #pragma unroll
                        for (int mi = 0; mi < MI; ++mi) {
                            int row = wm0 + mi * 16 + (l & 15);
                            int pc = (kk * 4 + (l >> 4)) ^ (row & 7);
                            al[mi] = *(const short8*)&lsA[ASHORT + row * 64 + pc * 8];
                        }
                        #pragma unroll
                        for (int ni = 0; ni < NI; ++ni) {
                            int row = wn0 + ni * 16 + (l & 15);
                            int pc = (kk * 4 + (l >> 4)) ^ (row & 7);
                            bl[ni] = *(const short8*)&lsB[BSHORT + row * 64 + pc * 8];
                        }
                        #pragma unroll
                        for (int mi = 0; mi < MI; ++mi)
                            #pragma unroll
                            for (int ni = 0; ni < NI; ++ni) {
                                acc[mi*NI+ni] = __builtin_amdgcn_mfma_f32_16x16x32_bf16(ah[mi], bh[ni], acc[mi*NI+ni], 0, 0, 0);
                                acc[mi*NI+ni] = __builtin_amdgcn_mfma_f32_16x16x32_bf16(ah[mi], bl[ni], acc[mi*NI+ni], 0, 0, 0);
                                acc[mi*NI+ni] = __builtin_amdgcn_mfma_f32_16x16x32_bf16(al[mi], bh[ni], acc[mi*NI+ni], 0, 0, 0);
                            }
                    } else {
                        #pragma unroll
                        for (int mi = 0; mi < MI; ++mi)
                            #pragma unroll
                            for (int ni = 0; ni < NI; ++ni)
                                acc[mi*NI+ni] = __builtin_amdgcn_mfma_f32_16x16x32_bf16(ah[mi], bh[ni], acc[mi*NI+ni], 0, 0, 0);
                    }
                }
                __syncthreads();
            }
        }
    }

    // ---- epilogue ----
    #pragma unroll
    for (int mi = 0; mi < MI; ++mi) {
        #pragma unroll
        for (int ni = 0; ni < NI; ++ni) {
            int n = ncol0 + wn0 + ni * 16 + (l & 15);
            if (n >= Cout) continue;
            float bv = BIAS ? bias[n] : 0.f;
            #pragma unroll
            for (int j = 0; j < 4; ++j) {
                int m = tm + wm0 + mi * 16 + (l >> 4) * 4 + j;
                float v = acc[mi * NI + ni][j] + bv;
                if (RESID == 1) { size_t ri = (size_t)m * Cout + n; v += bf2f(rH[ri]) + bf2f(rL[ri]); }
                if (RESID == 2) { v += bf2f(rH[(size_t)m * Cout + n]); }
                float vr = RELU ? fmaxf(v, 0.f) : v;
                if (DUAL) {
                    size_t oi = (size_t)m * Cout + n;
                    us hb = f2bf(v);
                    o2H[oi] = hb;
                    if (SPLIT) o2L[oi] = f2bf(v - bf2f(hb));
                }
                if (OMODE == 0) {
                    size_t oi = (size_t)m * Cout + n;
                    us hb = f2bf(vr);
                    oH[oi] = hb;
                    if (SPLIT) oL[oi] = f2bf(vr - bf2f(hb));
                } else if (OMODE == 1) {
                    int b2 = m / HWout, rem = m - b2 * HWout;
                    oF[(size_t)(b2 * Cout + n) * HWout + rem] = vr;
                } else if (OMODE == 2) {
                    int b2 = m / HWout, rem = m - b2 * HWout;
                    int y = rem / Wout, x2 = rem - y * Wout;
                    oF[(size_t)(b2 * Cout + n) * (4 * HWout)
                       + (size_t)(2 * y + py) * (2 * Wout) + (2 * x2 + px)] = vr;
                } else {
                    int b2 = m / HWout, rem = m - b2 * HWout;
                    int y = rem / Wout, x2 = rem - y * Wout;
                    int Hg2 = 2 * (HWout / Wout);
                    size_t oi = (((size_t)b2 * Hg2 + (2 * y + py)) * (size_t)(2 * Wout)
                                 + (2 * x2 + px)) * Cout + n;
                    oH[oi] = f2bf(vr);
                }
            }
        }
    }
}

// ---------------------------------------------------------------------------
// Weight packing. swz=1: store logical k-chunk (pc ^ (n&7)) at physical pc
// within each 64-k block (so linear gload -> swizzled LDS).
// ---------------------------------------------------------------------------
struct PackDesc {
    const float* src; unsigned long long dstoff;
    int Npad, N, CIN, KH, KW, K, Kpad, mode, py, px, split, swz;
};
struct PackArgs { PackDesc d[21]; };

__global__ __launch_bounds__(256) void wpack_all(PackArgs pa, us* __restrict__ wp)
{
    PackDesc d = pa.d[blockIdx.y];
    int gid = blockIdx.x * 256 + threadIdx.x;
    int tot = d.Npad * d.Kpad;
    if (gid >= tot) return;
    int n = gid / d.Kpad;
    int k = gid - n * d.Kpad;          // physical k
    int klog = k;
    if (d.swz) {
        int kb = k >> 6, pc = (k >> 3) & 7, j = k & 7;
        klog = (kb << 6) + (((pc ^ (n & 7)) & 7) << 3) + j;
    }
    float v = 0.0f;
    if (n < d.N && klog < d.K) {
        int tap = klog / d.CIN, c = klog - tap * d.CIN;
        int ky, kx;
        if (d.mode == 0) { ky = tap / d.KW; kx = tap - (tap / d.KW) * d.KW; }
        else { int ty = tap >> 1, tx = tap & 1; ky = d.py + 2 * ty; kx = d.px + 2 * tx; }
        v = d.src[((size_t)(n * d.CIN + c) * d.KH + ky) * d.KW + kx];
    }
    us hb = f2bf(v);
    wp[d.dstoff + gid] = hb;
    if (d.split) wp[d.dstoff + tot + gid] = f2bf(v - bf2f(hb));
}

// ---------------------------------------------------------------------------
// VQ (unchanged from round 10)
// ---------------------------------------------------------------------------
__global__ __launch_bounds__(256) void vq_sq(
    const float* __restrict__ cb, float* __restrict__ ccsq)
{
    int k = blockIdx.x * 256 + threadIdx.x;
    const float* c = cb + (size_t)k * 64;
    float a0 = 0.f, a1 = 0.f;
    #pragma unroll
    for (int d = 0; d < 64; d += 2) {
        a0 = fmaf(c[d], c[d], a0);
        a1 = fmaf(c[d + 1], c[d + 1], a1);
    }
    ccsq[k] = a0 + a1;
}

__global__ __launch_bounds__(256) void vq_scan(
    const float* __restrict__ z, const float* __restrict__ cb,
    const float* __restrict__ ccsq,
    float* __restrict__ pdist, int* __restrict__ pidx)
{
    const int HW = 1024;
    int n = blockIdx.x * 256 + threadIdx.x;
    int chunk = blockIdx.y;
    int base = chunk * 64;
    int b = n >> 10;
    int p = n & 1023;
    const float* zp = z + (size_t)b * 64 * HW + p;
    float zv[64];
    #pragma unroll
    for (int d = 0; d < 64; ++d) zv[d] = zp[(size_t)d * HW];

    float best = 3.402823e38f;
    int bi = base;
    for (int kk = 0; kk < 64; kk += 2) {
        const float* c0 = cb + (size_t)(base + kk) * 64;
        float a0 = 0.f, a1 = 0.f, b0 = 0.f, b1 = 0.f;
        #pragma unroll
        for (int d = 0; d < 64; d += 2) {
            a0 = fmaf(zv[d],     c0[d],          a0);
            a1 = fmaf(zv[d + 1], c0[d + 1],      a1);
            b0 = fmaf(zv[d],     c0[64 + d],     b0);
            b1 = fmaf(zv[d + 1], c0[64 + d + 1], b1);
        }
        float s0 = ccsq[base + kk]     - 2.0f * (a0 + a1);
        float s1 = ccsq[base + kk + 1] - 2.0f * (b0 + b1);
        if (s0 < best) { best = s0; bi = base + kk; }
        if (s1 < best) { best = s1; bi = base + kk + 1; }
    }
    pdist[(size_t)chunk * 32768 + n] = best;
    pidx [(size_t)chunk * 32768 + n] = bi;
}

__global__ __launch_bounds__(256) void vq_reduce(
    const float* __restrict__ z, const float* __restrict__ cb,
    const float* __restrict__ pdist, const int* __restrict__ pidx,
    us* __restrict__ qb, int* __restrict__ idxbuf, float* __restrict__ sse)
{
    const int HW = 1024;
    int nl = threadIdx.x & 31;
    int dg = threadIdx.x >> 5;
    int n = blockIdx.x * 32 + nl;
    float best = pdist[n];
    int bi = pidx[n];
    #pragma unroll
    for (int ch = 1; ch < 8; ++ch) {
        float dv = pdist[(size_t)ch * 32768 + n];
        int iv = pidx[(size_t)ch * 32768 + n];
        if (dv < best) { best = dv; bi = iv; }
    }
    if (dg == 0) idxbuf[n] = bi;
    int b = n >> 10;
    int p = n & 1023;
    const float* zp = z + (size_t)b * 64 * HW + p;
    const float* c = cb + (size_t)bi * 64;
    float s = 0.f;
    short8 qv;
    #pragma unroll
    for (int j = 0; j < 8; ++j) {
        int d = dg * 8 + j;
        float q = c[d];
        qv[j] = (short)f2bf(q);
        float df = q - zp[(size_t)d * HW];
        s = fmaf(df, df, s);
    }
    *(short8*)&qb[(size_t)n * 64 + dg * 8] = qv;
    #pragma unroll
    for (int off = 32; off > 0; off >>= 1) s += __shfl_down(s, off, 64);
    __shared__ float red[4];
    if ((threadIdx.x & 63) == 0) red[threadIdx.x >> 6] = s;
    __syncthreads();
    if (threadIdx.x == 0) atomicAdd(sse, red[0] + red[1] + red[2] + red[3]);
}

__global__ __launch_bounds__(1024) void vq_hist(
    const int* __restrict__ idxbuf, float* __restrict__ hist)
{
    __shared__ int lh[512];
    int t = threadIdx.x;
    if (t < 512) lh[t] = 0;
    __syncthreads();
    #pragma unroll
    for (int j = 0; j < 32; ++j)
        atomicAdd(&lh[idxbuf[j * 1024 + t]], 1);
    __syncthreads();
    if (t < 512) hist[t] = (float)lh[t];
}

__global__ __launch_bounds__(512) void vq_finalize(
    const float* __restrict__ hist, const float* __restrict__ sse,
    float* __restrict__ out_loss, float* __restrict__ out_ppl)
{
    __shared__ float red[512];
    int t = threadIdx.x;
    float p = hist[t] * (1.0f / 32768.0f);
    red[t] = p * logf(p + 1e-10f);
    __syncthreads();
    for (int s = 256; s > 0; s >>= 1) {
        if (t < s) red[t] += red[t + s];
        __syncthreads();
    }
    if (t == 0) {
        *out_ppl = expf(-red[0]);
        *out_loss = 1.25f * (*sse) * (1.0f / 2097152.0f);
    }
}

// ---------------------------------------------------------------------------
extern "C" void kernel_launch(void* const* d_in, const int* in_sizes, int n_in,
                              void* d_out, int out_size, void* d_ws, size_t ws_size,
                              hipStream_t stream)
{
    const float* x        = (const float*)d_in[0];
    const float* e_w1     = (const float*)d_in[1];
    const float* e_b1     = (const float*)d_in[2];
    const float* e_w2     = (const float*)d_in[3];
    const float* e_b2     = (const float*)d_in[4];
    const float* e_w3     = (const float*)d_in[5];
    const float* e_b3     = (const float*)d_in[6];
    const float* e_r1a    = (const float*)d_in[7];
    const float* e_r1b    = (const float*)d_in[8];
    const float* e_r2a    = (const float*)d_in[9];
    const float* e_r2b    = (const float*)d_in[10];
    const float* pre_w    = (const float*)d_in[11];
    const float* pre_b    = (const float*)d_in[12];
    const float* codebook = (const float*)d_in[13];
    const float* d_w1     = (const float*)d_in[14];
    const float* d_b1     = (const float*)d_in[15];
    const float* d_r1a    = (const float*)d_in[16];
    const float* d_r1b    = (const float*)d_in[17];
    const float* d_r2a    = (const float*)d_in[18];
    const float* d_r2b    = (const float*)d_in[19];
    const float* dt_w1    = (const float*)d_in[20];
    const float* dt_b1    = (const float*)d_in[21];
    const float* dt_w2    = (const float*)d_in[22];
    const float* dt_b2    = (const float*)d_in[23];
    float* out = (float*)d_out;

    // ---- arena ----
    const size_t MB = 1024 * 1024;
    char* base = (char*)d_ws;
    char* A0 = base;               // 32 MB slot
    char* B0 = base + 32 * MB;     // 16 MB slot
    char* C0 = base + 48 * MB;     // 16 MB slot
    char* D0 = base + 64 * MB;     //  4 MB slot
    float* st = (float*)(base + 68 * MB);                 // 4 KB (hist/sse/zpage)
    us* wp = (us*)(base + 68 * MB + 4096);

    us* h1H = (us*)A0;              us* h1L = (us*)(A0 + 16 * MB);
    us* hBH = (us*)B0;              us* hBL = (us*)(B0 + 8 * MB);
    us* CeH = (us*)A0;              us* CeL = (us*)(A0 + 8 * MB);   // C relu
    us* CrH = (us*)C0;              us* CrL = (us*)(C0 + 8 * MB);   // C raw
    us* DsH = (us*)D0;              us* DsL = (us*)(D0 + 2 * MB);
    us* T2rH = (us*)A0;             us* T2rL = (us*)(A0 + 8 * MB);  // T2 raw
    us* T2eH = (us*)B0;             us* T2eL = (us*)(B0 + 8 * MB);  // T2 relu
    us* T3H = (us*)C0;              us* T3L = (us*)(C0 + 8 * MB);
    float* E = (float*)B0;                                          // z fp32
    us* qb = (us*)(B0 + 8 * MB);                                    // q bf16 NHWC
    float* pdist = (float*)A0;
    int* pidx = (int*)(A0 + 1 * MB);
    int* idxbuf = (int*)(A0 + 2 * MB);
    float* ccsq = (float*)(A0 + 2 * MB + 128 * 1024);
    us* GeH = (us*)A0;              us* GrH = (us*)(A0 + 8 * MB);   // dec g relu/raw
    us* dDs = (us*)D0;
    us* dT2e = (us*)B0;             us* dT2r = (us*)(B0 + 8 * MB);
    us* dT3 = (us*)C0;
    us* gbuf = (us*)A0;
    const us* zpage = (const us*)(st + 576);                        // zeros

    // ---- weight packing ----
    PackArgs pa;
    int np = 0; unsigned long long wpo = 0;
    auto addpack = [&](const float* src, int N, int Npad, int CIN, int KH, int KW,
                       int K, int Kpad, int mode, int py, int px, int split,
                       int swz) -> unsigned long long {
        pa.d[np].src = src; pa.d[np].dstoff = wpo;
        pa.d[np].Npad = Npad; pa.d[np].N = N; pa.d[np].CIN = CIN;
        pa.d[np].KH = KH; pa.d[np].KW = KW; pa.d[np].K = K; pa.d[np].Kpad = Kpad;
        pa.d[np].mode = mode; pa.d[np].py = py; pa.d[np].px = px;
        pa.d[np].split = split; pa.d[np].swz = swz;
        ++np; unsigned long long off = wpo; wpo += (unsigned long long)Npad * Kpad * (split ? 2 : 1);
        return off;
    };
    unsigned long long P_E1  = addpack(e_w1, 64, 64, 3, 4, 4, 48, 64, 0, 0, 0, 1, 0);
    unsigned long long P_E2  = addpack(e_w2, 128, 128, 64, 4, 4, 1024, 1024, 0, 0, 0, 1, 1);
    unsigned long long P_E3  = addpack(e_w3, 128, 128, 128, 3, 3, 1152, 1152, 0, 0, 0, 1, 1);
    unsigned long long P_R1A = addpack(e_r1a, 32, 32, 128, 3, 3, 1152, 1152, 0, 0, 0, 1, 1);
    unsigned long long P_R1B = addpack(e_r1b, 128, 128, 32, 1, 1, 32, 32, 0, 0, 0, 1, 0);
    unsigned long long P_R2A = addpack(e_r2a, 32, 32, 128, 3, 3, 1152, 1152, 0, 0, 0, 1, 1);
    unsigned long long P_R2B = addpack(e_r2b, 128, 128, 32, 1, 1, 32, 32, 0, 0, 0, 1, 0);
    unsigned long long P_PRE = addpack(pre_w, 64, 64, 128, 1, 1, 128, 128, 0, 0, 0, 1, 1);
    unsigned long long P_D1  = addpack(d_w1, 128, 128, 64, 3, 3, 576, 576, 0, 0, 0, 0, 1);
    unsigned long long P_DR1A = addpack(d_r1a, 32, 32, 128, 3, 3, 1152, 1152, 0, 0, 0, 0, 1);
    unsigned long long P_DR1B = addpack(d_r1b, 128, 128, 32, 1, 1, 32, 32, 0, 0, 0, 0, 0);
    unsigned long long P_DR2A = addpack(d_r2a, 32, 32, 128, 3, 3, 1152, 1152, 0, 0, 0, 0, 1);
    unsigned long long P_DR2B = addpack(d_r2b, 128, 128, 32, 1, 1, 32, 32, 0, 0, 0, 0, 0);
    unsigned long long P_DT1[4], P_DT2[4];
    for (int p = 0; p < 4; ++p)
        P_DT1[p] = addpack(dt_w1, 64, 64, 128, 4, 4, 512, 512, 1, p >> 1, p & 1, 0, 1);
    for (int p = 0; p < 4; ++p)
        P_DT2[p] = addpack(dt_w2, 3, 16, 64, 4, 4, 256, 256, 1, p >> 1, p & 1, 0, 1);

    hipMemsetAsync(st, 0, 4096, stream);    // hist, sse, zero page
    wpack_all<<<dim3(576, 21), 256, 0, stream>>>(pa, wp);

    // ----- encoder (split) -----
    conv_gemm<3,4,4,2, true,true, 64,2,2, true,0,true,false,0, false><<<dim3(2048),256,0,stream>>>(
        nullptr, nullptr, x, wp + P_E1, 64ull*64, e_b1,
        h1H, h1L, nullptr, nullptr, nullptr, nullptr, nullptr, zpage,
        128,128, 64, 4096, 64, 1,1, 0,0, 1);
    conv_gemm<64,4,4,2, false,true, 64,2,2, true,0,true,false,0, true><<<dim3(1024),256,0,stream>>>(
        h1H, h1L, nullptr, wp + P_E2, 128ull*1024, e_b2,
        hBH, hBL, nullptr, nullptr, nullptr, nullptr, nullptr, zpage,
        64,64, 32, 1024, 128, 1,1, 0,0, 2);
    conv_gemm<128,3,3,1, false,true, 64,2,2, true,0,true,true,0, true><<<dim3(1024),256,0,stream>>>(
        hBH, hBL, nullptr, wp + P_E3, 128ull*1152, e_b3,
        CeH, CeL, CrH, CrL, nullptr, nullptr, nullptr, zpage,
        32,32, 32, 1024, 128, 1,1, 0,0, 2);
    conv_gemm<128,3,3,1, false,true, 32,4,1, false,0,true,false,0, true><<<dim3(512),256,0,stream>>>(
        CeH, CeL, nullptr, wp + P_R1A, 32ull*1152, nullptr,
        DsH, DsL, nullptr, nullptr, nullptr, nullptr, nullptr, zpage,
        32,32, 32, 1024, 32, 1,1, 0,0, 1);
    conv_gemm<32,1,1,1, false,true, 64,2,2, false,1,true,true,0, false><<<dim3(1024),256,0,stream>>>(
        DsH, DsL, nullptr, wp + P_R1B, 128ull*32, nullptr,
        T2eH, T2eL, T2rH, T2rL, nullptr, CrH, CrL, zpage,
        32,32, 32, 1024, 128, 0,0, 0,0, 2);
    conv_gemm<128,3,3,1, false,true, 32,4,1, false,0,true,false,0, true><<<dim3(512),256,0,stream>>>(
        T2eH, T2eL, nullptr, wp + P_R2A, 32ull*1152, nullptr,
        DsH, DsL, nullptr, nullptr, nullptr, nullptr, nullptr, zpage,
        32,32, 32, 1024, 32, 1,1, 0,0, 1);
    conv_gemm<32,1,1,1, false,true, 64,2,2, false,1,true,false,0, false><<<dim3(1024),256,0,stream>>>(
        DsH, DsL, nullptr, wp + P_R2B, 128ull*32, nullptr,
        T3H, T3L, nullptr, nullptr, nullptr, T2rH, T2rL, zpage,
        32,32, 32, 1024, 128, 0,0, 0,0, 2);
    conv_gemm<128,1,1,1, false,true, 64,2,2, true,0,false,false,1, true><<<dim3(512),256,0,stream>>>(
        T3H, T3L, nullptr, wp + P_PRE, 64ull*128, pre_b,
        nullptr, nullptr, nullptr, nullptr, E, nullptr, nullptr, zpage,
        32,32, 32, 1024, 64, 0,0, 0,0, 1);

    // ----- vector quantizer -----
    vq_sq<<<dim3(2), 256, 0, stream>>>(codebook, ccsq);
    vq_scan<<<dim3(128, 8), 256, 0, stream>>>(E, codebook, ccsq, pdist, pidx);
    vq_reduce<<<dim3(1024), 256, 0, stream>>>(E, codebook, pdist, pidx, qb, idxbuf, st + 512);
    vq_hist<<<dim3(1), 1024, 0, stream>>>(idxbuf, st);
    vq_finalize<<<dim3(1), 512, 0, stream>>>(st, st + 512, out, out + 1572865);

    // ----- decoder (plain bf16) -----
    conv_gemm<64,3,3,1, false,false, 64,2,2, true,0,true,true,0, true><<<dim3(1024),256,0,stream>>>(
        qb, nullptr, nullptr, wp + P_D1, 0ull, d_b1,
        GeH, nullptr, GrH, nullptr, nullptr, nullptr, nullptr, zpage,
        32,32, 32, 1024, 128, 1,1, 0,0, 2);
    conv_gemm<128,3,3,1, false,false, 32,4,1, false,0,true,false,0, true><<<dim3(512),256,0,stream>>>(
        GeH, nullptr, nullptr, wp + P_DR1A, 0ull, nullptr,
        dDs, nullptr, nullptr, nullptr, nullptr, nullptr, nullptr, zpage,
        32,32, 32, 1024, 32, 1,1, 0,0, 1);
    conv_gemm<32,1,1,1, false,false, 64,2,2, false,2,true,true,0, false><<<dim3(1024),256,0,stream>>>(
        dDs, nullptr, nullptr, wp + P_DR1B, 0ull, nullptr,
        dT2e, nullptr, dT2r, nullptr, nullptr, GrH, nullptr, zpage,
        32,32, 32, 1024, 128, 0,0, 0,0, 2);
    conv_gemm<128,3,3,1, false,false, 32,4,1, false,0,true,false,0, true><<<dim3(512),256,0,stream>>>(
        dT2e, nullptr, nullptr, wp + P_DR2A, 0ull, nullptr,
        dDs, nullptr, nullptr, nullptr, nullptr, nullptr, nullptr, zpage,
        32,32, 32, 1024, 32, 1,1, 0,0, 1);
    conv_gemm<32,1,1,1, false,false, 64,2,2, false,2,true,false,0, false><<<dim3(1024),256,0,stream>>>(
        dDs, nullptr, nullptr, wp + P_DR2B, 0ull, nullptr,
        dT3, nullptr, nullptr, nullptr, nullptr, dT2r, nullptr, zpage,
        32,32, 32, 1024, 128, 0,0, 0,0, 2);
    for (int p = 0; p < 4; ++p) {
        conv_gemm<128,2,2,1, false,false, 64,2,2, true,0,true,false,3, true><<<dim3(512),256,0,stream>>>(
            dT3, nullptr, nullptr, wp + P_DT1[p], 0ull, dt_b1,
            gbuf, nullptr, nullptr, nullptr, nullptr, nullptr, nullptr, zpage,
            32,32, 32, 1024, 64, 1-(p>>1), 1-(p&1), p>>1, p&1, 1);
    }
    for (int p = 0; p < 4; ++p) {
        conv_gemm<64,2,2,1, false,false, 16,4,1, true,0,false,false,2, true><<<dim3(2048),256,0,stream>>>(
            gbuf, nullptr, nullptr, wp + P_DT2[p], 0ull, dt_b2,
            nullptr, nullptr, nullptr, nullptr, out + 1, nullptr, nullptr, zpage,
            64,64, 64, 4096, 3, 1-(p>>1), 1-(p&1), p>>1, p&1, 1);
    }
}

// Round 12
// 422.873 us; speedup vs baseline: 19.4647x; 1.0784x over previous
//
#include <hip/hip_runtime.h>

// ---------------------------------------------------------------------------
// VQ-VAE forward, round 12 = round 11 +
//  - BN=128 for E2/E3/D1 (48 MFMA per barrier-pair, half the blocks)
//  - DT1/DT2 parity classes merged into single launches (blockIdx.y = parity)
//  - vq_hist + vq_finalize merged
// Numerics identical to rounds 10/11.
// ---------------------------------------------------------------------------

typedef short short8 __attribute__((ext_vector_type(8)));
typedef float f32x4 __attribute__((ext_vector_type(4)));
typedef unsigned short us;

__device__ __forceinline__ us f2bf(float f) {
    unsigned u = __builtin_bit_cast(unsigned, f);
    u += 0x7fffu + ((u >> 16) & 1u);      // RNE
    return (us)(u >> 16);
}
__device__ __forceinline__ float bf2f(us b) {
    unsigned u = ((unsigned)b) << 16;
    return __builtin_bit_cast(float, u);
}
__device__ __forceinline__ void gload_lds16(const void* g, void* l) {
    __builtin_amdgcn_global_load_lds(
        (const __attribute__((address_space(1))) void*)g,
        (__attribute__((address_space(3))) void*)l, 16, 0, 0);
}

// BK=32 linear fragment reads (FP32IN path / K=32 path)
template<bool SPLIT, int MI, int NI, int ASTR, int APLANE, int BPLANE>
__device__ __forceinline__ void mfma_step32(
    const us* lsA, const us* lsB, f32x4* acc, int wm0, int wn0, int l)
{
    short8 ah[MI], bh[NI];
    #pragma unroll
    for (int mi = 0; mi < MI; ++mi)
        ah[mi] = *(const short8*)&lsA[(wm0 + mi*16 + (l&15))*ASTR + (l>>4)*8];
    #pragma unroll
    for (int ni = 0; ni < NI; ++ni)
        bh[ni] = *(const short8*)&lsB[(wn0 + ni*16 + (l&15))*32 + (l>>4)*8];
    if (SPLIT) {
        short8 al[MI], bl[NI];
        #pragma unroll
        for (int mi = 0; mi < MI; ++mi)
            al[mi] = *(const short8*)&lsA[APLANE + (wm0 + mi*16 + (l&15))*ASTR + (l>>4)*8];
        #pragma unroll
        for (int ni = 0; ni < NI; ++ni)
            bl[ni] = *(const short8*)&lsB[BPLANE + (wn0 + ni*16 + (l&15))*32 + (l>>4)*8];
        #pragma unroll
        for (int mi = 0; mi < MI; ++mi)
            #pragma unroll
            for (int ni = 0; ni < NI; ++ni) {
                acc[mi*NI+ni] = __builtin_amdgcn_mfma_f32_16x16x32_bf16(ah[mi], bh[ni], acc[mi*NI+ni], 0, 0, 0);
                acc[mi*NI+ni] = __builtin_amdgcn_mfma_f32_16x16x32_bf16(ah[mi], bl[ni], acc[mi*NI+ni], 0, 0, 0);
                acc[mi*NI+ni] = __builtin_amdgcn_mfma_f32_16x16x32_bf16(al[mi], bh[ni], acc[mi*NI+ni], 0, 0, 0);
            }
    } else {
        #pragma unroll
        for (int mi = 0; mi < MI; ++mi)
            #pragma unroll
            for (int ni = 0; ni < NI; ++ni)
                acc[mi*NI+ni] = __builtin_amdgcn_mfma_f32_16x16x32_bf16(ah[mi], bh[ni], acc[mi*NI+ni], 0, 0, 0);
    }
}

// ---------------------------------------------------------------------------
// Fused conv GEMM. FP32IN: fp32 NCHW cvt path (E1). Else bf16 NHWC planes
// via global_load_lds; BK64: 64-k steps + XOR chunk swizzle (conflict-free).
// RESID: 0 none, 1 bf16 hi+lo, 2 bf16 single. DUAL: also write raw copy.
// OMODE: 0 bf16 NHWC, 1 fp32 NCHW, 2 fp32 NCHW scatter, 3 bf16 NHWC scatter.
// PMULTI: blockIdx.y = transposed-conv parity class (overrides pad/py/px,
//         selects weight pack at stride BN*KP).
// ---------------------------------------------------------------------------
template<int CIN, int KH, int KW, int S, bool FP32IN, bool SPLIT,
         int BN, int WM_, int WN_, bool BIAS, int RESID, bool RELU, bool DUAL,
         int OMODE, bool BK64, bool PMULTI>
__global__ __launch_bounds__(256, 4) void conv_gemm(
    const us* __restrict__ inH, const us* __restrict__ inL,
    const float* __restrict__ inF,
    const us* __restrict__ Wp, unsigned long long wloff,
    const float* __restrict__ bias,
    us* __restrict__ oH, us* __restrict__ oL,
    us* __restrict__ o2H, us* __restrict__ o2L,
    float* __restrict__ oF,
    const us* __restrict__ rH, const us* __restrict__ rL,
    const us* __restrict__ zpage,
    int Hin, int Win, int Wout, int HWout, int Cout, int pady, int padx,
    int py, int px, int nbn)
{
    constexpr int BM = 64;
    constexpr int K = CIN * KH * KW;
    constexpr int KP = ((K + 31) / 32) * 32;
    constexpr int TAPS = KH * KW;
    constexpr int ASTR = FP32IN ? 40 : 32;
    constexpr int ASHORT = FP32IN ? BM*40 : (BK64 ? BM*64 : BM*32);
    constexpr int BSHORT = (BK64 && !FP32IN) ? BN*64 : BN*32;
    constexpr int MI = BM / WM_ / 16, NI = BN / WN_ / 16;
    constexpr bool PIX1 = (KH == 1 && KW == 1 && S == 1);
    __shared__ __align__(16) us lsA[(SPLIT ? 2 : 1) * ASHORT];
    __shared__ __align__(16) us lsB[(SPLIT ? 2 : 1) * BSHORT];

    int t = threadIdx.x, l = t & 63, w = t >> 6;
    int bid = blockIdx.x;
    int nt = bid % nbn;
    int tm = (bid / nbn) * BM;
    int ncol0 = nt * BN;
    int par = 0;
    if (PMULTI) {
        par = blockIdx.y;
        pady = 1 - (par >> 1); padx = 1 - (par & 1);
        py = par >> 1;         px = par & 1;
    }
    const us* Wt = Wp + (size_t)par * BN * KP + (size_t)ncol0 * KP;
    int wm0 = (w / WN_) * (BM / WM_);
    int wn0 = (w % WN_) * (BN / WN_);
    f32x4 acc[MI * NI] = {};
    const int e0 = t * 8;

    if (FP32IN) {
        int m_l = t & 63, kseg = t >> 6;
        int ms = tm + m_l;
        int bsv = ms / HWout; int remv = ms - bsv * HWout;
        int oys = remv / Wout, oxs = remv - (remv / Wout) * Wout;
        int iy0 = oys * S - pady, ix0 = oxs * S - padx;
        const float* ibase = inF + (size_t)bsv * CIN * Hin * Win;
        for (int k0 = 0; k0 < KP; k0 += 32) {
            if (e0 < BN * 32) {
                size_t gb = (size_t)(e0 >> 5) * KP + k0 + (e0 & 31);
                gload_lds16(Wt + gb, &lsB[e0]);
                if (SPLIT) gload_lds16(Wt + wloff + gb, &lsB[BSHORT + e0]);
            }
            short8 hi, lo;
            #pragma unroll
            for (int j = 0; j < 8; ++j) {
                int k = k0 + kseg * 8 + j;
                float v = 0.f;
                if (k < K) {
                    int tap = k / CIN, c = k - tap * CIN;
                    int ky = tap / KW, kx = tap - (tap / KW) * KW;
                    int iy = iy0 + ky, ix = ix0 + kx;
                    if ((unsigned)iy < (unsigned)Hin && (unsigned)ix < (unsigned)Win)
                        v = ibase[((size_t)c * Hin + iy) * Win + ix];
                }
                us hb = f2bf(v);
                hi[j] = (short)hb;
                if (SPLIT) lo[j] = (short)f2bf(v - bf2f(hb));
            }
            *(short8*)&lsA[m_l * ASTR + kseg * 8] = hi;
            if (SPLIT) *(short8*)&lsA[ASHORT + m_l * ASTR + kseg * 8] = lo;
            __syncthreads();
            mfma_step32<SPLIT, MI, NI, ASTR, ASHORT, BSHORT>(lsA, lsB, acc, wm0, wn0, l);
            __syncthreads();
        }
    } else if (!BK64) {
        // BK=32 linear path (K=32 1x1 layers)
        int mrow = t >> 2;
        int lane8 = (t & 3) * 8;
        int m = tm + mrow;
        int bsv = m / HWout; int remv = m - bsv * HWout;
        int oys = remv / Wout, oxs = remv - oys * Wout;
        int iy0 = oys * S - pady, ix0 = oxs * S - padx;
        #pragma unroll
        for (int tap = 0; tap < TAPS; ++tap) {
            int ky = tap / KW, kx = tap - (tap / KW) * KW;
            int iy = iy0 + ky, ix = ix0 + kx;
            bool ok = PIX1 || ((unsigned)iy < (unsigned)Hin && (unsigned)ix < (unsigned)Win);
            size_t pix = ((size_t)bsv * Hin + iy) * Win + ix;
            const us* phi = ok ? inH + pix * CIN + lane8 : zpage + lane8;
            const us* plo = zpage;
            if (SPLIT) plo = ok ? inL + pix * CIN + lane8 : zpage + lane8;
            #pragma unroll
            for (int cc = 0; cc < CIN; cc += 32) {
                const int k0 = tap * CIN + cc;
                if (e0 < BN * 32) {
                    size_t gb = (size_t)(e0 >> 5) * KP + k0 + (e0 & 31);
                    gload_lds16(Wt + gb, &lsB[e0]);
                    if (SPLIT) gload_lds16(Wt + wloff + gb, &lsB[BSHORT + e0]);
                }
                gload_lds16(phi + cc, &lsA[t * 8]);
                if (SPLIT) gload_lds16(plo + cc, &lsA[ASHORT + t * 8]);
                __syncthreads();
                mfma_step32<SPLIT, MI, NI, ASTR, ASHORT, BSHORT>(lsA, lsB, acc, wm0, wn0, l);
                __syncthreads();
            }
        }
    } else {
        // BK=64 swizzled path.
        int r0 = t >> 3;
        int lc8 = (((t & 7) ^ (t >> 3)) & 7) * 8;
        int m0v = tm + r0, m1v = tm + r0 + 32;
        int bs0 = m0v / HWout, rm0 = m0v - bs0 * HWout;
        int oy0 = rm0 / Wout, ox0 = rm0 - oy0 * Wout;
        int bs1 = m1v / HWout, rm1 = m1v - bs1 * HWout;
        int oy1 = rm1 / Wout, ox1 = rm1 - oy1 * Wout;
        int iy00 = oy0 * S - pady, ix00 = ox0 * S - padx;
        int iy10 = oy1 * S - pady, ix10 = ox1 * S - padx;
        #pragma unroll
        for (int tap = 0; tap < TAPS; ++tap) {
            int ky = tap / KW, kx = tap - (tap / KW) * KW;
            int iyA = iy00 + ky, ixA = ix00 + kx;
            int iyB = iy10 + ky, ixB = ix10 + kx;
            bool okA = PIX1 || ((unsigned)iyA < (unsigned)Hin && (unsigned)ixA < (unsigned)Win);
            bool okB = PIX1 || ((unsigned)iyB < (unsigned)Hin && (unsigned)ixB < (unsigned)Win);
            size_t pxA = ((size_t)bs0 * Hin + iyA) * Win + ixA;
            size_t pxB = ((size_t)bs1 * Hin + iyB) * Win + ixB;
            const us* pA = okA ? inH + pxA * CIN + lc8 : zpage + lc8;
            const us* pB = okB ? inH + pxB * CIN + lc8 : zpage + lc8;
            const us* qA = zpage + lc8;
            const us* qB = zpage + lc8;
            if (SPLIT) {
                qA = okA ? inL + pxA * CIN + lc8 : zpage + lc8;
                qB = okB ? inL + pxB * CIN + lc8 : zpage + lc8;
            }
            #pragma unroll
            for (int cc = 0; cc < CIN; cc += 64) {
                const int k0 = tap * CIN + cc;
                // B stage (storage pre-swizzled -> linear load)
                #pragma unroll
                for (int q = 0; q < (BN + 31) / 32; ++q) {
                    if (BN >= 32 || t < BN * 8) {
                        size_t gb = (size_t)(q * 32 + (t >> 3)) * KP + k0 + (t & 7) * 8;
                        gload_lds16(Wt + gb, &lsB[q * 2048 + t * 8]);
                        if (SPLIT) gload_lds16(Wt + wloff + gb, &lsB[BSHORT + q * 2048 + t * 8]);
                    }
                }
                // A stage: per-lane swizzled global source
                gload_lds16(pA + cc, &lsA[t * 8]);
                gload_lds16(pB + cc, &lsA[2048 + t * 8]);
                if (SPLIT) {
                    gload_lds16(qA + cc, &lsA[ASHORT + t * 8]);
                    gload_lds16(qB + cc, &lsA[ASHORT + 2048 + t * 8]);
                }
                __syncthreads();
                #pragma unroll
                for (int kk = 0; kk < 2; ++kk) {
                    short8 ah[MI], bh[NI];
                    #pragma unroll
                    for (int mi = 0; mi < MI; ++mi) {
                        int row = wm0 + mi * 16 + (l & 15);
                        int pc = (kk * 4 + (l >> 4)) ^ (row & 7);
                        ah[mi] = *(const short8*)&lsA[row * 64 + pc * 8];
                    }
                    #pragma unroll
                    for (int ni = 0; ni < NI; ++ni) {
                        int row = wn0 + ni * 16 + (l & 15);
                        int pc = (kk * 4 + (l >> 4)) ^ (row & 7);
                        bh[ni] = *(const short8*)&lsB[row * 64 + pc * 8];
                    }
                    if (SPLIT) {
                        short8 al[MI], bl[NI];
                        #pragma unroll
                        for (int mi = 0; mi < MI; ++mi) {
                            int row = wm0 + mi * 16 + (l & 15);
                            int pc = (kk * 4 + (l >> 4)) ^ (row & 7);
                            al[mi] = *(const short8*)&lsA[ASHORT + row * 64 + pc * 8];
                        }
                        #pragma unroll
                        for (int ni = 0; ni < NI; ++ni) {
                            int row = wn0 + ni * 16 + (l & 15);
                            int pc = (kk * 4 + (l >> 4)) ^ (row & 7);
                            bl[ni] = *(const short8*)&lsB[BSHORT + row * 64 + pc * 8];
                        }
                        #pragma unroll
                        for (int mi = 0; mi < MI; ++mi)
                            #pragma unroll
                            for (int ni = 0; ni < NI; ++ni) {
                                acc[mi*NI+ni] = __builtin_amdgcn_mfma_f32_16x16x32_bf16(ah[mi], bh[ni], acc[mi*NI+ni], 0, 0, 0);
                                acc[mi*NI+ni] = __builtin_amdgcn_mfma_f32_16x16x32_bf16(ah[mi], bl[ni], acc[mi*NI+ni], 0, 0, 0);
                                acc[mi*NI+ni] = __builtin_amdgcn_mfma_f32_16x16x32_bf16(al[mi], bh[ni], acc[mi*NI+ni], 0, 0, 0);
                            }
                    } else {
                        #pragma unroll
                        for (int mi = 0; mi < MI; ++mi)
                            #pragma unroll
                            for (int ni = 0; ni < NI; ++ni)
                                acc[mi*NI+ni] = __builtin_amdgcn_mfma_f32_16x16x32_bf16(ah[mi], bh[ni], acc[mi*NI+ni], 0, 0, 0);
                    }
                }
                __syncthreads();
            }
        }
    }

    // ---- epilogue ----
    #pragma unroll
    for (int mi = 0; mi < MI; ++mi) {
        #pragma unroll
        for (int ni = 0; ni < NI; ++ni) {
            int n = ncol0 + wn0 + ni * 16 + (l & 15);
            if (n >= Cout) continue;
            float bv = BIAS ? bias[n] : 0.f;
            #pragma unroll
            for (int j = 0; j < 4; ++j) {
                int m = tm + wm0 + mi * 16 + (l >> 4) * 4 + j;
                float v = acc[mi * NI + ni][j] + bv;
                if (RESID == 1) { size_t ri = (size_t)m * Cout + n; v += bf2f(rH[ri]) + bf2f(rL[ri]); }
                if (RESID == 2) { v += bf2f(rH[(size_t)m * Cout + n]); }
                float vr = RELU ? fmaxf(v, 0.f) : v;
                if (DUAL) {
                    size_t oi = (size_t)m * Cout + n;
                    us hb = f2bf(v);
                    o2H[oi] = hb;
                    if (SPLIT) o2L[oi] = f2bf(v - bf2f(hb));
                }
                if (OMODE == 0) {
                    size_t oi = (size_t)m * Cout + n;
                    us hb = f2bf(vr);
                    oH[oi] = hb;
                    if (SPLIT) oL[oi] = f2bf(vr - bf2f(hb));
                } else if (OMODE == 1) {
                    int b2 = m / HWout, rem = m - b2 * HWout;
                    oF[(size_t)(b2 * Cout + n) * HWout + rem] = vr;
                } else if (OMODE == 2) {
                    int b2 = m / HWout, rem = m - b2 * HWout;
                    int y = rem / Wout, x2 = rem - y * Wout;
                    oF[(size_t)(b2 * Cout + n) * (4 * HWout)
                       + (size_t)(2 * y + py) * (2 * Wout) + (2 * x2 + px)] = vr;
                } else {
                    int b2 = m / HWout, rem = m - b2 * HWout;
                    int y = rem / Wout, x2 = rem - y * Wout;
                    int Hg2 = 2 * (HWout / Wout);
                    size_t oi = (((size_t)b2 * Hg2 + (2 * y + py)) * (size_t)(2 * Wout)
                                 + (2 * x2 + px)) * Cout + n;
                    oH[oi] = f2bf(vr);
                }
            }
        }
    }
}

// ---------------------------------------------------------------------------
// Weight packing. swz=1: store logical k-chunk (pc ^ (n&7)) at physical pc
// within each 64-k block (so linear gload -> swizzled LDS).
// ---------------------------------------------------------------------------
struct PackDesc {
    const float* src; unsigned long long dstoff;
    int Npad, N, CIN, KH, KW, K, Kpad, mode, py, px, split, swz;
};
struct PackArgs { PackDesc d[21]; };

__global__ __launch_bounds__(256) void wpack_all(PackArgs pa, us* __restrict__ wp)
{
    PackDesc d = pa.d[blockIdx.y];
    int gid = blockIdx.x * 256 + threadIdx.x;
    int tot = d.Npad * d.Kpad;
    if (gid >= tot) return;
    int n = gid / d.Kpad;
    int k = gid - n * d.Kpad;          // physical k
    int klog = k;
    if (d.swz) {
        int kb = k >> 6, pc = (k >> 3) & 7, j = k & 7;
        klog = (kb << 6) + (((pc ^ (n & 7)) & 7) << 3) + j;
    }
    float v = 0.0f;
    if (n < d.N && klog < d.K) {
        int tap = klog / d.CIN, c = klog - tap * d.CIN;
        int ky, kx;
        if (d.mode == 0) { ky = tap / d.KW; kx = tap - (tap / d.KW) * d.KW; }
        else { int ty = tap >> 1, tx = tap & 1; ky = d.py + 2 * ty; kx = d.px + 2 * tx; }
        v = d.src[((size_t)(n * d.CIN + c) * d.KH + ky) * d.KW + kx];
    }
    us hb = f2bf(v);
    wp[d.dstoff + gid] = hb;
    if (d.split) wp[d.dstoff + tot + gid] = f2bf(v - bf2f(hb));
}

// ---------------------------------------------------------------------------
// VQ
// ---------------------------------------------------------------------------
__global__ __launch_bounds__(256) void vq_sq(
    const float* __restrict__ cb, float* __restrict__ ccsq)
{
    int k = blockIdx.x * 256 + threadIdx.x;
    const float* c = cb + (size_t)k * 64;
    float a0 = 0.f, a1 = 0.f;
    #pragma unroll
    for (int d = 0; d < 64; d += 2) {
        a0 = fmaf(c[d], c[d], a0);
        a1 = fmaf(c[d + 1], c[d + 1], a1);
    }
    ccsq[k] = a0 + a1;
}

__global__ __launch_bounds__(256) void vq_scan(
    const float* __restrict__ z, const float* __restrict__ cb,
    const float* __restrict__ ccsq,
    float* __restrict__ pdist, int* __restrict__ pidx)
{
    const int HW = 1024;
    int n = blockIdx.x * 256 + threadIdx.x;
    int chunk = blockIdx.y;
    int base = chunk * 64;
    int b = n >> 10;
    int p = n & 1023;
    const float* zp = z + (size_t)b * 64 * HW + p;
    float zv[64];
    #pragma unroll
    for (int d = 0; d < 64; ++d) zv[d] = zp[(size_t)d * HW];

    float best = 3.402823e38f;
    int bi = base;
    for (int kk = 0; kk < 64; kk += 2) {
        const float* c0 = cb + (size_t)(base + kk) * 64;
        float a0 = 0.f, a1 = 0.f, b0 = 0.f, b1 = 0.f;
        #pragma unroll
        for (int d = 0; d < 64; d += 2) {
            a0 = fmaf(zv[d],     c0[d],          a0);
            a1 = fmaf(zv[d + 1], c0[d + 1],      a1);
            b0 = fmaf(zv[d],     c0[64 + d],     b0);
            b1 = fmaf(zv[d + 1], c0[64 + d + 1], b1);
        }
        float s0 = ccsq[base + kk]     - 2.0f * (a0 + a1);
        float s1 = ccsq[base + kk + 1] - 2.0f * (b0 + b1);
        if (s0 < best) { best = s0; bi = base + kk; }
        if (s1 < best) { best = s1; bi = base + kk + 1; }
    }
    pdist[(size_t)chunk * 32768 + n] = best;
    pidx [(size_t)chunk * 32768 + n] = bi;
}

__global__ __launch_bounds__(256) void vq_reduce(
    const float* __restrict__ z, const float* __restrict__ cb,
    const float* __restrict__ pdist, const int* __restrict__ pidx,
    us* __restrict__ qb, int* __restrict__ idxbuf, float* __restrict__ sse)
{
    const int HW = 1024;
    int nl = threadIdx.x & 31;
    int dg = threadIdx.x >> 5;
    int n = blockIdx.x * 32 + nl;
    float best = pdist[n];
    int bi = pidx[n];
    #pragma unroll
    for (int ch = 1; ch < 8; ++ch) {
        float dv = pdist[(size_t)ch * 32768 + n];
        int iv = pidx[(size_t)ch * 32768 + n];
        if (dv < best) { best = dv; bi = iv; }
    }
    if (dg == 0) idxbuf[n] = bi;
    int b = n >> 10;
    int p = n & 1023;
    const float* zp = z + (size_t)b * 64 * HW + p;
    const float* c = cb + (size_t)bi * 64;
    float s = 0.f;
    short8 qv;
    #pragma unroll
    for (int j = 0; j < 8; ++j) {
        int d = dg * 8 + j;
        float q = c[d];
        qv[j] = (short)f2bf(q);
        float df = q - zp[(size_t)d * HW];
        s = fmaf(df, df, s);
    }
    *(short8*)&qb[(size_t)n * 64 + dg * 8] = qv;
    #pragma unroll
    for (int off = 32; off > 0; off >>= 1) s += __shfl_down(s, off, 64);
    __shared__ float red[4];
    if ((threadIdx.x & 63) == 0) red[threadIdx.x >> 6] = s;
    __syncthreads();
    if (threadIdx.x == 0) atomicAdd(sse, red[0] + red[1] + red[2] + red[3]);
}

// single block: LDS histogram + perplexity + loss (merged hist+finalize)
__global__ __launch_bounds__(1024) void vq_hist_fin(
    const int* __restrict__ idxbuf, const float* __restrict__ sse,
    float* __restrict__ out_loss, float* __restrict__ out_ppl)
{
    __shared__ int lh[512];
    __shared__ float red[512];
    int t = threadIdx.x;
    if (t < 512) lh[t] = 0;
    __syncthreads();
    #pragma unroll
    for (int j = 0; j < 32; ++j)
        atomicAdd(&lh[idxbuf[j * 1024 + t]], 1);
    __syncthreads();
    if (t < 512) {
        float p = (float)lh[t] * (1.0f / 32768.0f);
        red[t] = p * logf(p + 1e-10f);
    }
    __syncthreads();
    for (int s = 256; s > 0; s >>= 1) {
        if (t < s) red[t] += red[t + s];
        __syncthreads();
    }
    if (t == 0) {
        *out_ppl = expf(-red[0]);
        *out_loss = 1.25f * (*sse) * (1.0f / 2097152.0f);
    }
}

// ---------------------------------------------------------------------------
extern "C" void kernel_launch(void* const* d_in, const int* in_sizes, int n_in,
                              void* d_out, int out_size, void* d_ws, size_t ws_size,
                              hipStream_t stream)
{
    const float* x        = (const float*)d_in[0];
    const float* e_w1     = (const float*)d_in[1];
    const float* e_b1     = (const float*)d_in[2];
    const float* e_w2     = (const float*)d_in[3];
    const float* e_b2     = (const float*)d_in[4];
    const float* e_w3     = (const float*)d_in[5];
    const float* e_b3     = (const float*)d_in[6];
    const float* e_r1a    = (const float*)d_in[7];
    const float* e_r1b    = (const float*)d_in[8];
    const float* e_r2a    = (const float*)d_in[9];
    const float* e_r2b    = (const float*)d_in[10];
    const float* pre_w    = (const float*)d_in[11];
    const float* pre_b    = (const float*)d_in[12];
    const float* codebook = (const float*)d_in[13];
    const float* d_w1     = (const float*)d_in[14];
    const float* d_b1     = (const float*)d_in[15];
    const float* d_r1a    = (const float*)d_in[16];
    const float* d_r1b    = (const float*)d_in[17];
    const float* d_r2a    = (const float*)d_in[18];
    const float* d_r2b    = (const float*)d_in[19];
    const float* dt_w1    = (const float*)d_in[20];
    const float* dt_b1    = (const float*)d_in[21];
    const float* dt_w2    = (const float*)d_in[22];
    const float* dt_b2    = (const float*)d_in[23];
    float* out = (float*)d_out;

    // ---- arena ----
    const size_t MB = 1024 * 1024;
    char* base = (char*)d_ws;
    char* A0 = base;               // 32 MB slot
    char* B0 = base + 32 * MB;     // 16 MB slot
    char* C0 = base + 48 * MB;     // 16 MB slot
    char* D0 = base + 64 * MB;     //  4 MB slot
    float* st = (float*)(base + 68 * MB);                 // 4 KB (hist/sse/zpage)
    us* wp = (us*)(base + 68 * MB + 4096);

    us* h1H = (us*)A0;              us* h1L = (us*)(A0 + 16 * MB);
    us* hBH = (us*)B0;              us* hBL = (us*)(B0 + 8 * MB);
    us* CeH = (us*)A0;              us* CeL = (us*)(A0 + 8 * MB);   // C relu
    us* CrH = (us*)C0;              us* CrL = (us*)(C0 + 8 * MB);   // C raw
    us* DsH = (us*)D0;              us* DsL = (us*)(D0 + 2 * MB);
    us* T2rH = (us*)A0;             us* T2rL = (us*)(A0 + 8 * MB);  // T2 raw
    us* T2eH = (us*)B0;             us* T2eL = (us*)(B0 + 8 * MB);  // T2 relu
    us* T3H = (us*)C0;              us* T3L = (us*)(C0 + 8 * MB);
    float* E = (float*)B0;                                          // z fp32
    us* qb = (us*)(B0 + 8 * MB);                                    // q bf16 NHWC
    float* pdist = (float*)A0;
    int* pidx = (int*)(A0 + 1 * MB);
    int* idxbuf = (int*)(A0 + 2 * MB);
    float* ccsq = (float*)(A0 + 2 * MB + 128 * 1024);
    us* GeH = (us*)A0;              us* GrH = (us*)(A0 + 8 * MB);   // dec g relu/raw
    us* dDs = (us*)D0;
    us* dT2e = (us*)B0;             us* dT2r = (us*)(B0 + 8 * MB);
    us* dT3 = (us*)C0;
    us* gbuf = (us*)A0;
    const us* zpage = (const us*)(st + 576);                        // zeros

    // ---- weight packing ----
    PackArgs pa;
    int np = 0; unsigned long long wpo = 0;
    auto addpack = [&](const float* src, int N, int Npad, int CIN, int KH, int KW,
                       int K, int Kpad, int mode, int py, int px, int split,
                       int swz) -> unsigned long long {
        pa.d[np].src = src; pa.d[np].dstoff = wpo;
        pa.d[np].Npad = Npad; pa.d[np].N = N; pa.d[np].CIN = CIN;
        pa.d[np].KH = KH; pa.d[np].KW = KW; pa.d[np].K = K; pa.d[np].Kpad = Kpad;
        pa.d[np].mode = mode; pa.d[np].py = py; pa.d[np].px = px;
        pa.d[np].split = split; pa.d[np].swz = swz;
        ++np; unsigned long long off = wpo; wpo += (unsigned long long)Npad * Kpad * (split ? 2 : 1);
        return off;
    };
    unsigned long long P_E1  = addpack(e_w1, 64, 64, 3, 4, 4, 48, 64, 0, 0, 0, 1, 0);
    unsigned long long P_E2  = addpack(e_w2, 128, 128, 64, 4, 4, 1024, 1024, 0, 0, 0, 1, 1);
    unsigned long long P_E3  = addpack(e_w3, 128, 128, 128, 3, 3, 1152, 1152, 0, 0, 0, 1, 1);
    unsigned long long P_R1A = addpack(e_r1a, 32, 32, 128, 3, 3, 1152, 1152, 0, 0, 0, 1, 1);
    unsigned long long P_R1B = addpack(e_r1b, 128, 128, 32, 1, 1, 32, 32, 0, 0, 0, 1, 0);
    unsigned long long P_R2A = addpack(e_r2a, 32, 32, 128, 3, 3, 1152, 1152, 0, 0, 0, 1, 1);
    unsigned long long P_R2B = addpack(e_r2b, 128, 128, 32, 1, 1, 32, 32, 0, 0, 0, 1, 0);
    unsigned long long P_PRE = addpack(pre_w, 64, 64, 128, 1, 1, 128, 128, 0, 0, 0, 1, 1);
    unsigned long long P_D1  = addpack(d_w1, 128, 128, 64, 3, 3, 576, 576, 0, 0, 0, 0, 1);
    unsigned long long P_DR1A = addpack(d_r1a, 32, 32, 128, 3, 3, 1152, 1152, 0, 0, 0, 0, 1);
    unsigned long long P_DR1B = addpack(d_r1b, 128, 128, 32, 1, 1, 32, 32, 0, 0, 0, 0, 0);
    unsigned long long P_DR2A = addpack(d_r2a, 32, 32, 128, 3, 3, 1152, 1152, 0, 0, 0, 0, 1);
    unsigned long long P_DR2B = addpack(d_r2b, 128, 128, 32, 1, 1, 32, 32, 0, 0, 0, 0, 0);
    unsigned long long P_DT1[4], P_DT2[4];
    for (int p = 0; p < 4; ++p)
        P_DT1[p] = addpack(dt_w1, 64, 64, 128, 4, 4, 512, 512, 1, p >> 1, p & 1, 0, 1);
    for (int p = 0; p < 4; ++p)
        P_DT2[p] = addpack(dt_w2, 3, 16, 64, 4, 4, 256, 256, 1, p >> 1, p & 1, 0, 1);

    hipMemsetAsync(st, 0, 4096, stream);    // hist, sse, zero page
    wpack_all<<<dim3(576, 21), 256, 0, stream>>>(pa, wp);

    // ----- encoder (split) -----
    conv_gemm<3,4,4,2, true,true, 64,2,2, true,0,true,false,0, false,false><<<dim3(2048),256,0,stream>>>(
        nullptr, nullptr, x, wp + P_E1, 64ull*64, e_b1,
        h1H, h1L, nullptr, nullptr, nullptr, nullptr, nullptr, zpage,
        128,128, 64, 4096, 64, 1,1, 0,0, 1);
    conv_gemm<64,4,4,2, false,true, 128,2,2, true,0,true,false,0, true,false><<<dim3(512),256,0,stream>>>(
        h1H, h1L, nullptr, wp + P_E2, 128ull*1024, e_b2,
        hBH, hBL, nullptr, nullptr, nullptr, nullptr, nullptr, zpage,
        64,64, 32, 1024, 128, 1,1, 0,0, 1);
    conv_gemm<128,3,3,1, false,true, 128,2,2, true,0,true,true,0, true,false><<<dim3(512),256,0,stream>>>(
        hBH, hBL, nullptr, wp + P_E3, 128ull*1152, e_b3,
        CeH, CeL, CrH, CrL, nullptr, nullptr, nullptr, zpage,
        32,32, 32, 1024, 128, 1,1, 0,0, 1);
    conv_gemm<128,3,3,1, false,true, 32,4,1, false,0,true,false,0, true,false><<<dim3(512),256,0,stream>>>(
        CeH, CeL, nullptr, wp + P_R1A, 32ull*1152, nullptr,
        DsH, DsL, nullptr, nullptr, nullptr, nullptr, nullptr, zpage,
        32,32, 32, 1024, 32, 1,1, 0,0, 1);
    conv_gemm<32,1,1,1, false,true, 64,2,2, false,1,true,true,0, false,false><<<dim3(1024),256,0,stream>>>(
        DsH, DsL, nullptr, wp + P_R1B, 128ull*32, nullptr,
        T2eH, T2eL, T2rH, T2rL, nullptr, CrH, CrL, zpage,
        32,32, 32, 1024, 128, 0,0, 0,0, 2);
    conv_gemm<128,3,3,1, false,true, 32,4,1, false,0,true,false,0, true,false><<<dim3(512),256,0,stream>>>(
        T2eH, T2eL, nullptr, wp + P_R2A, 32ull*1152, nullptr,
        DsH, DsL, nullptr, nullptr, nullptr, nullptr, nullptr, zpage,
        32,32, 32, 1024, 32, 1,1, 0,0, 1);
    conv_gemm<32,1,1,1, false,true, 64,2,2, false,1,true,false,0, false,false><<<dim3(1024),256,0,stream>>>(
        DsH, DsL, nullptr, wp + P_R2B, 128ull*32, nullptr,
        T3H, T3L, nullptr, nullptr, nullptr, T2rH, T2rL, zpage,
        32,32, 32, 1024, 128, 0,0, 0,0, 2);
    conv_gemm<128,1,1,1, false,true, 64,2,2, true,0,false,false,1, true,false><<<dim3(512),256,0,stream>>>(
        T3H, T3L, nullptr, wp + P_PRE, 64ull*128, pre_b,
        nullptr, nullptr, nullptr, nullptr, E, nullptr, nullptr, zpage,
        32,32, 32, 1024, 64, 0,0, 0,0, 1);

    // ----- vector quantizer -----
    vq_sq<<<dim3(2), 256, 0, stream>>>(codebook, ccsq);
    vq_scan<<<dim3(128, 8), 256, 0, stream>>>(E, codebook, ccsq, pdist, pidx);
    vq_reduce<<<dim3(1024), 256, 0, stream>>>(E, codebook, pdist, pidx, qb, idxbuf, st + 512);
    vq_hist_fin<<<dim3(1), 1024, 0, stream>>>(idxbuf, st + 512, out, out + 1572865);

    // ----- decoder (plain bf16) -----
    conv_gemm<64,3,3,1, false,false, 128,2,2, true,0,true,true,0, true,false><<<dim3(512),256,0,stream>>>(
        qb, nullptr, nullptr, wp + P_D1, 0ull, d_b1,
        GeH, nullptr, GrH, nullptr, nullptr, nullptr, nullptr, zpage,
        32,32, 32, 1024, 128, 1,1, 0,0, 1);
    conv_gemm<128,3,3,1, false,false, 32,4,1, false,0,true,false,0, true,false><<<dim3(512),256,0,stream>>>(
        GeH, nullptr, nullptr, wp + P_DR1A, 0ull, nullptr,
        dDs, nullptr, nullptr, nullptr, nullptr, nullptr, nullptr, zpage,
        32,32, 32, 1024, 32, 1,1, 0,0, 1);
    conv_gemm<32,1,1,1, false,false, 64,2,2, false,2,true,true,0, false,false><<<dim3(1024),256,0,stream>>>(
        dDs, nullptr, nullptr, wp + P_DR1B, 0ull, nullptr,
        dT2e, nullptr, dT2r, nullptr, nullptr, GrH, nullptr, zpage,
        32,32, 32, 1024, 128, 0,0, 0,0, 2);
    conv_gemm<128,3,3,1, false,false, 32,4,1, false,0,true,false,0, true,false><<<dim3(512),256,0,stream>>>(
        dT2e, nullptr, nullptr, wp + P_DR2A, 0ull, nullptr,
        dDs, nullptr, nullptr, nullptr, nullptr, nullptr, nullptr, zpage,
        32,32, 32, 1024, 32, 1,1, 0,0, 1);
    conv_gemm<32,1,1,1, false,false, 64,2,2, false,2,true,false,0, false,false><<<dim3(1024),256,0,stream>>>(
        dDs, nullptr, nullptr, wp + P_DR2B, 0ull, nullptr,
        dT3, nullptr, nullptr, nullptr, nullptr, dT2r, nullptr, zpage,
        32,32, 32, 1024, 128, 0,0, 0,0, 2);
    // DT1: 4 parity classes in one launch (blockIdx.y)
    conv_gemm<128,2,2,1, false,false, 64,2,2, true,0,true,false,3, true,true><<<dim3(512,4),256,0,stream>>>(
        dT3, nullptr, nullptr, wp + P_DT1[0], 0ull, dt_b1,
        gbuf, nullptr, nullptr, nullptr, nullptr, nullptr, nullptr, zpage,
        32,32, 32, 1024, 64, 0,0, 0,0, 1);
    // DT2: 4 parity classes in one launch
    conv_gemm<64,2,2,1, false,false, 16,4,1, true,0,false,false,2, true,true><<<dim3(2048,4),256,0,stream>>>(
        gbuf, nullptr, nullptr, wp + P_DT2[0], 0ull, dt_b2,
        nullptr, nullptr, nullptr, nullptr, out + 1, nullptr, nullptr, zpage,
        64,64, 64, 4096, 3, 0,0, 0,0, 1);
}